// Round 1
// baseline (1149.004 us; speedup 1.0000x reference)
//
#include <hip/hip_runtime.h>
#include <hip/hip_bf16.h>
#include <math.h>

#define B_  8
#define N_  128
#define T_  1024
#define D_  512
#define LD_ 64
#define H_  8
#define Q_  4

// ---------------------------------------------------------------------------
// segmentation: idx[b,t] = argmax_n alignments, dur/seg_start per (b,n)
// ---------------------------------------------------------------------------
__global__ void k_seg_init(int* __restrict__ dur, int* __restrict__ segst) {
  int i = blockIdx.x * blockDim.x + threadIdx.x;
  if (i < B_ * N_) { dur[i] = 0; segst[i] = 0x7fffffff; }
}

__global__ void k_seg_build(const float* __restrict__ align, int* __restrict__ idx,
                            int* __restrict__ dur, int* __restrict__ segst) {
  int gid = blockIdx.x * blockDim.x + threadIdx.x;   // b*T + t
  if (gid >= B_ * T_) return;
  const float* row = align + (size_t)gid * N_;
  int n = 0;
  for (; n < N_; ++n) if (row[n] > 0.5f) break;
  if (n >= N_) n = 0;  // cannot happen for one-hot input
  idx[gid] = n;
  int b = gid >> 10, t = gid & 1023;
  atomicAdd(&dur[b * N_ + n], 1);
  atomicMin(&segst[b * N_ + n], t);
}

// ---------------------------------------------------------------------------
// queries[b, n*Q+j, :] = j==0 ? embeddings[b,n,:] : learnable[j-1,:]
// ---------------------------------------------------------------------------
__global__ void k_build_queries(const float* __restrict__ emb, const float* __restrict__ lq,
                                float* __restrict__ out) {
  int gid = blockIdx.x * blockDim.x + threadIdx.x;
  if (gid >= B_ * N_ * Q_ * D_) return;
  int d = gid & (D_ - 1);
  int row = gid >> 9;
  int j = row & 3;
  int bn = row >> 2;
  out[gid] = (j == 0) ? emb[(size_t)bn * D_ + d] : lq[(j - 1) * D_ + d];
}

// ---------------------------------------------------------------------------
// generic fp32 GEMM: C[m][n] = sum_k A[m][k] * W[n][k] + bias[n]
//   EPI: 0 none, 1 silu, 2 silu + extra[m*Nc+n]
//   APAD: A physical row = m + 2*(m>>10)   (padded [B][T+2][*] buffers)
//   CMODE: 0 C row = m; 1 C row = m + 2*(m>>10) + 1 (write into padded buffer)
// ---------------------------------------------------------------------------
template<int EPI, int APAD, int CMODE>
__global__ __launch_bounds__(256) void k_gemm(
    const float* __restrict__ A, int lda,
    const float* __restrict__ W,
    const float* __restrict__ bias,
    const float* __restrict__ extra,
    float* __restrict__ C, int ldc,
    int M, int Nc, int K)
{
  __shared__ float As[16][66];
  __shared__ float Bs[16][66];
  int tid = threadIdx.x;
  int tx = tid & 15, ty = tid >> 4;
  int m0 = blockIdx.y * 64;
  int n0 = blockIdx.x * 64;
  float acc[4][4] = {};
  for (int kt = 0; kt < K; kt += 16) {
#pragma unroll
    for (int l = 0; l < 4; ++l) {
      int lin = tid + l * 256;
      int k = lin & 15, m = lin >> 4;
      int gm = m0 + m, gk = kt + k;
      float v = 0.f;
      if (gm < M && gk < K) {
        int ar = APAD ? (gm + ((gm >> 10) << 1)) : gm;
        v = A[(size_t)ar * lda + gk];
      }
      As[k][m] = v;
    }
#pragma unroll
    for (int l = 0; l < 4; ++l) {
      int lin = tid + l * 256;
      int k = lin & 15, n = lin >> 4;
      int gn = n0 + n, gk = kt + k;
      float v = 0.f;
      if (gn < Nc && gk < K) v = W[(size_t)gn * K + gk];
      Bs[k][n] = v;
    }
    __syncthreads();
#pragma unroll
    for (int k = 0; k < 16; ++k) {
      float a[4], bb[4];
#pragma unroll
      for (int i = 0; i < 4; ++i) a[i] = As[k][ty + i * 16];
#pragma unroll
      for (int j = 0; j < 4; ++j) bb[j] = Bs[k][tx + j * 16];
#pragma unroll
      for (int i = 0; i < 4; ++i)
#pragma unroll
        for (int j = 0; j < 4; ++j)
          acc[i][j] = fmaf(a[i], bb[j], acc[i][j]);
    }
    __syncthreads();
  }
#pragma unroll
  for (int i = 0; i < 4; ++i) {
    int gm = m0 + ty + i * 16;
    if (gm >= M) continue;
    int cr = (CMODE == 1) ? (gm + ((gm >> 10) << 1) + 1) : gm;
#pragma unroll
    for (int j = 0; j < 4; ++j) {
      int gn = n0 + tx + j * 16;
      if (gn >= Nc) continue;
      float v = acc[i][j] + bias[gn];
      if (EPI >= 1) v = v / (1.f + expf(-v));     // silu
      if (EPI == 2) v += extra[(size_t)gm * Nc + gn];
      C[(size_t)cr * ldc + gn] = v;
    }
  }
}

// ---------------------------------------------------------------------------
// per-(b,n) segment attention. kv layout: [b*T+t][1024] (k: 0..511, v: 512..1023)
// block = 256 threads = 4 waves, wave w handles query j=w
// ---------------------------------------------------------------------------
__global__ __launch_bounds__(256) void k_attn(
    const float* __restrict__ qbuf, const float* __restrict__ kv,
    const int* __restrict__ segst, const int* __restrict__ dur,
    float* __restrict__ ctx)
{
  __shared__ float q_sh[4][64];
  __shared__ float sc[4][T_];
  int bn = blockIdx.x;
  int b = bn >> 7;
  int w = threadIdx.x >> 6;
  int lane = threadIdx.x & 63;
  int s0 = segst[bn], cnt = dur[bn];
  if (cnt == 0) { s0 = 0; cnt = T_; }   // all-masked row -> attend everywhere
  size_t qrow = (size_t)bn * 4 + w;
  const float* kvb = kv + (size_t)b * T_ * 1024;
  for (int h = 0; h < H_; ++h) {
    q_sh[w][lane] = qbuf[qrow * D_ + h * 64 + lane];
    __syncthreads();
    float lmax = -1e30f;
    for (int s = lane; s < cnt; s += 64) {
      const float* kr = kvb + (size_t)(s0 + s) * 1024 + h * 64;
      float a = 0.f;
#pragma unroll
      for (int d = 0; d < 64; ++d) a = fmaf(q_sh[w][d], kr[d], a);
      a *= 0.125f;                       // 1/sqrt(64)
      sc[w][s] = a;
      lmax = fmaxf(lmax, a);
    }
#pragma unroll
    for (int off = 32; off; off >>= 1) lmax = fmaxf(lmax, __shfl_xor(lmax, off));
    float lsum = 0.f;
    for (int s = lane; s < cnt; s += 64) {
      float p = expf(sc[w][s] - lmax);
      sc[w][s] = p;
      lsum += p;
    }
#pragma unroll
    for (int off = 32; off; off >>= 1) lsum += __shfl_xor(lsum, off);
    __syncthreads();
    float o = 0.f;
    const float* vb = kvb + 512 + h * 64 + lane;
    for (int s = 0; s < cnt; ++s)
      o = fmaf(sc[w][s], vb[(size_t)(s0 + s) * 1024], o);
    ctx[qrow * D_ + h * 64 + lane] = o / lsum;
    __syncthreads();
  }
}

// ---------------------------------------------------------------------------
// layernorm over D of (queries + attn_out), scale/shift
// ---------------------------------------------------------------------------
__global__ __launch_bounds__(256) void k_ln(
    const float* __restrict__ qin, const float* __restrict__ attn,
    const float* __restrict__ g, const float* __restrict__ bb,
    float* __restrict__ qn)
{
  int r = blockIdx.x * 4 + (threadIdx.x >> 6);
  int lane = threadIdx.x & 63;
  float h[8];
  float s = 0.f, s2 = 0.f;
#pragma unroll
  for (int i = 0; i < 8; ++i) {
    int d = i * 64 + lane;
    float v = qin[(size_t)r * D_ + d] + attn[(size_t)r * D_ + d];
    h[i] = v; s += v; s2 += v * v;
  }
#pragma unroll
  for (int off = 32; off; off >>= 1) { s += __shfl_xor(s, off); s2 += __shfl_xor(s2, off); }
  float mean = s * (1.f / 512.f);
  float var = s2 * (1.f / 512.f) - mean * mean;
  float inv = rsqrtf(var + 1e-5f);
#pragma unroll
  for (int i = 0; i < 8; ++i) {
    int d = i * 64 + lane;
    qn[(size_t)r * D_ + d] = (h[i] - mean) * inv * g[d] + bb[d];
  }
}

// ---------------------------------------------------------------------------
// pooled[b,n,d] = sum_{t in seg} x[b,t,d] / (dur + 1e-8)
// ---------------------------------------------------------------------------
__global__ __launch_bounds__(256) void k_pool(
    const float* __restrict__ x, const int* __restrict__ segst,
    const int* __restrict__ dur, float* __restrict__ pooled)
{
  int bn = blockIdx.x;
  int b = bn >> 7;
  int s0 = segst[bn], cnt = dur[bn];
  int d0 = threadIdx.x;
  float a0 = 0.f, a1 = 0.f;
  for (int i = 0; i < cnt; ++i) {
    const float* xr = x + (size_t)(b * T_ + s0 + i) * D_;
    a0 += xr[d0];
    a1 += xr[d0 + 256];
  }
  float inv = 1.f / ((float)cnt + 1e-8f);
  pooled[(size_t)bn * D_ + d0] = a0 * inv;
  pooled[(size_t)bn * D_ + d0 + 256] = a1 * inv;
}

// ---------------------------------------------------------------------------
// mu/logvar/z + per-(b,n) KL partial
// ---------------------------------------------------------------------------
__global__ __launch_bounds__(128) void k_muz(
    const float* __restrict__ hidden,
    const float* __restrict__ mu_w, const float* __restrict__ mu_b,
    const float* __restrict__ lv_w, const float* __restrict__ lv_b,
    const float* __restrict__ eps, float* __restrict__ z, float* __restrict__ klpart)
{
  __shared__ float hs[512];
  __shared__ float ms[64], ls[64];
  int bn = blockIdx.x;
  int tid = threadIdx.x;
  for (int i = tid; i < 512; i += 128) hs[i] = hidden[(size_t)bn * 512 + i];
  __syncthreads();
  int ld = tid & 63;
  const float* wrow = (tid < 64) ? (mu_w + (size_t)ld * 512) : (lv_w + (size_t)ld * 512);
  float acc = 0.f;
  for (int k = 0; k < 512; ++k) acc = fmaf(hs[k], wrow[k], acc);
  acc += (tid < 64) ? mu_b[ld] : lv_b[ld];
  if (tid < 64) ms[ld] = acc; else ls[ld] = acc;
  __syncthreads();
  if (tid < 64) {
    float mu = ms[ld], lv = ls[ld];
    z[(size_t)bn * 64 + ld] = mu + eps[(size_t)bn * 64 + ld] * expf(0.5f * lv);
    float klt = 1.f + lv - mu * mu - expf(lv);
#pragma unroll
    for (int off = 32; off; off >>= 1) klt += __shfl_xor(klt, off);
    if (ld == 0) klpart[bn] = klt;
  }
}

// ---------------------------------------------------------------------------
// build padded conv1 input zcT [B][T+2][65]: z_up | phase, zero pad rows
// ---------------------------------------------------------------------------
__global__ void k_zc(const float* __restrict__ z, const int* __restrict__ idx,
                     const int* __restrict__ segst, const int* __restrict__ dur,
                     float* __restrict__ zcT)
{
  int gid = blockIdx.x * blockDim.x + threadIdx.x;
  const int total = B_ * (T_ + 2) * 65;
  if (gid >= total) return;
  int c = gid % 65;
  int rest = gid / 65;
  int r = rest % (T_ + 2);
  int b = rest / (T_ + 2);
  float v = 0.f;
  if (r >= 1 && r <= T_) {
    int t = r - 1;
    int iv = idx[b * T_ + t];
    if (c < 64) v = z[(size_t)(b * N_ + iv) * 64 + c];
    else {
      int s0 = segst[b * N_ + iv];
      float d = (float)dur[b * N_ + iv];     // >=1 for any assigned frame
      v = ((float)(t - s0) + 0.5f) / d;
    }
  }
  zcT[gid] = v;
}

// zero the two pad rows of y1p per batch
__global__ void k_zero_pad(float* __restrict__ y1p) {
  int gid = blockIdx.x * blockDim.x + threadIdx.x;
  if (gid >= B_ * 2 * 512) return;
  int d = gid & 511;
  int rest = gid >> 9;
  int which = rest & 1;
  int b = rest >> 1;
  int r = which ? (T_ + 1) : 0;
  y1p[(size_t)(b * (T_ + 2) + r) * 512 + d] = 0.f;
}

// conv weight transposes: [c][i][k] -> [c][k][i]
__global__ void k_w1t(const float* __restrict__ w, float* __restrict__ wt) {
  int gid = blockIdx.x * blockDim.x + threadIdx.x;
  if (gid >= 512 * 65 * 3) return;
  int k = gid % 3;
  int i = (gid / 3) % 65;
  int c = gid / 195;
  wt[c * 195 + k * 65 + i] = w[gid];
}
__global__ void k_w2t(const float* __restrict__ w, float* __restrict__ wt) {
  int gid = blockIdx.x * blockDim.x + threadIdx.x;
  if (gid >= 512 * 512 * 3) return;
  int k = gid % 3;
  int ci = (gid / 3) % 512;
  int co = gid / 1536;
  wt[(size_t)co * 1536 + k * 512 + ci] = w[gid];
}

// ---------------------------------------------------------------------------
// losses
// ---------------------------------------------------------------------------
__global__ __launch_bounds__(256) void k_loss_part(
    const float* __restrict__ x, const float* __restrict__ xr,
    float* __restrict__ l1part, float* __restrict__ l2part)
{
  __shared__ float sh1[4], sh2[4];
  float a = 0.f, b2 = 0.f;
  const int total = B_ * T_ * D_;
  for (int i = blockIdx.x * blockDim.x + threadIdx.x; i < total; i += gridDim.x * blockDim.x) {
    float d = x[i] - xr[i];
    a += fabsf(d);
    b2 += d * d;
  }
#pragma unroll
  for (int off = 32; off; off >>= 1) { a += __shfl_xor(a, off); b2 += __shfl_xor(b2, off); }
  int w = threadIdx.x >> 6, lane = threadIdx.x & 63;
  if (lane == 0) { sh1[w] = a; sh2[w] = b2; }
  __syncthreads();
  if (threadIdx.x == 0) {
    l1part[blockIdx.x] = sh1[0] + sh1[1] + sh1[2] + sh1[3];
    l2part[blockIdx.x] = sh2[0] + sh2[1] + sh2[2] + sh2[3];
  }
}

__global__ __launch_bounds__(256) void k_final(
    const float* __restrict__ klpart, const float* __restrict__ l1part,
    const float* __restrict__ l2part, const float* __restrict__ klw,
    float* __restrict__ out)
{
  __shared__ float sa[4], sb[4], sc2[4];
  float a = 0.f, b2 = 0.f, c = 0.f;
  for (int i = threadIdx.x; i < 1024; i += 256) {
    a += klpart[i]; b2 += l1part[i]; c += l2part[i];
  }
#pragma unroll
  for (int off = 32; off; off >>= 1) {
    a += __shfl_xor(a, off); b2 += __shfl_xor(b2, off); c += __shfl_xor(c, off);
  }
  int w = threadIdx.x >> 6, lane = threadIdx.x & 63;
  if (lane == 0) { sa[w] = a; sb[w] = b2; sc2[w] = c; }
  __syncthreads();
  if (threadIdx.x == 0) {
    float kl = sa[0] + sa[1] + sa[2] + sa[3];
    float l1 = sb[0] + sb[1] + sb[2] + sb[3];
    float l2 = sc2[0] + sc2[1] + sc2[2] + sc2[3];
    out[(size_t)B_ * T_ * D_]     = -0.5f * kl * klw[0];
    out[(size_t)B_ * T_ * D_ + 1] = (l1 + l2) / (float)(B_ * T_ * D_);
  }
}

// ---------------------------------------------------------------------------
extern "C" void kernel_launch(void* const* d_in, const int* in_sizes, int n_in,
                              void* d_out, int out_size, void* d_ws, size_t ws_size,
                              hipStream_t stream)
{
  const float* emb  = (const float*)d_in[0];
  const float* algn = (const float*)d_in[1];
  const float* x    = (const float*)d_in[2];
  const float* klw  = (const float*)d_in[5];
  const float* eps  = (const float*)d_in[6];
  const float* lq   = (const float*)d_in[7];
  const float* inw  = (const float*)d_in[8];
  const float* inb  = (const float*)d_in[9];
  const float* outw = (const float*)d_in[10];
  const float* outb = (const float*)d_in[11];
  const float* lng  = (const float*)d_in[12];
  const float* lnb  = (const float*)d_in[13];
  const float* botw = (const float*)d_in[14];
  const float* botb = (const float*)d_in[15];
  const float* muw  = (const float*)d_in[16];
  const float* mub  = (const float*)d_in[17];
  const float* lvw  = (const float*)d_in[18];
  const float* lvb  = (const float*)d_in[19];
  const float* c1w  = (const float*)d_in[20];
  const float* c1b  = (const float*)d_in[21];
  const float* c2w  = (const float*)d_in[22];
  const float* c2b  = (const float*)d_in[23];
  float* out = (float*)d_out;

  float* ws = (float*)d_ws;
  size_t o = 0;
  auto alloc = [&](size_t n) { float* p = ws + o; o += n; return p; };
  float* kvbuf   = alloc(8192ull * 1024);   // reused for zcT + y1p after attention
  float* queries = alloc(4096ull * 512);
  float* qbuf    = alloc(4096ull * 512);    // reused for qn after attention
  float* ctx     = alloc(4096ull * 512);
  float* attn    = alloc(4096ull * 512);
  float* pooled  = alloc(1024ull * 512);
  float* hidden  = alloc(1024ull * 512);
  float* zbuf    = alloc(1024ull * 64);
  float* w1t     = alloc(512ull * 195);
  float* w2t     = alloc(512ull * 1536);
  float* klpart  = alloc(1024);
  float* l1part  = alloc(1024);
  float* l2part  = alloc(1024);
  int* idx   = (int*)(ws + o); o += 8192;
  int* segst = (int*)(ws + o); o += 1024;
  int* durI  = (int*)(ws + o); o += 1024;
  // sequential aliases (kv is dead after attention; qbuf dead after attention)
  float* qn  = qbuf;
  float* zcT = kvbuf;                // 533,520 floats
  float* y1p = kvbuf + 540000;       // 4,202,496 floats; 540000+4202496 < 8388608

  // segmentation + queries + weight transposes
  k_seg_init<<<dim3((B_ * N_ + 255) / 256), 256, 0, stream>>>(durI, segst);
  k_seg_build<<<dim3(B_ * T_ / 256), 256, 0, stream>>>(algn, idx, durI, segst);
  k_build_queries<<<dim3(B_ * N_ * Q_ * D_ / 256), 256, 0, stream>>>(emb, lq, queries);
  k_w1t<<<dim3((512 * 65 * 3 + 255) / 256), 256, 0, stream>>>(c1w, w1t);
  k_w2t<<<dim3(512 * 512 * 3 / 256), 256, 0, stream>>>(c2w, w2t);

  // projections
  {
    dim3 g(1024 / 64, 8192 / 64);
    k_gemm<0, 0, 0><<<g, 256, 0, stream>>>(x, 512, inw + 512 * 512, inb + 512,
                                           nullptr, kvbuf, 1024, 8192, 1024, 512);
  }
  {
    dim3 g(512 / 64, 4096 / 64);
    k_gemm<0, 0, 0><<<g, 256, 0, stream>>>(queries, 512, inw, inb,
                                           nullptr, qbuf, 512, 4096, 512, 512);
  }

  // attention + out_proj + LN
  k_attn<<<dim3(B_ * N_), 256, 0, stream>>>(qbuf, kvbuf, segst, durI, ctx);
  {
    dim3 g(512 / 64, 4096 / 64);
    k_gemm<0, 0, 0><<<g, 256, 0, stream>>>(ctx, 512, outw, outb,
                                           nullptr, attn, 512, 4096, 512, 512);
  }
  k_ln<<<dim3(1024), 256, 0, stream>>>(queries, attn, lng, lnb, qn);

  // pooling + bottleneck (silu + add pooled)
  k_pool<<<dim3(B_ * N_), 256, 0, stream>>>(x, segst, durI, pooled);
  {
    dim3 g(512 / 64, 1024 / 64);
    k_gemm<2, 0, 0><<<g, 256, 0, stream>>>(qn, 2048, botw, botb,
                                           pooled, hidden, 512, 1024, 512, 2048);
  }

  // VAE + conv input build
  k_muz<<<dim3(B_ * N_), 128, 0, stream>>>(hidden, muw, mub, lvw, lvb, eps, zbuf, klpart);
  k_zc<<<dim3((B_ * (T_ + 2) * 65 + 255) / 256), 256, 0, stream>>>(zbuf, idx, segst, durI, zcT);
  k_zero_pad<<<dim3((B_ * 2 * 512 + 255) / 256), 256, 0, stream>>>(y1p);

  // conv1 (silu) into padded y1p, conv2 into d_out
  {
    dim3 g(512 / 64, 8192 / 64);
    k_gemm<1, 1, 1><<<g, 256, 0, stream>>>(zcT, 65, w1t, c1b,
                                           nullptr, y1p, 512, 8192, 512, 195);
    k_gemm<0, 1, 0><<<g, 256, 0, stream>>>(y1p, 512, w2t, c2b,
                                           nullptr, out, 512, 8192, 512, 1536);
  }

  // losses
  k_loss_part<<<dim3(1024), 256, 0, stream>>>(x, out, l1part, l2part);
  k_final<<<dim3(1), 256, 0, stream>>>(klpart, l1part, l2part, klw, out);
}

// Round 2
// 305.160 us; speedup vs baseline: 3.7652x; 3.7652x over previous
//
#include <hip/hip_runtime.h>
#include <hip/hip_bf16.h>
#include <math.h>

#define B_  8
#define N_  128
#define T_  1024
#define D_  512
#define LD_ 64
#define H_  8
#define Q_  4

typedef __hip_bfloat16 bf16;
typedef __attribute__((ext_vector_type(8))) short short8v;
typedef __attribute__((ext_vector_type(4))) float f32x4;

__device__ __forceinline__ void gload16(const void* g, void* l) {
  __builtin_amdgcn_global_load_lds(
      (const __attribute__((address_space(1))) void*)g,
      (__attribute__((address_space(3))) void*)l, 16, 0, 0);
}

// ---------------------------------------------------------------------------
// segmentation
// ---------------------------------------------------------------------------
__global__ void k_seg_init(int* __restrict__ dur, int* __restrict__ segst) {
  int i = blockIdx.x * blockDim.x + threadIdx.x;
  if (i < B_ * N_) { dur[i] = 0; segst[i] = 0x7fffffff; }
}

__global__ void k_seg_build(const float* __restrict__ align, int* __restrict__ idx,
                            int* __restrict__ dur, int* __restrict__ segst) {
  int gid = blockIdx.x * blockDim.x + threadIdx.x;   // b*T + t
  if (gid >= B_ * T_) return;
  const float* row = align + (size_t)gid * N_;
  int n = 0;
  for (; n < N_; ++n) if (row[n] > 0.5f) break;
  if (n >= N_) n = 0;
  idx[gid] = n;
  int b = gid >> 10, t = gid & 1023;
  atomicAdd(&dur[b * N_ + n], 1);
  atomicMin(&segst[b * N_ + n], t);
}

// ---------------------------------------------------------------------------
// fp32 -> bf16 copy
// ---------------------------------------------------------------------------
__global__ void k_f2b(const float* __restrict__ in, bf16* __restrict__ out, int n) {
  int gid = blockIdx.x * blockDim.x + threadIdx.x;
  if (gid < n) out[gid] = bf16(in[gid]);
}

// queries (bf16) for the q projection
__global__ void k_build_queries(const float* __restrict__ emb, const float* __restrict__ lq,
                                bf16* __restrict__ out) {
  int gid = blockIdx.x * blockDim.x + threadIdx.x;
  if (gid >= B_ * N_ * Q_ * D_) return;
  int d = gid & (D_ - 1);
  int row = gid >> 9;
  int j = row & 3;
  int bn = row >> 2;
  float v = (j == 0) ? emb[(size_t)bn * D_ + d] : lq[(j - 1) * D_ + d];
  out[gid] = bf16(v);
}

// conv weight repacks to bf16 [co][K] matching A-panel k = tap*C + ci
__global__ void k_w1t(const float* __restrict__ w, bf16* __restrict__ wt) {
  int gid = blockIdx.x * blockDim.x + threadIdx.x;
  if (gid >= 512 * 224) return;
  int kk = gid % 224; int c = gid / 224;
  float v = 0.f;
  if (kk < 195) { int tap = kk / 65, i = kk - tap * 65; v = w[c * 195 + i * 3 + tap]; }
  wt[gid] = bf16(v);
}
__global__ void k_w2t(const float* __restrict__ w, bf16* __restrict__ wt) {
  int gid = blockIdx.x * blockDim.x + threadIdx.x;
  if (gid >= 512 * 1536) return;
  int kk = gid % 1536; int co = gid / 1536;
  int tap = kk >> 9, ci = kk & 511;
  wt[gid] = bf16(w[co * 1536 + ci * 3 + tap]);
}

// ---------------------------------------------------------------------------
// bf16 MFMA GEMM: C[m][n] = sum_k A[m][k] * W[n][k] + bias[n]
// 128x128 tile, BK=32, 4 waves (2x2), 16x16x32 MFMA, global_load_lds staging.
//   EPI: 0 none, 1 silu, 2 silu + extra[m*Nc+n]
//   APAD: A physical row = m + 2*(m>>10)   (padded [B][T+2][*] buffers)
//   CMODE: 0 C row = m; 1 C row = m + 2*(m>>10) + 1
// M % 128 == 0, Nc % 128 == 0, K % 32 == 0 required.
// ---------------------------------------------------------------------------
template<int EPI, int APAD, int CMODE, typename CT>
__global__ __launch_bounds__(256) void k_mgemm(
    const bf16* __restrict__ A, int lda,
    const bf16* __restrict__ W, int ldw,
    const float* __restrict__ bias,
    const float* __restrict__ extra,
    CT* __restrict__ C, int ldc,
    int M, int Nc, int K)
{
  __shared__ __align__(16) short As[128 * 32];
  __shared__ __align__(16) short Bs[128 * 32];
  const int tid = threadIdx.x;
  const int m0 = blockIdx.y * 128;
  const int n0 = blockIdx.x * 128;
  const int w = tid >> 6, lane = tid & 63;
  const int wm = (w >> 1) * 64, wn = (w & 1) * 64;
  const int lr = lane & 15, lk = (lane >> 4) * 8;

  // staging geometry: thread t -> LDS byte t*16 (row t>>2, kcol (t&3)*8)
  const int r = tid >> 2;
  const int kc = (tid & 3) * 8;
  int gmA0 = m0 + r, gmA1 = m0 + r + 64;
  int ar0 = APAD ? gmA0 + ((gmA0 >> 10) << 1) : gmA0;
  int ar1 = APAD ? gmA1 + ((gmA1 >> 10) << 1) : gmA1;
  const size_t aOff0 = (size_t)ar0 * lda + kc;
  const size_t aOff1 = (size_t)ar1 * lda + kc;
  const size_t wOff0 = (size_t)(n0 + r) * ldw + kc;
  const size_t wOff1 = (size_t)(n0 + r + 64) * ldw + kc;

  f32x4 acc[4][4] = {};

  for (int kt = 0; kt < K; kt += 32) {
    gload16(A + aOff0 + kt, As + tid * 8);
    gload16(A + aOff1 + kt, As + 2048 + tid * 8);
    gload16(W + wOff0 + kt, Bs + tid * 8);
    gload16(W + wOff1 + kt, Bs + 2048 + tid * 8);
    asm volatile("s_waitcnt vmcnt(0)" ::: "memory");
    __syncthreads();
    short8v af[4], bfv[4];
#pragma unroll
    for (int i = 0; i < 4; ++i)
      af[i] = *(const short8v*)&As[(wm + i * 16 + lr) * 32 + lk];
#pragma unroll
    for (int j = 0; j < 4; ++j)
      bfv[j] = *(const short8v*)&Bs[(wn + j * 16 + lr) * 32 + lk];
#pragma unroll
    for (int i = 0; i < 4; ++i)
#pragma unroll
      for (int j = 0; j < 4; ++j)
        acc[i][j] = __builtin_amdgcn_mfma_f32_16x16x32_bf16(af[i], bfv[j], acc[i][j], 0, 0, 0);
    __syncthreads();
  }

  // epilogue: C/D layout col=lane&15, row=(lane>>4)*4+q
  const int orow = (lane >> 4) * 4;
  const int ocol = lane & 15;
#pragma unroll
  for (int i = 0; i < 4; ++i) {
#pragma unroll
    for (int q = 0; q < 4; ++q) {
      int gm = m0 + wm + i * 16 + orow + q;
      int cr = CMODE ? gm + ((gm >> 10) << 1) + 1 : gm;
#pragma unroll
      for (int j = 0; j < 4; ++j) {
        int gn = n0 + wn + j * 16 + ocol;
        float v = acc[i][j][q] + bias[gn];
        if (EPI >= 1) v = v / (1.f + __expf(-v));
        if (EPI == 2) v += extra[(size_t)gm * Nc + gn];
        C[(size_t)cr * ldc + gn] = (CT)v;
      }
    }
  }
}

// ---------------------------------------------------------------------------
// per-(b,n) segment attention (bf16 q/k/v, fp32 math, bf16 ctx out)
// kv layout: [b*T+t][1024] (k: 0..511, v: 512..1023)
// ---------------------------------------------------------------------------
__global__ __launch_bounds__(256) void k_attn(
    const bf16* __restrict__ qbuf, const bf16* __restrict__ kv,
    const int* __restrict__ segst, const int* __restrict__ dur,
    bf16* __restrict__ ctx)
{
  __shared__ float q_sh[4][64];
  __shared__ float sc[4][T_];
  int bn = blockIdx.x;
  int b = bn >> 7;
  int w = threadIdx.x >> 6;
  int lane = threadIdx.x & 63;
  int s0 = segst[bn], cnt = dur[bn];
  if (cnt == 0) { s0 = 0; cnt = T_; }
  size_t qrow = (size_t)bn * 4 + w;
  const bf16* kvb = kv + (size_t)b * T_ * 1024;
  for (int h = 0; h < H_; ++h) {
    q_sh[w][lane] = __bfloat162float(qbuf[qrow * D_ + h * 64 + lane]);
    __syncthreads();
    float lmax = -1e30f;
    for (int s = lane; s < cnt; s += 64) {
      const bf16* kr = kvb + (size_t)(s0 + s) * 1024 + h * 64;
      float a = 0.f;
#pragma unroll
      for (int d = 0; d < 64; ++d) a = fmaf(q_sh[w][d], __bfloat162float(kr[d]), a);
      a *= 0.125f;
      sc[w][s] = a;
      lmax = fmaxf(lmax, a);
    }
#pragma unroll
    for (int off = 32; off; off >>= 1) lmax = fmaxf(lmax, __shfl_xor(lmax, off));
    float lsum = 0.f;
    for (int s = lane; s < cnt; s += 64) {
      float p = expf(sc[w][s] - lmax);
      sc[w][s] = p;
      lsum += p;
    }
#pragma unroll
    for (int off = 32; off; off >>= 1) lsum += __shfl_xor(lsum, off);
    __syncthreads();
    float o = 0.f;
    const bf16* vb = kvb + 512 + h * 64 + lane;
    for (int s = 0; s < cnt; ++s)
      o = fmaf(sc[w][s], __bfloat162float(vb[(size_t)(s0 + s) * 1024]), o);
    ctx[qrow * D_ + h * 64 + lane] = bf16(o / lsum);
    __syncthreads();
  }
}

// ---------------------------------------------------------------------------
// layernorm of (queries + attn_out) -> bf16 qn
// ---------------------------------------------------------------------------
__global__ __launch_bounds__(256) void k_ln(
    const float* __restrict__ emb, const float* __restrict__ lq,
    const float* __restrict__ attn,
    const float* __restrict__ g, const float* __restrict__ bb,
    bf16* __restrict__ qn)
{
  int r = blockIdx.x * 4 + (threadIdx.x >> 6);
  int lane = threadIdx.x & 63;
  int bn = r >> 2, j = r & 3;
  const float* src = (j == 0) ? emb + (size_t)bn * D_ : lq + (size_t)(j - 1) * D_;
  float h[8];
  float s = 0.f, s2 = 0.f;
#pragma unroll
  for (int i = 0; i < 8; ++i) {
    int d = i * 64 + lane;
    float v = src[d] + attn[(size_t)r * D_ + d];
    h[i] = v; s += v; s2 += v * v;
  }
#pragma unroll
  for (int off = 32; off; off >>= 1) { s += __shfl_xor(s, off); s2 += __shfl_xor(s2, off); }
  float mean = s * (1.f / 512.f);
  float var = s2 * (1.f / 512.f) - mean * mean;
  float inv = rsqrtf(var + 1e-5f);
#pragma unroll
  for (int i = 0; i < 8; ++i) {
    int d = i * 64 + lane;
    qn[(size_t)r * D_ + d] = bf16((h[i] - mean) * inv * g[d] + bb[d]);
  }
}

// ---------------------------------------------------------------------------
// pooled[b,n,d] = segment mean of x
// ---------------------------------------------------------------------------
__global__ __launch_bounds__(256) void k_pool(
    const float* __restrict__ x, const int* __restrict__ segst,
    const int* __restrict__ dur, float* __restrict__ pooled)
{
  int bn = blockIdx.x;
  int b = bn >> 7;
  int s0 = segst[bn], cnt = dur[bn];
  int d0 = threadIdx.x;
  float a0 = 0.f, a1 = 0.f;
  for (int i = 0; i < cnt; ++i) {
    const float* xr = x + (size_t)(b * T_ + s0 + i) * D_;
    a0 += xr[d0];
    a1 += xr[d0 + 256];
  }
  float inv = 1.f / ((float)cnt + 1e-8f);
  pooled[(size_t)bn * D_ + d0] = a0 * inv;
  pooled[(size_t)bn * D_ + d0 + 256] = a1 * inv;
}

// ---------------------------------------------------------------------------
// mu/logvar/z + KL partial
// ---------------------------------------------------------------------------
__global__ __launch_bounds__(128) void k_muz(
    const float* __restrict__ hidden,
    const float* __restrict__ mu_w, const float* __restrict__ mu_b,
    const float* __restrict__ lv_w, const float* __restrict__ lv_b,
    const float* __restrict__ eps, float* __restrict__ z, float* __restrict__ klpart)
{
  __shared__ float hs[512];
  __shared__ float ms[64], ls[64];
  int bn = blockIdx.x;
  int tid = threadIdx.x;
  for (int i = tid; i < 512; i += 128) hs[i] = hidden[(size_t)bn * 512 + i];
  __syncthreads();
  int ld = tid & 63;
  const float* wrow = (tid < 64) ? (mu_w + (size_t)ld * 512) : (lv_w + (size_t)ld * 512);
  float acc = 0.f;
  for (int k = 0; k < 512; ++k) acc = fmaf(hs[k], wrow[k], acc);
  acc += (tid < 64) ? mu_b[ld] : lv_b[ld];
  if (tid < 64) ms[ld] = acc; else ls[ld] = acc;
  __syncthreads();
  if (tid < 64) {
    float mu = ms[ld], lv = ls[ld];
    z[(size_t)bn * 64 + ld] = mu + eps[(size_t)bn * 64 + ld] * expf(0.5f * lv);
    float klt = 1.f + lv - mu * mu - expf(lv);
#pragma unroll
    for (int off = 32; off; off >>= 1) klt += __shfl_xor(klt, off);
    if (ld == 0) klpart[bn] = klt;
  }
}

// ---------------------------------------------------------------------------
// im2col A for conv1: azc bf16 [8192][224], k = tap*65 + c, zero-padded
// ---------------------------------------------------------------------------
__global__ void k_azc(const float* __restrict__ z, const int* __restrict__ idx,
                      const int* __restrict__ segst, const int* __restrict__ dur,
                      bf16* __restrict__ azc)
{
  int gid = blockIdx.x * blockDim.x + threadIdx.x;
  if (gid >= 8192 * 224) return;
  int k = gid % 224;
  int m = gid / 224;
  int b = m >> 10, t = m & 1023;
  float v = 0.f;
  if (k < 195) {
    int tap = k / 65, c = k - tap * 65;
    int tt = t + tap - 1;
    if (tt >= 0 && tt < T_) {
      int iv = idx[b * T_ + tt];
      if (c < 64) v = z[(size_t)(b * N_ + iv) * 64 + c];
      else {
        int s0 = segst[b * N_ + iv];
        float d = (float)dur[b * N_ + iv];
        v = ((float)(tt - s0) + 0.5f) / d;
      }
    }
  }
  azc[gid] = bf16(v);
}

// zero pad rows of y1p (bf16)
__global__ void k_zero_pad(bf16* __restrict__ y1p) {
  int gid = blockIdx.x * blockDim.x + threadIdx.x;
  if (gid >= B_ * 2 * 512) return;
  int d = gid & 511;
  int rest = gid >> 9;
  int which = rest & 1;
  int b = rest >> 1;
  int rr = which ? (T_ + 1) : 0;
  y1p[(size_t)(b * (T_ + 2) + rr) * 512 + d] = bf16(0.f);
}

// ---------------------------------------------------------------------------
// losses
// ---------------------------------------------------------------------------
__global__ __launch_bounds__(256) void k_loss_part(
    const float* __restrict__ x, const float* __restrict__ xr,
    float* __restrict__ l1part, float* __restrict__ l2part)
{
  __shared__ float sh1[4], sh2[4];
  float a = 0.f, b2 = 0.f;
  const int total = B_ * T_ * D_;
  for (int i = blockIdx.x * blockDim.x + threadIdx.x; i < total; i += gridDim.x * blockDim.x) {
    float d = x[i] - xr[i];
    a += fabsf(d);
    b2 += d * d;
  }
#pragma unroll
  for (int off = 32; off; off >>= 1) { a += __shfl_xor(a, off); b2 += __shfl_xor(b2, off); }
  int w = threadIdx.x >> 6, lane = threadIdx.x & 63;
  if (lane == 0) { sh1[w] = a; sh2[w] = b2; }
  __syncthreads();
  if (threadIdx.x == 0) {
    l1part[blockIdx.x] = sh1[0] + sh1[1] + sh1[2] + sh1[3];
    l2part[blockIdx.x] = sh2[0] + sh2[1] + sh2[2] + sh2[3];
  }
}

__global__ __launch_bounds__(256) void k_final(
    const float* __restrict__ klpart, const float* __restrict__ l1part,
    const float* __restrict__ l2part, const float* __restrict__ klw,
    float* __restrict__ out)
{
  __shared__ float sa[4], sb[4], sc2[4];
  float a = 0.f, b2 = 0.f, c = 0.f;
  for (int i = threadIdx.x; i < 1024; i += 256) {
    a += klpart[i]; b2 += l1part[i]; c += l2part[i];
  }
#pragma unroll
  for (int off = 32; off; off >>= 1) {
    a += __shfl_xor(a, off); b2 += __shfl_xor(b2, off); c += __shfl_xor(c, off);
  }
  int w = threadIdx.x >> 6, lane = threadIdx.x & 63;
  if (lane == 0) { sa[w] = a; sb[w] = b2; sc2[w] = c; }
  __syncthreads();
  if (threadIdx.x == 0) {
    float kl = sa[0] + sa[1] + sa[2] + sa[3];
    float l1 = sb[0] + sb[1] + sb[2] + sb[3];
    float l2 = sc2[0] + sc2[1] + sc2[2] + sc2[3];
    out[(size_t)B_ * T_ * D_]     = -0.5f * kl * klw[0];
    out[(size_t)B_ * T_ * D_ + 1] = (l1 + l2) / (float)(B_ * T_ * D_);
  }
}

// ---------------------------------------------------------------------------
extern "C" void kernel_launch(void* const* d_in, const int* in_sizes, int n_in,
                              void* d_out, int out_size, void* d_ws, size_t ws_size,
                              hipStream_t stream)
{
  const float* emb  = (const float*)d_in[0];
  const float* algn = (const float*)d_in[1];
  const float* x    = (const float*)d_in[2];
  const float* klw  = (const float*)d_in[5];
  const float* eps  = (const float*)d_in[6];
  const float* lq   = (const float*)d_in[7];
  const float* inw  = (const float*)d_in[8];
  const float* inb  = (const float*)d_in[9];
  const float* outw = (const float*)d_in[10];
  const float* outb = (const float*)d_in[11];
  const float* lng  = (const float*)d_in[12];
  const float* lnb  = (const float*)d_in[13];
  const float* botw = (const float*)d_in[14];
  const float* botb = (const float*)d_in[15];
  const float* muw  = (const float*)d_in[16];
  const float* mub  = (const float*)d_in[17];
  const float* lvw  = (const float*)d_in[18];
  const float* lvb  = (const float*)d_in[19];
  const float* c1w  = (const float*)d_in[20];
  const float* c1b  = (const float*)d_in[21];
  const float* c2w  = (const float*)d_in[22];
  const float* c2b  = (const float*)d_in[23];
  float* out = (float*)d_out;

  float* ws = (float*)d_ws;
  size_t o = 0;
  auto allocF = [&](size_t n) { float* p = ws + o; o += n; return p; };
  auto allocB = [&](size_t n) { bf16* p = (bf16*)(ws + o); o += (n + 1) / 2; return p; };

  bf16* kvB    = allocB(8192ull * 1024);
  bf16* xb     = allocB(8192ull * 512);
  bf16* qryB   = allocB(4096ull * 512);
  bf16* qbufB  = allocB(4096ull * 512);
  bf16* ctxB   = allocB(4096ull * 512);
  bf16* qnB    = allocB(4096ull * 512);
  bf16* inwb   = allocB(1536ull * 512);
  bf16* outwb  = allocB(512ull * 512);
  bf16* botwb  = allocB(512ull * 2048);
  bf16* w1tb   = allocB(512ull * 224);
  bf16* w2tb   = allocB(512ull * 1536);
  bf16* azc    = allocB(8192ull * 224);
  bf16* y1p    = allocB(8ull * (T_ + 2) * 512);
  float* attnF  = allocF(4096ull * 512);
  float* pooled = allocF(1024ull * 512);
  float* hidden = allocF(1024ull * 512);
  float* zbuf   = allocF(1024ull * 64);
  float* klpart = allocF(1024);
  float* l1part = allocF(1024);
  float* l2part = allocF(1024);
  int* idx   = (int*)(ws + o); o += 8192;
  int* segst = (int*)(ws + o); o += 1024;
  int* durI  = (int*)(ws + o); o += 1024;

  // segmentation + conversions + repacks
  k_seg_init<<<dim3((B_ * N_ + 255) / 256), 256, 0, stream>>>(durI, segst);
  k_seg_build<<<dim3(B_ * T_ / 256), 256, 0, stream>>>(algn, idx, durI, segst);
  k_f2b<<<dim3(8192 * 512 / 256), 256, 0, stream>>>(x, xb, 8192 * 512);
  k_f2b<<<dim3(1536 * 512 / 256), 256, 0, stream>>>(inw, inwb, 1536 * 512);
  k_f2b<<<dim3(512 * 512 / 256), 256, 0, stream>>>(outw, outwb, 512 * 512);
  k_f2b<<<dim3(512 * 2048 / 256), 256, 0, stream>>>(botw, botwb, 512 * 2048);
  k_w1t<<<dim3(512 * 224 / 256), 256, 0, stream>>>(c1w, w1tb);
  k_w2t<<<dim3(512 * 1536 / 256), 256, 0, stream>>>(c2w, w2tb);
  k_build_queries<<<dim3(B_ * N_ * Q_ * D_ / 256), 256, 0, stream>>>(emb, lq, qryB);

  // kv projection: [8192,512] x [1024,512]^T -> bf16 [8192,1024]
  k_mgemm<0, 0, 0, bf16><<<dim3(8, 64), 256, 0, stream>>>(
      xb, 512, inwb + 512 * 512, 512, inb + 512, nullptr, kvB, 1024, 8192, 1024, 512);
  // q projection: [4096,512] x [512,512]^T -> bf16
  k_mgemm<0, 0, 0, bf16><<<dim3(4, 32), 256, 0, stream>>>(
      qryB, 512, inwb, 512, inb, nullptr, qbufB, 512, 4096, 512, 512);

  k_attn<<<dim3(B_ * N_), 256, 0, stream>>>(qbufB, kvB, segst, durI, ctxB);

  // out projection -> fp32 attnF
  k_mgemm<0, 0, 0, float><<<dim3(4, 32), 256, 0, stream>>>(
      ctxB, 512, outwb, 512, outb, nullptr, attnF, 512, 4096, 512, 512);

  k_ln<<<dim3(1024), 256, 0, stream>>>(emb, lq, attnF, lng, lnb, qnB);
  k_pool<<<dim3(B_ * N_), 256, 0, stream>>>(x, segst, durI, pooled);

  // bottleneck: [1024,2048] x [512,2048]^T, silu + pooled -> fp32 hidden
  k_mgemm<2, 0, 0, float><<<dim3(4, 8), 256, 0, stream>>>(
      qnB, 2048, botwb, 2048, botb, pooled, hidden, 512, 1024, 512, 2048);

  k_muz<<<dim3(B_ * N_), 128, 0, stream>>>(hidden, muw, mub, lvw, lvb, eps, zbuf, klpart);
  k_azc<<<dim3(8192 * 224 / 256), 256, 0, stream>>>(zbuf, idx, segst, durI, azc);
  k_zero_pad<<<dim3((B_ * 2 * 512 + 255) / 256), 256, 0, stream>>>(y1p);

  // conv1: [8192,224] x [512,224]^T, silu -> bf16 y1p (padded rows, CMODE=1)
  k_mgemm<1, 0, 1, bf16><<<dim3(4, 64), 256, 0, stream>>>(
      azc, 224, w1tb, 224, c1b, nullptr, y1p, 512, 8192, 512, 224);
  // conv2: padded A (APAD=1), K=1536 -> fp32 out
  k_mgemm<0, 1, 0, float><<<dim3(4, 64), 256, 0, stream>>>(
      y1p, 512, w2tb, 1536, c2b, nullptr, out, 512, 8192, 512, 1536);

  k_loss_part<<<dim3(1024), 256, 0, stream>>>(x, out, l1part, l2part);
  k_final<<<dim3(1), 256, 0, stream>>>(klpart, l1part, l2part, klw, out);
}

// Round 3
// 246.027 us; speedup vs baseline: 4.6702x; 1.2404x over previous
//
#include <hip/hip_runtime.h>
#include <hip/hip_bf16.h>
#include <math.h>

#define B_  8
#define N_  128
#define T_  1024
#define D_  512
#define LD_ 64
#define H_  8
#define Q_  4

typedef __hip_bfloat16 bf16;
typedef __attribute__((ext_vector_type(8))) short short8v;
typedef __attribute__((ext_vector_type(4))) float f32x4;
typedef __attribute__((ext_vector_type(4))) float float4v;

__device__ __forceinline__ void gload16(const void* g, void* l) {
  __builtin_amdgcn_global_load_lds(
      (const __attribute__((address_space(1))) void*)g,
      (__attribute__((address_space(3))) void*)l, 16, 0, 0);
}

// ---------------------------------------------------------------------------
// segmentation: wave-per-row ballot scan
// ---------------------------------------------------------------------------
__global__ void k_seg_init(int* __restrict__ dur, int* __restrict__ segst) {
  int i = blockIdx.x * blockDim.x + threadIdx.x;
  if (i < B_ * N_) { dur[i] = 0; segst[i] = 0x7fffffff; }
}

__global__ __launch_bounds__(256) void k_seg_build(
    const float* __restrict__ align, int* __restrict__ idx,
    int* __restrict__ dur, int* __restrict__ segst) {
  int row = blockIdx.x * 4 + (threadIdx.x >> 6);    // b*T + t
  int lane = threadIdx.x & 63;
  const float* r = align + (size_t)row * N_;
  unsigned long long m0 = __ballot(r[lane] > 0.5f);
  unsigned long long m1 = __ballot(r[lane + 64] > 0.5f);
  if (lane == 0) {
    int n = m0 ? (__ffsll(m0) - 1) : (m1 ? (__ffsll(m1) - 1 + 64) : 0);
    idx[row] = n;
    int b = row >> 10, t = row & 1023;
    atomicAdd(&dur[b * N_ + n], 1);
    atomicMin(&segst[b * N_ + n], t);
  }
}

// ---------------------------------------------------------------------------
// fp32 -> bf16, 4 elems/thread
// ---------------------------------------------------------------------------
__global__ void k_f2b4(const float* __restrict__ in, bf16* __restrict__ out, int n4) {
  int gid = blockIdx.x * blockDim.x + threadIdx.x;
  if (gid >= n4) return;
  float4v v = *(const float4v*)(in + (size_t)gid * 4);
  bf16 o[4] = {bf16(v.x), bf16(v.y), bf16(v.z), bf16(v.w)};
  *(ulong1*)(out + (size_t)gid * 4) = *(ulong1*)o;
}

__global__ void k_build_queries(const float* __restrict__ emb, const float* __restrict__ lq,
                                bf16* __restrict__ out) {
  int gid = blockIdx.x * blockDim.x + threadIdx.x;
  if (gid >= B_ * N_ * Q_ * D_) return;
  int d = gid & (D_ - 1);
  int row = gid >> 9;
  int j = row & 3;
  int bn = row >> 2;
  float v = (j == 0) ? emb[(size_t)bn * D_ + d] : lq[(j - 1) * D_ + d];
  out[gid] = bf16(v);
}

// conv weight repacks to bf16 [co][K] matching A-panel k = tap*C + ci
__global__ void k_w1t(const float* __restrict__ w, bf16* __restrict__ wt) {
  int gid = blockIdx.x * blockDim.x + threadIdx.x;
  if (gid >= 512 * 224) return;
  int kk = gid % 224; int c = gid / 224;
  float v = 0.f;
  if (kk < 195) { int tap = kk / 65, i = kk - tap * 65; v = w[c * 195 + i * 3 + tap]; }
  wt[gid] = bf16(v);
}
__global__ void k_w2t(const float* __restrict__ w, bf16* __restrict__ wt) {
  int gid = blockIdx.x * blockDim.x + threadIdx.x;
  if (gid >= 512 * 1536) return;
  int kk = gid % 1536; int co = gid / 1536;
  int tap = kk >> 9, ci = kk & 511;
  wt[gid] = bf16(w[co * 1536 + ci * 3 + tap]);
}

// ---------------------------------------------------------------------------
// bf16 MFMA GEMM, 128x128 tile, BK=32, depth-3 pipelined global_load_lds.
//   EPI: 0 none, 1 silu, 3 raw partial (split-K, no bias)
//   APAD: A physical row = m + 2*(m>>10); CMODE: C row = m + 2*(m>>10) + 1
// grid.z = split-K chunks (K = chunk length). M%128==0, Nc%128==0, K%32==0.
// ---------------------------------------------------------------------------
template<int EPI, int APAD, int CMODE, typename CT>
__global__ __launch_bounds__(256) void k_mgemm(
    const bf16* __restrict__ A, int lda,
    const bf16* __restrict__ W, int ldw,
    const float* __restrict__ bias,
    CT* __restrict__ C, int ldc,
    int M, int Nc, int K)
{
  __shared__ __align__(16) short As[3][4096];
  __shared__ __align__(16) short Bs[3][4096];
  const int tid = threadIdx.x;
  const int m0 = blockIdx.y * 128;
  const int n0 = blockIdx.x * 128;
  const int kz = blockIdx.z;
  const int kbase = kz * K;
  const int w = tid >> 6, lane = tid & 63;
  const int wm = (w >> 1) * 64, wn = (w & 1) * 64;
  const int lr = lane & 15, lk = (lane >> 4) * 8;

  // staging geometry: thread t -> LDS shorts [t*8, t*8+8)
  const int r = tid >> 2;
  const int kc = (tid & 3) * 8;
  int gmA0 = m0 + r, gmA1 = m0 + r + 64;
  int ar0 = APAD ? gmA0 + ((gmA0 >> 10) << 1) : gmA0;
  int ar1 = APAD ? gmA1 + ((gmA1 >> 10) << 1) : gmA1;
  const size_t aOff0 = (size_t)ar0 * lda + kc + kbase;
  const size_t aOff1 = (size_t)ar1 * lda + kc + kbase;
  const size_t wOff0 = (size_t)(n0 + r) * ldw + kc + kbase;
  const size_t wOff1 = (size_t)(n0 + r + 64) * ldw + kc + kbase;

  const int nt = K >> 5;

  // prologue: stage tiles 0,1
  gload16(A + aOff0, &As[0][tid * 8]);
  gload16(A + aOff1, &As[0][2048 + tid * 8]);
  gload16(W + wOff0, &Bs[0][tid * 8]);
  gload16(W + wOff1, &Bs[0][2048 + tid * 8]);
  if (nt > 1) {
    gload16(A + aOff0 + 32, &As[1][tid * 8]);
    gload16(A + aOff1 + 32, &As[1][2048 + tid * 8]);
    gload16(W + wOff0 + 32, &Bs[1][tid * 8]);
    gload16(W + wOff1 + 32, &Bs[1][2048 + tid * 8]);
  }

  f32x4 acc[4][4] = {};
  int cur = 0;
  for (int t = 0; t < nt; ++t) {
    if (t + 2 < nt) {
      int b2 = cur + 2; if (b2 >= 3) b2 -= 3;
      size_t kk = (size_t)(t + 2) * 32;
      gload16(A + aOff0 + kk, &As[b2][tid * 8]);
      gload16(A + aOff1 + kk, &As[b2][2048 + tid * 8]);
      gload16(W + wOff0 + kk, &Bs[b2][tid * 8]);
      gload16(W + wOff1 + kk, &Bs[b2][2048 + tid * 8]);
      asm volatile("s_waitcnt vmcnt(8)" ::: "memory");
    } else if (t + 1 < nt) {
      asm volatile("s_waitcnt vmcnt(4)" ::: "memory");
    } else {
      asm volatile("s_waitcnt vmcnt(0)" ::: "memory");
    }
    __builtin_amdgcn_sched_barrier(0);
    __builtin_amdgcn_s_barrier();
    __builtin_amdgcn_sched_barrier(0);
    short8v af[4], bfv[4];
#pragma unroll
    for (int i = 0; i < 4; ++i)
      af[i] = *(const short8v*)&As[cur][(wm + i * 16 + lr) * 32 + lk];
#pragma unroll
    for (int j = 0; j < 4; ++j)
      bfv[j] = *(const short8v*)&Bs[cur][(wn + j * 16 + lr) * 32 + lk];
#pragma unroll
    for (int i = 0; i < 4; ++i)
#pragma unroll
      for (int j = 0; j < 4; ++j)
        acc[i][j] = __builtin_amdgcn_mfma_f32_16x16x32_bf16(af[i], bfv[j], acc[i][j], 0, 0, 0);
    __builtin_amdgcn_sched_barrier(0);
    __builtin_amdgcn_s_barrier();
    __builtin_amdgcn_sched_barrier(0);
    cur = (cur == 2) ? 0 : cur + 1;
  }

  if (EPI == 3) C += (size_t)kz * M * ldc;
  const int orow = (lane >> 4) * 4;
  const int ocol = lane & 15;
#pragma unroll
  for (int i = 0; i < 4; ++i) {
#pragma unroll
    for (int q = 0; q < 4; ++q) {
      int gm = m0 + wm + i * 16 + orow + q;
      int cr = CMODE ? gm + ((gm >> 10) << 1) + 1 : gm;
#pragma unroll
      for (int j = 0; j < 4; ++j) {
        int gn = n0 + wn + j * 16 + ocol;
        float v = acc[i][j][q];
        if (EPI != 3) v += bias[gn];
        if (EPI == 1) v = v / (1.f + __expf(-v));
        C[(size_t)cr * ldc + gn] = (CT)v;
      }
    }
  }
}

// split-K epilogue for bottleneck: sum 4 partials + bias, silu, + pooled
__global__ __launch_bounds__(256) void k_bot_epi(
    const float* __restrict__ part, const float* __restrict__ bias,
    const float* __restrict__ pooled, float* __restrict__ hidden) {
  int gid = blockIdx.x * blockDim.x + threadIdx.x;
  if (gid >= 1024 * 512) return;
  int n = gid & 511;
  const size_t S = 1024ull * 512;
  float v = part[gid] + part[gid + S] + part[gid + 2 * S] + part[gid + 3 * S] + bias[n];
  v = v / (1.f + __expf(-v));
  hidden[gid] = v + pooled[gid];
}

// ---------------------------------------------------------------------------
// per-(b,n) segment attention (bf16 q/k/v, fp32 math, bf16 ctx out)
// ---------------------------------------------------------------------------
__global__ __launch_bounds__(256) void k_attn(
    const bf16* __restrict__ qbuf, const bf16* __restrict__ kv,
    const int* __restrict__ segst, const int* __restrict__ dur,
    bf16* __restrict__ ctx)
{
  __shared__ float q_sh[4][64];
  __shared__ float sc[4][T_];
  int bn = blockIdx.x;
  int b = bn >> 7;
  int w = threadIdx.x >> 6;
  int lane = threadIdx.x & 63;
  int s0 = segst[bn], cnt = dur[bn];
  if (cnt == 0) { s0 = 0; cnt = T_; }
  size_t qrow = (size_t)bn * 4 + w;
  const bf16* kvb = kv + (size_t)b * T_ * 1024;
  for (int h = 0; h < H_; ++h) {
    q_sh[w][lane] = __bfloat162float(qbuf[qrow * D_ + h * 64 + lane]);
    __syncthreads();
    float lmax = -1e30f;
    for (int s = lane; s < cnt; s += 64) {
      const bf16* kr = kvb + (size_t)(s0 + s) * 1024 + h * 64;
      float a = 0.f;
#pragma unroll
      for (int d = 0; d < 64; ++d) a = fmaf(q_sh[w][d], __bfloat162float(kr[d]), a);
      a *= 0.125f;
      sc[w][s] = a;
      lmax = fmaxf(lmax, a);
    }
#pragma unroll
    for (int off = 32; off; off >>= 1) lmax = fmaxf(lmax, __shfl_xor(lmax, off));
    float lsum = 0.f;
    for (int s = lane; s < cnt; s += 64) {
      float p = expf(sc[w][s] - lmax);
      sc[w][s] = p;
      lsum += p;
    }
#pragma unroll
    for (int off = 32; off; off >>= 1) lsum += __shfl_xor(lsum, off);
    __syncthreads();
    float o = 0.f;
    const bf16* vb = kvb + 512 + h * 64 + lane;
    for (int s = 0; s < cnt; ++s)
      o = fmaf(sc[w][s], __bfloat162float(vb[(size_t)(s0 + s) * 1024]), o);
    ctx[qrow * D_ + h * 64 + lane] = bf16(o / lsum);
    __syncthreads();
  }
}

// ---------------------------------------------------------------------------
// layernorm of (queries + attn_out) -> bf16 qn
// ---------------------------------------------------------------------------
__global__ __launch_bounds__(256) void k_ln(
    const float* __restrict__ emb, const float* __restrict__ lq,
    const float* __restrict__ attn,
    const float* __restrict__ g, const float* __restrict__ bb,
    bf16* __restrict__ qn)
{
  int r = blockIdx.x * 4 + (threadIdx.x >> 6);
  int lane = threadIdx.x & 63;
  int bn = r >> 2, j = r & 3;
  const float* src = (j == 0) ? emb + (size_t)bn * D_ : lq + (size_t)(j - 1) * D_;
  float h[8];
  float s = 0.f, s2 = 0.f;
#pragma unroll
  for (int i = 0; i < 8; ++i) {
    int d = i * 64 + lane;
    float v = src[d] + attn[(size_t)r * D_ + d];
    h[i] = v; s += v; s2 += v * v;
  }
#pragma unroll
  for (int off = 32; off; off >>= 1) { s += __shfl_xor(s, off); s2 += __shfl_xor(s2, off); }
  float mean = s * (1.f / 512.f);
  float var = s2 * (1.f / 512.f) - mean * mean;
  float inv = rsqrtf(var + 1e-5f);
#pragma unroll
  for (int i = 0; i < 8; ++i) {
    int d = i * 64 + lane;
    qn[(size_t)r * D_ + d] = bf16((h[i] - mean) * inv * g[d] + bb[d]);
  }
}

// ---------------------------------------------------------------------------
// pooled[b,n,d] = segment mean of x
// ---------------------------------------------------------------------------
__global__ __launch_bounds__(256) void k_pool(
    const float* __restrict__ x, const int* __restrict__ segst,
    const int* __restrict__ dur, float* __restrict__ pooled)
{
  int bn = blockIdx.x;
  int b = bn >> 7;
  int s0 = segst[bn], cnt = dur[bn];
  int d0 = threadIdx.x;
  float a0 = 0.f, a1 = 0.f;
  for (int i = 0; i < cnt; ++i) {
    const float* xr = x + (size_t)(b * T_ + s0 + i) * D_;
    a0 += xr[d0];
    a1 += xr[d0 + 256];
  }
  float inv = 1.f / ((float)cnt + 1e-8f);
  pooled[(size_t)bn * D_ + d0] = a0 * inv;
  pooled[(size_t)bn * D_ + d0 + 256] = a1 * inv;
}

// ---------------------------------------------------------------------------
// mu/logvar/z + KL partial
// ---------------------------------------------------------------------------
__global__ __launch_bounds__(128) void k_muz(
    const float* __restrict__ hidden,
    const float* __restrict__ mu_w, const float* __restrict__ mu_b,
    const float* __restrict__ lv_w, const float* __restrict__ lv_b,
    const float* __restrict__ eps, float* __restrict__ z, float* __restrict__ klpart)
{
  __shared__ float hs[512];
  __shared__ float ms[64], ls[64];
  int bn = blockIdx.x;
  int tid = threadIdx.x;
  for (int i = tid; i < 512; i += 128) hs[i] = hidden[(size_t)bn * 512 + i];
  __syncthreads();
  int ld = tid & 63;
  const float* wrow = (tid < 64) ? (mu_w + (size_t)ld * 512) : (lv_w + (size_t)ld * 512);
  float acc = 0.f;
  for (int k = 0; k < 512; ++k) acc = fmaf(hs[k], wrow[k], acc);
  acc += (tid < 64) ? mu_b[ld] : lv_b[ld];
  if (tid < 64) ms[ld] = acc; else ls[ld] = acc;
  __syncthreads();
  if (tid < 64) {
    float mu = ms[ld], lv = ls[ld];
    z[(size_t)bn * 64 + ld] = mu + eps[(size_t)bn * 64 + ld] * expf(0.5f * lv);
    float klt = 1.f + lv - mu * mu - expf(lv);
#pragma unroll
    for (int off = 32; off; off >>= 1) klt += __shfl_xor(klt, off);
    if (ld == 0) klpart[bn] = klt;
  }
}

// ---------------------------------------------------------------------------
// im2col A for conv1: azc bf16 [8192][224], k = tap*65 + c, zero-padded
// ---------------------------------------------------------------------------
__global__ void k_azc(const float* __restrict__ z, const int* __restrict__ idx,
                      const int* __restrict__ segst, const int* __restrict__ dur,
                      bf16* __restrict__ azc)
{
  int gid = blockIdx.x * blockDim.x + threadIdx.x;
  if (gid >= 8192 * 224) return;
  int k = gid % 224;
  int m = gid / 224;
  int b = m >> 10, t = m & 1023;
  float v = 0.f;
  if (k < 195) {
    int tap = k / 65, c = k - tap * 65;
    int tt = t + tap - 1;
    if (tt >= 0 && tt < T_) {
      int iv = idx[b * T_ + tt];
      if (c < 64) v = z[(size_t)(b * N_ + iv) * 64 + c];
      else {
        int s0 = segst[b * N_ + iv];
        float d = (float)dur[b * N_ + iv];
        v = ((float)(tt - s0) + 0.5f) / d;
      }
    }
  }
  azc[gid] = bf16(v);
}

// zero pad rows of y1p (bf16)
__global__ void k_zero_pad(bf16* __restrict__ y1p) {
  int gid = blockIdx.x * blockDim.x + threadIdx.x;
  if (gid >= B_ * 2 * 512) return;
  int d = gid & 511;
  int rest = gid >> 9;
  int which = rest & 1;
  int b = rest >> 1;
  int rr = which ? (T_ + 1) : 0;
  y1p[(size_t)(b * (T_ + 2) + rr) * 512 + d] = bf16(0.f);
}

// ---------------------------------------------------------------------------
// losses
// ---------------------------------------------------------------------------
__global__ __launch_bounds__(256) void k_loss_part(
    const float* __restrict__ x, const float* __restrict__ xr,
    float* __restrict__ l1part, float* __restrict__ l2part)
{
  __shared__ float sh1[4], sh2[4];
  float a = 0.f, b2 = 0.f;
  const int total = B_ * T_ * D_;
  for (int i = blockIdx.x * blockDim.x + threadIdx.x; i < total; i += gridDim.x * blockDim.x) {
    float d = x[i] - xr[i];
    a += fabsf(d);
    b2 += d * d;
  }
#pragma unroll
  for (int off = 32; off; off >>= 1) { a += __shfl_xor(a, off); b2 += __shfl_xor(b2, off); }
  int w = threadIdx.x >> 6, lane = threadIdx.x & 63;
  if (lane == 0) { sh1[w] = a; sh2[w] = b2; }
  __syncthreads();
  if (threadIdx.x == 0) {
    l1part[blockIdx.x] = sh1[0] + sh1[1] + sh1[2] + sh1[3];
    l2part[blockIdx.x] = sh2[0] + sh2[1] + sh2[2] + sh2[3];
  }
}

__global__ __launch_bounds__(256) void k_final(
    const float* __restrict__ klpart, const float* __restrict__ l1part,
    const float* __restrict__ l2part, const float* __restrict__ klw,
    float* __restrict__ out)
{
  __shared__ float sa[4], sb[4], sc2[4];
  float a = 0.f, b2 = 0.f, c = 0.f;
  for (int i = threadIdx.x; i < 1024; i += 256) {
    a += klpart[i]; b2 += l1part[i]; c += l2part[i];
  }
#pragma unroll
  for (int off = 32; off; off >>= 1) {
    a += __shfl_xor(a, off); b2 += __shfl_xor(b2, off); c += __shfl_xor(c, off);
  }
  int w = threadIdx.x >> 6, lane = threadIdx.x & 63;
  if (lane == 0) { sa[w] = a; sb[w] = b2; sc2[w] = c; }
  __syncthreads();
  if (threadIdx.x == 0) {
    float kl = sa[0] + sa[1] + sa[2] + sa[3];
    float l1 = sb[0] + sb[1] + sb[2] + sb[3];
    float l2 = sc2[0] + sc2[1] + sc2[2] + sc2[3];
    out[(size_t)B_ * T_ * D_]     = -0.5f * kl * klw[0];
    out[(size_t)B_ * T_ * D_ + 1] = (l1 + l2) / (float)(B_ * T_ * D_);
  }
}

// ---------------------------------------------------------------------------
extern "C" void kernel_launch(void* const* d_in, const int* in_sizes, int n_in,
                              void* d_out, int out_size, void* d_ws, size_t ws_size,
                              hipStream_t stream)
{
  const float* emb  = (const float*)d_in[0];
  const float* algn = (const float*)d_in[1];
  const float* x    = (const float*)d_in[2];
  const float* klw  = (const float*)d_in[5];
  const float* eps  = (const float*)d_in[6];
  const float* lq   = (const float*)d_in[7];
  const float* inw  = (const float*)d_in[8];
  const float* inb  = (const float*)d_in[9];
  const float* outw = (const float*)d_in[10];
  const float* outb = (const float*)d_in[11];
  const float* lng  = (const float*)d_in[12];
  const float* lnb  = (const float*)d_in[13];
  const float* botw = (const float*)d_in[14];
  const float* botb = (const float*)d_in[15];
  const float* muw  = (const float*)d_in[16];
  const float* mub  = (const float*)d_in[17];
  const float* lvw  = (const float*)d_in[18];
  const float* lvb  = (const float*)d_in[19];
  const float* c1w  = (const float*)d_in[20];
  const float* c1b  = (const float*)d_in[21];
  const float* c2w  = (const float*)d_in[22];
  const float* c2b  = (const float*)d_in[23];
  float* out = (float*)d_out;

  float* ws = (float*)d_ws;
  size_t o = 0;
  auto allocF = [&](size_t n) { float* p = ws + o; o += n; return p; };
  auto allocB = [&](size_t n) { bf16* p = (bf16*)(ws + o); o += (n + 1) / 2; return p; };

  bf16* kvB    = allocB(8192ull * 1024);
  bf16* xb     = allocB(8192ull * 512);     // dead after kv GEMM; azc aliases it
  bf16* qryB   = allocB(4096ull * 512);
  bf16* qbufB  = allocB(4096ull * 512);
  bf16* ctxB   = allocB(4096ull * 512);
  bf16* qnB    = allocB(4096ull * 512);
  bf16* inwb   = allocB(1536ull * 512);
  bf16* outwb  = allocB(512ull * 512);
  bf16* botwb  = allocB(512ull * 2048);
  bf16* w1tb   = allocB(512ull * 224);
  bf16* w2tb   = allocB(512ull * 1536);
  bf16* y1p    = allocB(8ull * (T_ + 2) * 512);
  float* attnF  = allocF(4096ull * 512);    // dead after k_ln; botP aliases it
  float* pooled = allocF(1024ull * 512);
  float* hidden = allocF(1024ull * 512);
  float* zbuf   = allocF(1024ull * 64);
  float* klpart = allocF(1024);
  float* l1part = allocF(1024);
  float* l2part = allocF(1024);
  int* idx   = (int*)(ws + o); o += 8192;
  int* segst = (int*)(ws + o); o += 1024;
  int* durI  = (int*)(ws + o); o += 1024;
  bf16* azc  = xb;                          // 8192*224 bf16 < 8192*512 bf16
  float* botP = attnF;                      // 4*1024*512 fp32 == 4096*512 fp32

  // segmentation + conversions + repacks
  k_seg_init<<<dim3((B_ * N_ + 255) / 256), 256, 0, stream>>>(durI, segst);
  k_seg_build<<<dim3(B_ * T_ / 4), 256, 0, stream>>>(algn, idx, durI, segst);
  k_f2b4<<<dim3(8192 * 512 / 4 / 256), 256, 0, stream>>>(x, xb, 8192 * 512 / 4);
  k_f2b4<<<dim3(1536 * 512 / 4 / 256), 256, 0, stream>>>(inw, inwb, 1536 * 512 / 4);
  k_f2b4<<<dim3(512 * 512 / 4 / 256), 256, 0, stream>>>(outw, outwb, 512 * 512 / 4);
  k_f2b4<<<dim3(512 * 2048 / 4 / 256), 256, 0, stream>>>(botw, botwb, 512 * 2048 / 4);
  k_w1t<<<dim3(512 * 224 / 256), 256, 0, stream>>>(c1w, w1tb);
  k_w2t<<<dim3(512 * 1536 / 256), 256, 0, stream>>>(c2w, w2tb);
  k_build_queries<<<dim3(B_ * N_ * Q_ * D_ / 256), 256, 0, stream>>>(emb, lq, qryB);

  // kv projection: [8192,512] x [1024,512]^T -> bf16 [8192,1024]
  k_mgemm<0, 0, 0, bf16><<<dim3(8, 64), 256, 0, stream>>>(
      xb, 512, inwb + 512 * 512, 512, inb + 512, kvB, 1024, 8192, 1024, 512);
  // q projection
  k_mgemm<0, 0, 0, bf16><<<dim3(4, 32), 256, 0, stream>>>(
      qryB, 512, inwb, 512, inb, qbufB, 512, 4096, 512, 512);

  k_attn<<<dim3(B_ * N_), 256, 0, stream>>>(qbufB, kvB, segst, durI, ctxB);

  // out projection -> fp32 attnF
  k_mgemm<0, 0, 0, float><<<dim3(4, 32), 256, 0, stream>>>(
      ctxB, 512, outwb, 512, outb, attnF, 512, 4096, 512, 512);

  k_ln<<<dim3(1024), 256, 0, stream>>>(emb, lq, attnF, lng, lnb, qnB);
  k_pool<<<dim3(B_ * N_), 256, 0, stream>>>(x, segst, durI, pooled);

  // bottleneck: split-K=4 partials + epilogue
  k_mgemm<3, 0, 0, float><<<dim3(4, 8, 4), 256, 0, stream>>>(
      qnB, 2048, botwb, 2048, nullptr, botP, 512, 1024, 512, 512);
  k_bot_epi<<<dim3(1024 * 512 / 256), 256, 0, stream>>>(botP, botb, pooled, hidden);

  k_muz<<<dim3(B_ * N_), 128, 0, stream>>>(hidden, muw, mub, lvw, lvb, eps, zbuf, klpart);
  k_azc<<<dim3(8192 * 224 / 256), 256, 0, stream>>>(zbuf, idx, segst, durI, azc);
  k_zero_pad<<<dim3((B_ * 2 * 512 + 255) / 256), 256, 0, stream>>>(y1p);

  // conv1: silu -> bf16 y1p (padded rows, CMODE=1)
  k_mgemm<1, 0, 1, bf16><<<dim3(4, 64), 256, 0, stream>>>(
      azc, 224, w1tb, 224, c1b, y1p, 512, 8192, 512, 224);
  // conv2: padded A (APAD=1), K=1536 -> fp32 out
  k_mgemm<0, 1, 0, float><<<dim3(4, 64), 256, 0, stream>>>(
      y1p, 512, w2tb, 1536, c2b, out, 512, 8192, 512, 1536);

  k_loss_part<<<dim3(1024), 256, 0, stream>>>(x, out, l1part, l2part);
  k_final<<<dim3(1), 256, 0, stream>>>(klpart, l1part, l2part, klw, out);
}

// Round 4
// 211.431 us; speedup vs baseline: 5.4344x; 1.1636x over previous
//
#include <hip/hip_runtime.h>
#include <hip/hip_bf16.h>
#include <math.h>

#define B_  8
#define N_  128
#define T_  1024
#define D_  512
#define LD_ 64
#define H_  8
#define Q_  4

typedef __hip_bfloat16 bf16;
typedef __attribute__((ext_vector_type(8))) short short8v;
typedef __attribute__((ext_vector_type(4))) float f32x4;
typedef __attribute__((ext_vector_type(4))) float float4v;
typedef __attribute__((ext_vector_type(4))) unsigned int uint4v;

__device__ __forceinline__ void gload16(const void* g, void* l) {
  __builtin_amdgcn_global_load_lds(
      (const __attribute__((address_space(1))) void*)g,
      (__attribute__((address_space(3))) void*)l, 16, 0, 0);
}

// ---------------------------------------------------------------------------
// segmentation: wave-per-row ballot scan; also zeros loss accumulators
// ---------------------------------------------------------------------------
__global__ void k_seg_init(int* __restrict__ dur, int* __restrict__ segst,
                           float* __restrict__ lacc) {
  int i = blockIdx.x * blockDim.x + threadIdx.x;
  if (i < B_ * N_) { dur[i] = 0; segst[i] = 0x7fffffff; }
  if (i < 2) lacc[i] = 0.f;
}

__global__ __launch_bounds__(256) void k_seg_build(
    const float* __restrict__ align, int* __restrict__ idx,
    int* __restrict__ dur, int* __restrict__ segst) {
  int row = blockIdx.x * 4 + (threadIdx.x >> 6);    // b*T + t
  int lane = threadIdx.x & 63;
  const float* r = align + (size_t)row * N_;
  unsigned long long m0 = __ballot(r[lane] > 0.5f);
  unsigned long long m1 = __ballot(r[lane + 64] > 0.5f);
  if (lane == 0) {
    int n = m0 ? (__ffsll(m0) - 1) : (m1 ? (__ffsll(m1) - 1 + 64) : 0);
    idx[row] = n;
    int b = row >> 10, t = row & 1023;
    atomicAdd(&dur[b * N_ + n], 1);
    atomicMin(&segst[b * N_ + n], t);
  }
}

// ---------------------------------------------------------------------------
// fp32 -> bf16, 4 elems/thread
// ---------------------------------------------------------------------------
__global__ void k_f2b4(const float* __restrict__ in, bf16* __restrict__ out, int n4) {
  int gid = blockIdx.x * blockDim.x + threadIdx.x;
  if (gid >= n4) return;
  float4v v = *(const float4v*)(in + (size_t)gid * 4);
  bf16 o[4] = {bf16(v.x), bf16(v.y), bf16(v.z), bf16(v.w)};
  *(ulong1*)(out + (size_t)gid * 4) = *(ulong1*)o;
}

__global__ void k_build_queries(const float* __restrict__ emb, const float* __restrict__ lq,
                                bf16* __restrict__ out) {
  int gid = blockIdx.x * blockDim.x + threadIdx.x;
  if (gid >= B_ * N_ * Q_ * D_) return;
  int d = gid & (D_ - 1);
  int row = gid >> 9;
  int j = row & 3;
  int bn = row >> 2;
  float v = (j == 0) ? emb[(size_t)bn * D_ + d] : lq[(j - 1) * D_ + d];
  out[gid] = bf16(v);
}

// conv weight repacks to bf16 [co][K] matching A-panel k = tap*C + ci
__global__ void k_w1t(const float* __restrict__ w, bf16* __restrict__ wt) {
  int gid = blockIdx.x * blockDim.x + threadIdx.x;
  if (gid >= 512 * 224) return;
  int kk = gid % 224; int c = gid / 224;
  float v = 0.f;
  if (kk < 195) { int tap = kk / 65, i = kk - tap * 65; v = w[c * 195 + i * 3 + tap]; }
  wt[gid] = bf16(v);
}
__global__ void k_w2t(const float* __restrict__ w, bf16* __restrict__ wt) {
  int gid = blockIdx.x * blockDim.x + threadIdx.x;
  if (gid >= 512 * 1536) return;
  int kk = gid % 1536; int co = gid / 1536;
  int tap = kk >> 9, ci = kk & 511;
  wt[gid] = bf16(w[co * 1536 + ci * 3 + tap]);
}

// ---------------------------------------------------------------------------
// bf16 MFMA GEMM, 128x128 tile, BK=32, depth-3 pipelined global_load_lds.
//   EPI: 0 none, 1 silu, 3 raw partial (split-K), 4 none + fused L1/L2 loss
//   APAD: A physical row = m + 2*(m>>10); CMODE: C row = m + 2*(m>>10) + 1
// ---------------------------------------------------------------------------
template<int EPI, int APAD, int CMODE, typename CT>
__global__ __launch_bounds__(256) void k_mgemm(
    const bf16* __restrict__ A, int lda,
    const bf16* __restrict__ W, int ldw,
    const float* __restrict__ bias,
    CT* __restrict__ C, int ldc,
    int M, int Nc, int K,
    const float* __restrict__ xref = nullptr,
    float* __restrict__ lacc = nullptr)
{
  __shared__ __align__(16) short As[3][4096];
  __shared__ __align__(16) short Bs[3][4096];
  const int tid = threadIdx.x;
  const int m0 = blockIdx.y * 128;
  const int n0 = blockIdx.x * 128;
  const int kz = blockIdx.z;
  const int kbase = kz * K;
  const int w = tid >> 6, lane = tid & 63;
  const int wm = (w >> 1) * 64, wn = (w & 1) * 64;
  const int lr = lane & 15, lk = (lane >> 4) * 8;

  const int r = tid >> 2;
  const int kc = (tid & 3) * 8;
  int gmA0 = m0 + r, gmA1 = m0 + r + 64;
  int ar0 = APAD ? gmA0 + ((gmA0 >> 10) << 1) : gmA0;
  int ar1 = APAD ? gmA1 + ((gmA1 >> 10) << 1) : gmA1;
  const size_t aOff0 = (size_t)ar0 * lda + kc + kbase;
  const size_t aOff1 = (size_t)ar1 * lda + kc + kbase;
  const size_t wOff0 = (size_t)(n0 + r) * ldw + kc + kbase;
  const size_t wOff1 = (size_t)(n0 + r + 64) * ldw + kc + kbase;

  const int nt = K >> 5;

  gload16(A + aOff0, &As[0][tid * 8]);
  gload16(A + aOff1, &As[0][2048 + tid * 8]);
  gload16(W + wOff0, &Bs[0][tid * 8]);
  gload16(W + wOff1, &Bs[0][2048 + tid * 8]);
  if (nt > 1) {
    gload16(A + aOff0 + 32, &As[1][tid * 8]);
    gload16(A + aOff1 + 32, &As[1][2048 + tid * 8]);
    gload16(W + wOff0 + 32, &Bs[1][tid * 8]);
    gload16(W + wOff1 + 32, &Bs[1][2048 + tid * 8]);
  }

  f32x4 acc[4][4] = {};
  int cur = 0;
  for (int t = 0; t < nt; ++t) {
    if (t + 2 < nt) {
      int b2 = cur + 2; if (b2 >= 3) b2 -= 3;
      size_t kk = (size_t)(t + 2) * 32;
      gload16(A + aOff0 + kk, &As[b2][tid * 8]);
      gload16(A + aOff1 + kk, &As[b2][2048 + tid * 8]);
      gload16(W + wOff0 + kk, &Bs[b2][tid * 8]);
      gload16(W + wOff1 + kk, &Bs[b2][2048 + tid * 8]);
      asm volatile("s_waitcnt vmcnt(8)" ::: "memory");
    } else if (t + 1 < nt) {
      asm volatile("s_waitcnt vmcnt(4)" ::: "memory");
    } else {
      asm volatile("s_waitcnt vmcnt(0)" ::: "memory");
    }
    __builtin_amdgcn_sched_barrier(0);
    __builtin_amdgcn_s_barrier();
    __builtin_amdgcn_sched_barrier(0);
    short8v af[4], bfv[4];
#pragma unroll
    for (int i = 0; i < 4; ++i)
      af[i] = *(const short8v*)&As[cur][(wm + i * 16 + lr) * 32 + lk];
#pragma unroll
    for (int j = 0; j < 4; ++j)
      bfv[j] = *(const short8v*)&Bs[cur][(wn + j * 16 + lr) * 32 + lk];
#pragma unroll
    for (int i = 0; i < 4; ++i)
#pragma unroll
      for (int j = 0; j < 4; ++j)
        acc[i][j] = __builtin_amdgcn_mfma_f32_16x16x32_bf16(af[i], bfv[j], acc[i][j], 0, 0, 0);
    __builtin_amdgcn_sched_barrier(0);
    __builtin_amdgcn_s_barrier();
    __builtin_amdgcn_sched_barrier(0);
    cur = (cur == 2) ? 0 : cur + 1;
  }

  if (EPI == 3) C += (size_t)kz * M * ldc;
  const int orow = (lane >> 4) * 4;
  const int ocol = lane & 15;
  float la = 0.f, lb = 0.f;
#pragma unroll
  for (int i = 0; i < 4; ++i) {
#pragma unroll
    for (int q = 0; q < 4; ++q) {
      int gm = m0 + wm + i * 16 + orow + q;
      int cr = CMODE ? gm + ((gm >> 10) << 1) + 1 : gm;
#pragma unroll
      for (int j = 0; j < 4; ++j) {
        int gn = n0 + wn + j * 16 + ocol;
        float v = acc[i][j][q];
        if (EPI != 3) v += bias[gn];
        if (EPI == 1) v = v / (1.f + __expf(-v));
        if (EPI == 4) {
          float diff = xref[(size_t)gm * Nc + gn] - v;
          la += fabsf(diff);
          lb += diff * diff;
        }
        C[(size_t)cr * ldc + gn] = (CT)v;
      }
    }
  }
  if (EPI == 4) {
    __shared__ float sh1[4], sh2[4];
#pragma unroll
    for (int off = 32; off; off >>= 1) { la += __shfl_xor(la, off); lb += __shfl_xor(lb, off); }
    if (lane == 0) { sh1[w] = la; sh2[w] = lb; }
    __syncthreads();
    if (tid == 0) {
      atomicAdd(&lacc[0], sh1[0] + sh1[1] + sh1[2] + sh1[3]);
      atomicAdd(&lacc[1], sh2[0] + sh2[1] + sh2[2] + sh2[3]);
    }
  }
}

// split-K epilogue for bottleneck: sum 4 partials + bias, silu, + pooled
__global__ __launch_bounds__(256) void k_bot_epi(
    const float* __restrict__ part, const float* __restrict__ bias,
    const float* __restrict__ pooled, float* __restrict__ hidden) {
  int gid = blockIdx.x * blockDim.x + threadIdx.x;
  if (gid >= 1024 * 512) return;
  int n = gid & 511;
  const size_t S = 1024ull * 512;
  float v = part[gid] + part[gid + S] + part[gid + 2 * S] + part[gid + 3 * S] + bias[n];
  v = v / (1.f + __expf(-v));
  hidden[gid] = v + pooled[gid];
}

// ---------------------------------------------------------------------------
// segment attention, one pass, all 8 heads at once.
// lane owns d = lane*8 .. lane*8+8 (head = lane>>3); wave w = query j.
// online softmax in registers; K/V rows loaded 16B/lane.
// ---------------------------------------------------------------------------
__global__ __launch_bounds__(256) void k_attn(
    const bf16* __restrict__ qbuf, const bf16* __restrict__ kv,
    const int* __restrict__ segst, const int* __restrict__ dur,
    bf16* __restrict__ ctx)
{
  int bn = blockIdx.x;
  int b = bn >> 7;
  int w = threadIdx.x >> 6;
  int lane = threadIdx.x & 63;
  int s0 = segst[bn], cnt = dur[bn];
  if (cnt == 0) { s0 = 0; cnt = T_; }
  size_t qrow = (size_t)bn * 4 + w;
  const bf16* kvb = kv + ((size_t)b * T_ + s0) * 1024;

  float qf[8];
  {
    uint4v qv = *(const uint4v*)(qbuf + qrow * 512 + lane * 8);
#pragma unroll
    for (int i = 0; i < 4; ++i) {
      unsigned u = qv[i];
      qf[2 * i]     = __uint_as_float(u << 16);
      qf[2 * i + 1] = __uint_as_float(u & 0xffff0000u);
    }
  }

  float m = -1e30f, l = 0.f;
  float o[8] = {};
  for (int s = 0; s < cnt; s += 4) {
    float sc4[4];
#pragma unroll
    for (int u = 0; u < 4; ++u) {
      int ss = s + u;
      int sscl = (ss < cnt) ? ss : (cnt - 1);
      uint4v kr = *(const uint4v*)(kvb + (size_t)sscl * 1024 + lane * 8);
      float d0 = 0.f;
#pragma unroll
      for (int i = 0; i < 4; ++i) {
        unsigned uu = kr[i];
        d0 = fmaf(qf[2 * i],     __uint_as_float(uu << 16),         d0);
        d0 = fmaf(qf[2 * i + 1], __uint_as_float(uu & 0xffff0000u), d0);
      }
      d0 += __shfl_xor(d0, 1);
      d0 += __shfl_xor(d0, 2);
      d0 += __shfl_xor(d0, 4);
      sc4[u] = (ss < cnt) ? d0 * 0.125f : -1e30f;
    }
    float cmax = fmaxf(fmaxf(sc4[0], sc4[1]), fmaxf(sc4[2], sc4[3]));
    float mn = fmaxf(m, cmax);
    float c = __expf(m - mn);
    float p[4];
#pragma unroll
    for (int u = 0; u < 4; ++u) p[u] = __expf(sc4[u] - mn);
    l = l * c + p[0] + p[1] + p[2] + p[3];
#pragma unroll
    for (int k = 0; k < 8; ++k) o[k] *= c;
#pragma unroll
    for (int u = 0; u < 4; ++u) {
      int ss = s + u;
      int sscl = (ss < cnt) ? ss : (cnt - 1);
      uint4v vr = *(const uint4v*)(kvb + (size_t)sscl * 1024 + 512 + lane * 8);
      float pu = p[u];
#pragma unroll
      for (int i = 0; i < 4; ++i) {
        unsigned uu = vr[i];
        o[2 * i]     = fmaf(pu, __uint_as_float(uu << 16),         o[2 * i]);
        o[2 * i + 1] = fmaf(pu, __uint_as_float(uu & 0xffff0000u), o[2 * i + 1]);
      }
    }
    m = mn;
  }
  float invl = 1.f / l;
  bf16 ob[8];
#pragma unroll
  for (int k = 0; k < 8; ++k) ob[k] = bf16(o[k] * invl);
  *(uint4v*)(ctx + qrow * 512 + lane * 8) = *(uint4v*)ob;
}

// ---------------------------------------------------------------------------
// layernorm of (queries + attn_out) -> bf16 qn
// ---------------------------------------------------------------------------
__global__ __launch_bounds__(256) void k_ln(
    const float* __restrict__ emb, const float* __restrict__ lq,
    const float* __restrict__ attn,
    const float* __restrict__ g, const float* __restrict__ bb,
    bf16* __restrict__ qn)
{
  int r = blockIdx.x * 4 + (threadIdx.x >> 6);
  int lane = threadIdx.x & 63;
  int bn = r >> 2, j = r & 3;
  const float* src = (j == 0) ? emb + (size_t)bn * D_ : lq + (size_t)(j - 1) * D_;
  float h[8];
  float s = 0.f, s2 = 0.f;
#pragma unroll
  for (int i = 0; i < 8; ++i) {
    int d = i * 64 + lane;
    float v = src[d] + attn[(size_t)r * D_ + d];
    h[i] = v; s += v; s2 += v * v;
  }
#pragma unroll
  for (int off = 32; off; off >>= 1) { s += __shfl_xor(s, off); s2 += __shfl_xor(s2, off); }
  float mean = s * (1.f / 512.f);
  float var = s2 * (1.f / 512.f) - mean * mean;
  float inv = rsqrtf(var + 1e-5f);
#pragma unroll
  for (int i = 0; i < 8; ++i) {
    int d = i * 64 + lane;
    qn[(size_t)r * D_ + d] = bf16((h[i] - mean) * inv * g[d] + bb[d]);
  }
}

// ---------------------------------------------------------------------------
// pooled[b,n,d] = segment mean of x
// ---------------------------------------------------------------------------
__global__ __launch_bounds__(256) void k_pool(
    const float* __restrict__ x, const int* __restrict__ segst,
    const int* __restrict__ dur, float* __restrict__ pooled)
{
  int bn = blockIdx.x;
  int b = bn >> 7;
  int s0 = segst[bn], cnt = dur[bn];
  int d0 = threadIdx.x;
  float a0 = 0.f, a1 = 0.f;
  for (int i = 0; i < cnt; ++i) {
    const float* xr = x + (size_t)(b * T_ + s0 + i) * D_;
    a0 += xr[d0];
    a1 += xr[d0 + 256];
  }
  float inv = 1.f / ((float)cnt + 1e-8f);
  pooled[(size_t)bn * D_ + d0] = a0 * inv;
  pooled[(size_t)bn * D_ + d0 + 256] = a1 * inv;
}

// ---------------------------------------------------------------------------
// mu/logvar/z + KL partial
// ---------------------------------------------------------------------------
__global__ __launch_bounds__(128) void k_muz(
    const float* __restrict__ hidden,
    const float* __restrict__ mu_w, const float* __restrict__ mu_b,
    const float* __restrict__ lv_w, const float* __restrict__ lv_b,
    const float* __restrict__ eps, float* __restrict__ z, float* __restrict__ klpart)
{
  __shared__ float hs[512];
  __shared__ float ms[64], ls[64];
  int bn = blockIdx.x;
  int tid = threadIdx.x;
  for (int i = tid; i < 512; i += 128) hs[i] = hidden[(size_t)bn * 512 + i];
  __syncthreads();
  int ld = tid & 63;
  const float* wrow = (tid < 64) ? (mu_w + (size_t)ld * 512) : (lv_w + (size_t)ld * 512);
  float acc = 0.f;
  for (int k = 0; k < 512; ++k) acc = fmaf(hs[k], wrow[k], acc);
  acc += (tid < 64) ? mu_b[ld] : lv_b[ld];
  if (tid < 64) ms[ld] = acc; else ls[ld] = acc;
  __syncthreads();
  if (tid < 64) {
    float mu = ms[ld], lv = ls[ld];
    z[(size_t)bn * 64 + ld] = mu + eps[(size_t)bn * 64 + ld] * expf(0.5f * lv);
    float klt = 1.f + lv - mu * mu - expf(lv);
#pragma unroll
    for (int off = 32; off; off >>= 1) klt += __shfl_xor(klt, off);
    if (ld == 0) klpart[bn] = klt;
  }
}

// ---------------------------------------------------------------------------
// im2col A for conv1: azc bf16 [8192][224], k = tap*65 + c, zero-padded
// ---------------------------------------------------------------------------
__global__ void k_azc(const float* __restrict__ z, const int* __restrict__ idx,
                      const int* __restrict__ segst, const int* __restrict__ dur,
                      bf16* __restrict__ azc)
{
  int gid = blockIdx.x * blockDim.x + threadIdx.x;
  if (gid >= 8192 * 224) return;
  int k = gid % 224;
  int m = gid / 224;
  int b = m >> 10, t = m & 1023;
  float v = 0.f;
  if (k < 195) {
    int tap = k / 65, c = k - tap * 65;
    int tt = t + tap - 1;
    if (tt >= 0 && tt < T_) {
      int iv = idx[b * T_ + tt];
      if (c < 64) v = z[(size_t)(b * N_ + iv) * 64 + c];
      else {
        int s0 = segst[b * N_ + iv];
        float d = (float)dur[b * N_ + iv];
        v = ((float)(tt - s0) + 0.5f) / d;
      }
    }
  }
  azc[gid] = bf16(v);
}

// zero pad rows of y1p (bf16)
__global__ void k_zero_pad(bf16* __restrict__ y1p) {
  int gid = blockIdx.x * blockDim.x + threadIdx.x;
  if (gid >= B_ * 2 * 512) return;
  int d = gid & 511;
  int rest = gid >> 9;
  int which = rest & 1;
  int b = rest >> 1;
  int rr = which ? (T_ + 1) : 0;
  y1p[(size_t)(b * (T_ + 2) + rr) * 512 + d] = bf16(0.f);
}

// ---------------------------------------------------------------------------
// final scalar outputs
// ---------------------------------------------------------------------------
__global__ __launch_bounds__(256) void k_final(
    const float* __restrict__ klpart, const float* __restrict__ lacc,
    const float* __restrict__ klw, float* __restrict__ out)
{
  __shared__ float sa[4];
  float a = 0.f;
  for (int i = threadIdx.x; i < 1024; i += 256) a += klpart[i];
#pragma unroll
  for (int off = 32; off; off >>= 1) a += __shfl_xor(a, off);
  int w = threadIdx.x >> 6, lane = threadIdx.x & 63;
  if (lane == 0) sa[w] = a;
  __syncthreads();
  if (threadIdx.x == 0) {
    float kl = sa[0] + sa[1] + sa[2] + sa[3];
    out[(size_t)B_ * T_ * D_]     = -0.5f * kl * klw[0];
    out[(size_t)B_ * T_ * D_ + 1] = (lacc[0] + lacc[1]) / (float)(B_ * T_ * D_);
  }
}

// ---------------------------------------------------------------------------
extern "C" void kernel_launch(void* const* d_in, const int* in_sizes, int n_in,
                              void* d_out, int out_size, void* d_ws, size_t ws_size,
                              hipStream_t stream)
{
  const float* emb  = (const float*)d_in[0];
  const float* algn = (const float*)d_in[1];
  const float* x    = (const float*)d_in[2];
  const float* klw  = (const float*)d_in[5];
  const float* eps  = (const float*)d_in[6];
  const float* lq   = (const float*)d_in[7];
  const float* inw  = (const float*)d_in[8];
  const float* inb  = (const float*)d_in[9];
  const float* outw = (const float*)d_in[10];
  const float* outb = (const float*)d_in[11];
  const float* lng  = (const float*)d_in[12];
  const float* lnb  = (const float*)d_in[13];
  const float* botw = (const float*)d_in[14];
  const float* botb = (const float*)d_in[15];
  const float* muw  = (const float*)d_in[16];
  const float* mub  = (const float*)d_in[17];
  const float* lvw  = (const float*)d_in[18];
  const float* lvb  = (const float*)d_in[19];
  const float* c1w  = (const float*)d_in[20];
  const float* c1b  = (const float*)d_in[21];
  const float* c2w  = (const float*)d_in[22];
  const float* c2b  = (const float*)d_in[23];
  float* out = (float*)d_out;

  float* ws = (float*)d_ws;
  size_t o = 0;
  auto allocF = [&](size_t n) { float* p = ws + o; o += n; return p; };
  auto allocB = [&](size_t n) { bf16* p = (bf16*)(ws + o); o += (n + 1) / 2; return p; };

  bf16* kvB    = allocB(8192ull * 1024);
  bf16* xb     = allocB(8192ull * 512);     // dead after kv GEMM; azc aliases it
  bf16* qryB   = allocB(4096ull * 512);
  bf16* qbufB  = allocB(4096ull * 512);
  bf16* ctxB   = allocB(4096ull * 512);
  bf16* qnB    = allocB(4096ull * 512);
  bf16* inwb   = allocB(1536ull * 512);
  bf16* outwb  = allocB(512ull * 512);
  bf16* botwb  = allocB(512ull * 2048);
  bf16* w1tb   = allocB(512ull * 224);
  bf16* w2tb   = allocB(512ull * 1536);
  bf16* y1p    = allocB(8ull * (T_ + 2) * 512);
  float* attnF  = allocF(4096ull * 512);    // dead after k_ln; botP aliases it
  float* pooled = allocF(1024ull * 512);
  float* hidden = allocF(1024ull * 512);
  float* zbuf   = allocF(1024ull * 64);
  float* klpart = allocF(1024);
  float* lacc   = allocF(2);
  int* idx   = (int*)(ws + o); o += 8192;
  int* segst = (int*)(ws + o); o += 1024;
  int* durI  = (int*)(ws + o); o += 1024;
  bf16* azc  = xb;                          // 8192*224 bf16 < 8192*512 bf16
  float* botP = attnF;                      // 4*1024*512 fp32 == 4096*512 fp32

  // segmentation + conversions + repacks
  k_seg_init<<<dim3((B_ * N_ + 255) / 256), 256, 0, stream>>>(durI, segst, lacc);
  k_seg_build<<<dim3(B_ * T_ / 4), 256, 0, stream>>>(algn, idx, durI, segst);
  k_f2b4<<<dim3(8192 * 512 / 4 / 256), 256, 0, stream>>>(x, xb, 8192 * 512 / 4);
  k_f2b4<<<dim3(1536 * 512 / 4 / 256), 256, 0, stream>>>(inw, inwb, 1536 * 512 / 4);
  k_f2b4<<<dim3(512 * 512 / 4 / 256), 256, 0, stream>>>(outw, outwb, 512 * 512 / 4);
  k_f2b4<<<dim3(512 * 2048 / 4 / 256), 256, 0, stream>>>(botw, botwb, 512 * 2048 / 4);
  k_w1t<<<dim3(512 * 224 / 256), 256, 0, stream>>>(c1w, w1tb);
  k_w2t<<<dim3(512 * 1536 / 256), 256, 0, stream>>>(c2w, w2tb);
  k_build_queries<<<dim3(B_ * N_ * Q_ * D_ / 256), 256, 0, stream>>>(emb, lq, qryB);

  // kv projection: [8192,512] x [1024,512]^T -> bf16 [8192,1024]
  k_mgemm<0, 0, 0, bf16><<<dim3(8, 64), 256, 0, stream>>>(
      xb, 512, inwb + 512 * 512, 512, inb + 512, kvB, 1024, 8192, 1024, 512);
  // q projection
  k_mgemm<0, 0, 0, bf16><<<dim3(4, 32), 256, 0, stream>>>(
      qryB, 512, inwb, 512, inb, qbufB, 512, 4096, 512, 512);

  k_attn<<<dim3(B_ * N_), 256, 0, stream>>>(qbufB, kvB, segst, durI, ctxB);

  // out projection -> fp32 attnF
  k_mgemm<0, 0, 0, float><<<dim3(4, 32), 256, 0, stream>>>(
      ctxB, 512, outwb, 512, outb, attnF, 512, 4096, 512, 512);

  k_ln<<<dim3(1024), 256, 0, stream>>>(emb, lq, attnF, lng, lnb, qnB);
  k_pool<<<dim3(B_ * N_), 256, 0, stream>>>(x, segst, durI, pooled);

  // bottleneck: split-K=4 partials + epilogue
  k_mgemm<3, 0, 0, float><<<dim3(4, 8, 4), 256, 0, stream>>>(
      qnB, 2048, botwb, 2048, nullptr, botP, 512, 1024, 512, 512);
  k_bot_epi<<<dim3(1024 * 512 / 256), 256, 0, stream>>>(botP, botb, pooled, hidden);

  k_muz<<<dim3(B_ * N_), 128, 0, stream>>>(hidden, muw, mub, lvw, lvb, eps, zbuf, klpart);
  k_azc<<<dim3(8192 * 224 / 256), 256, 0, stream>>>(zbuf, idx, segst, durI, azc);
  k_zero_pad<<<dim3((B_ * 2 * 512 + 255) / 256), 256, 0, stream>>>(y1p);

  // conv1: silu -> bf16 y1p (padded rows, CMODE=1)
  k_mgemm<1, 0, 1, bf16><<<dim3(4, 64), 256, 0, stream>>>(
      azc, 224, w1tb, 224, c1b, y1p, 512, 8192, 512, 224);
  // conv2: padded A (APAD=1), K=1536 -> fp32 out, fused L1/L2 loss vs x
  k_mgemm<4, 1, 0, float><<<dim3(4, 64), 256, 0, stream>>>(
      y1p, 512, w2tb, 1536, c2b, out, 512, 8192, 512, 1536, x, lacc);

  k_final<<<dim3(1), 256, 0, stream>>>(klpart, lacc, klw, out);
}

// Round 5
// 198.823 us; speedup vs baseline: 5.7790x; 1.0634x over previous
//
#include <hip/hip_runtime.h>
#include <hip/hip_bf16.h>
#include <math.h>

#define B_  8
#define N_  128
#define T_  1024
#define D_  512
#define LD_ 64
#define H_  8
#define Q_  4

typedef __hip_bfloat16 bf16;
typedef __attribute__((ext_vector_type(8))) short short8v;
typedef __attribute__((ext_vector_type(4))) float f32x4;
typedef __attribute__((ext_vector_type(4))) float float4v;
typedef __attribute__((ext_vector_type(4))) unsigned int uint4v;

__device__ __forceinline__ void gload16(const void* g, void* l) {
  __builtin_amdgcn_global_load_lds(
      (const __attribute__((address_space(1))) void*)g,
      (__attribute__((address_space(3))) void*)l, 16, 0, 0);
}

// ---------------------------------------------------------------------------
// segmentation: wave-per-row ballot scan; also zeros loss accumulators
// ---------------------------------------------------------------------------
__global__ void k_seg_init(int* __restrict__ dur, int* __restrict__ segst,
                           float* __restrict__ lacc) {
  int i = blockIdx.x * blockDim.x + threadIdx.x;
  if (i < B_ * N_) { dur[i] = 0; segst[i] = 0x7fffffff; }
  if (i < 2) lacc[i] = 0.f;
}

__global__ __launch_bounds__(256) void k_seg_build(
    const float* __restrict__ align, int* __restrict__ idx,
    int* __restrict__ dur, int* __restrict__ segst) {
  int row = blockIdx.x * 4 + (threadIdx.x >> 6);    // b*T + t
  int lane = threadIdx.x & 63;
  const float* r = align + (size_t)row * N_;
  unsigned long long m0 = __ballot(r[lane] > 0.5f);
  unsigned long long m1 = __ballot(r[lane + 64] > 0.5f);
  if (lane == 0) {
    int n = m0 ? (__ffsll(m0) - 1) : (m1 ? (__ffsll(m1) - 1 + 64) : 0);
    idx[row] = n;
    int b = row >> 10, t = row & 1023;
    atomicAdd(&dur[b * N_ + n], 1);
    atomicMin(&segst[b * N_ + n], t);
  }
}

// ---------------------------------------------------------------------------
// fp32 -> bf16, 4 elems/thread
// ---------------------------------------------------------------------------
__global__ void k_f2b4(const float* __restrict__ in, bf16* __restrict__ out, int n4) {
  int gid = blockIdx.x * blockDim.x + threadIdx.x;
  if (gid >= n4) return;
  float4v v = *(const float4v*)(in + (size_t)gid * 4);
  bf16 o[4] = {bf16(v.x), bf16(v.y), bf16(v.z), bf16(v.w)};
  *(ulong1*)(out + (size_t)gid * 4) = *(ulong1*)o;
}

__global__ void k_build_queries(const float* __restrict__ emb, const float* __restrict__ lq,
                                bf16* __restrict__ out) {
  int gid = blockIdx.x * blockDim.x + threadIdx.x;
  if (gid >= B_ * N_ * Q_ * D_) return;
  int d = gid & (D_ - 1);
  int row = gid >> 9;
  int j = row & 3;
  int bn = row >> 2;
  float v = (j == 0) ? emb[(size_t)bn * D_ + d] : lq[(j - 1) * D_ + d];
  out[gid] = bf16(v);
}

// conv weight repacks to bf16 [co][K] matching A-panel k = tap*C + ci
__global__ void k_w1t(const float* __restrict__ w, bf16* __restrict__ wt) {
  int gid = blockIdx.x * blockDim.x + threadIdx.x;
  if (gid >= 512 * 224) return;
  int kk = gid % 224; int c = gid / 224;
  float v = 0.f;
  if (kk < 195) { int tap = kk / 65, i = kk - tap * 65; v = w[c * 195 + i * 3 + tap]; }
  wt[gid] = bf16(v);
}
__global__ void k_w2t(const float* __restrict__ w, bf16* __restrict__ wt) {
  int gid = blockIdx.x * blockDim.x + threadIdx.x;
  if (gid >= 512 * 1536) return;
  int kk = gid % 1536; int co = gid / 1536;
  int tap = kk >> 9, ci = kk & 511;
  wt[gid] = bf16(w[co * 1536 + ci * 3 + tap]);
}

// ---------------------------------------------------------------------------
// bf16 MFMA GEMM, 128x128 tile, BK=32, 8 waves (2x4, 64x32 each), depth-3
// pipelined global_load_lds with LDS chunk swizzle (pre-swizzled source).
//   EPI: 0 none, 1 silu, 3 raw partial (split-K), 4 none + fused L1/L2 loss
//   APAD: A physical row = m + 2*(m>>10); CMODE: C row = m + 2*(m>>10) + 1
// ---------------------------------------------------------------------------
template<int EPI, int APAD, int CMODE, typename CT>
__global__ __launch_bounds__(512) void k_mgemm(
    const bf16* __restrict__ A, int lda,
    const bf16* __restrict__ W, int ldw,
    const float* __restrict__ bias,
    CT* __restrict__ C, int ldc,
    int M, int Nc, int K,
    const float* __restrict__ xref = nullptr,
    float* __restrict__ lacc = nullptr)
{
  __shared__ __align__(16) short As[3][4096];
  __shared__ __align__(16) short Bs[3][4096];
  const int tid = threadIdx.x;
  const int m0 = blockIdx.y * 128;
  const int n0 = blockIdx.x * 128;
  const int kz = blockIdx.z;
  const int kbase = kz * K;
  const int w = tid >> 6, lane = tid & 63;
  const int wm = (w >> 2) * 64, wn = (w & 3) * 32;
  const int lr = lane & 15;
  // swizzled read slot: chunk (lane>>4) of row (..+lr) lives at slot ^ ((row>>1)&3)
  const int slot8 = (((lane >> 4) ^ ((lane >> 1) & 3)) << 3);

  // staging: thread t -> LDS shorts [t*8, t*8+8) = row t>>2, chunk t&3.
  // source chunk pre-swizzled so LDS slot c holds global chunk c ^ ((row>>1)&3).
  const int r = tid >> 2;
  const int kcG = (((tid & 3) ^ ((tid >> 3) & 3)) << 3);
  int gmA = m0 + r;
  int ar = APAD ? gmA + ((gmA >> 10) << 1) : gmA;
  const size_t aOff = (size_t)ar * lda + kcG + kbase;
  const size_t wOff = (size_t)(n0 + r) * ldw + kcG + kbase;

  const int nt = K >> 5;

  gload16(A + aOff, &As[0][tid * 8]);
  gload16(W + wOff, &Bs[0][tid * 8]);
  if (nt > 1) {
    gload16(A + aOff + 32, &As[1][tid * 8]);
    gload16(W + wOff + 32, &Bs[1][tid * 8]);
  }

  f32x4 acc[4][2] = {};
  int cur = 0;
  for (int t = 0; t < nt; ++t) {
    if (t + 2 < nt) {
      int b2 = cur + 2; if (b2 >= 3) b2 -= 3;
      size_t kk = (size_t)(t + 2) * 32;
      gload16(A + aOff + kk, &As[b2][tid * 8]);
      gload16(W + wOff + kk, &Bs[b2][tid * 8]);
      asm volatile("s_waitcnt vmcnt(4)" ::: "memory");
    } else if (t + 1 < nt) {
      asm volatile("s_waitcnt vmcnt(2)" ::: "memory");
    } else {
      asm volatile("s_waitcnt vmcnt(0)" ::: "memory");
    }
    __builtin_amdgcn_sched_barrier(0);
    __builtin_amdgcn_s_barrier();
    __builtin_amdgcn_sched_barrier(0);
    short8v af[4], bfv[2];
#pragma unroll
    for (int i = 0; i < 4; ++i)
      af[i] = *(const short8v*)&As[cur][(wm + i * 16 + lr) * 32 + slot8];
#pragma unroll
    for (int j = 0; j < 2; ++j)
      bfv[j] = *(const short8v*)&Bs[cur][(wn + j * 16 + lr) * 32 + slot8];
    __builtin_amdgcn_s_setprio(1);
#pragma unroll
    for (int i = 0; i < 4; ++i)
#pragma unroll
      for (int j = 0; j < 2; ++j)
        acc[i][j] = __builtin_amdgcn_mfma_f32_16x16x32_bf16(af[i], bfv[j], acc[i][j], 0, 0, 0);
    __builtin_amdgcn_s_setprio(0);
    __builtin_amdgcn_sched_barrier(0);
    __builtin_amdgcn_s_barrier();
    __builtin_amdgcn_sched_barrier(0);
    cur = (cur == 2) ? 0 : cur + 1;
  }

  if (EPI == 3) C += (size_t)kz * M * ldc;
  const int orow = (lane >> 4) * 4;
  const int ocol = lane & 15;
  float la = 0.f, lb = 0.f;
#pragma unroll
  for (int i = 0; i < 4; ++i) {
#pragma unroll
    for (int q = 0; q < 4; ++q) {
      int gm = m0 + wm + i * 16 + orow + q;
      int cr = CMODE ? gm + ((gm >> 10) << 1) + 1 : gm;
#pragma unroll
      for (int j = 0; j < 2; ++j) {
        int gn = n0 + wn + j * 16 + ocol;
        float v = acc[i][j][q];
        if (EPI != 3) v += bias[gn];
        if (EPI == 1) v = v / (1.f + __expf(-v));
        if (EPI == 4) {
          float diff = xref[(size_t)gm * Nc + gn] - v;
          la += fabsf(diff);
          lb += diff * diff;
        }
        C[(size_t)cr * ldc + gn] = (CT)v;
      }
    }
  }
  if (EPI == 4) {
    __shared__ float sh1[8], sh2[8];
#pragma unroll
    for (int off = 32; off; off >>= 1) { la += __shfl_xor(la, off); lb += __shfl_xor(lb, off); }
    if (lane == 0) { sh1[w] = la; sh2[w] = lb; }
    __syncthreads();
    if (tid == 0) {
      float s1 = 0.f, s2 = 0.f;
#pragma unroll
      for (int i = 0; i < 8; ++i) { s1 += sh1[i]; s2 += sh2[i]; }
      atomicAdd(&lacc[0], s1);
      atomicAdd(&lacc[1], s2);
    }
  }
}

// split-K epilogue for bottleneck: sum 4 partials + bias, silu, + pooled
__global__ __launch_bounds__(256) void k_bot_epi(
    const float* __restrict__ part, const float* __restrict__ bias,
    const float* __restrict__ pooled, float* __restrict__ hidden) {
  int gid = blockIdx.x * blockDim.x + threadIdx.x;
  if (gid >= 1024 * 512) return;
  int n = gid & 511;
  const size_t S = 1024ull * 512;
  float v = part[gid] + part[gid + S] + part[gid + 2 * S] + part[gid + 3 * S] + bias[n];
  v = v / (1.f + __expf(-v));
  hidden[gid] = v + pooled[gid];
}

// ---------------------------------------------------------------------------
// segment attention, one pass, all 8 heads at once.
// lane owns d = lane*8 .. lane*8+8 (head = lane>>3); wave w = query j.
// ---------------------------------------------------------------------------
__global__ __launch_bounds__(256) void k_attn(
    const bf16* __restrict__ qbuf, const bf16* __restrict__ kv,
    const int* __restrict__ segst, const int* __restrict__ dur,
    bf16* __restrict__ ctx)
{
  int bn = blockIdx.x;
  int b = bn >> 7;
  int w = threadIdx.x >> 6;
  int lane = threadIdx.x & 63;
  int s0 = segst[bn], cnt = dur[bn];
  if (cnt == 0) { s0 = 0; cnt = T_; }
  size_t qrow = (size_t)bn * 4 + w;
  const bf16* kvb = kv + ((size_t)b * T_ + s0) * 1024;

  float qf[8];
  {
    uint4v qv = *(const uint4v*)(qbuf + qrow * 512 + lane * 8);
#pragma unroll
    for (int i = 0; i < 4; ++i) {
      unsigned u = qv[i];
      qf[2 * i]     = __uint_as_float(u << 16);
      qf[2 * i + 1] = __uint_as_float(u & 0xffff0000u);
    }
  }

  float m = -1e30f, l = 0.f;
  float o[8] = {};
  for (int s = 0; s < cnt; s += 4) {
    float sc4[4];
#pragma unroll
    for (int u = 0; u < 4; ++u) {
      int ss = s + u;
      int sscl = (ss < cnt) ? ss : (cnt - 1);
      uint4v kr = *(const uint4v*)(kvb + (size_t)sscl * 1024 + lane * 8);
      float d0 = 0.f;
#pragma unroll
      for (int i = 0; i < 4; ++i) {
        unsigned uu = kr[i];
        d0 = fmaf(qf[2 * i],     __uint_as_float(uu << 16),         d0);
        d0 = fmaf(qf[2 * i + 1], __uint_as_float(uu & 0xffff0000u), d0);
      }
      d0 += __shfl_xor(d0, 1);
      d0 += __shfl_xor(d0, 2);
      d0 += __shfl_xor(d0, 4);
      sc4[u] = (ss < cnt) ? d0 * 0.125f : -1e30f;
    }
    float cmax = fmaxf(fmaxf(sc4[0], sc4[1]), fmaxf(sc4[2], sc4[3]));
    float mn = fmaxf(m, cmax);
    float c = __expf(m - mn);
    float p[4];
#pragma unroll
    for (int u = 0; u < 4; ++u) p[u] = __expf(sc4[u] - mn);
    l = l * c + p[0] + p[1] + p[2] + p[3];
#pragma unroll
    for (int k = 0; k < 8; ++k) o[k] *= c;
#pragma unroll
    for (int u = 0; u < 4; ++u) {
      int ss = s + u;
      int sscl = (ss < cnt) ? ss : (cnt - 1);
      uint4v vr = *(const uint4v*)(kvb + (size_t)sscl * 1024 + 512 + lane * 8);
      float pu = p[u];
#pragma unroll
      for (int i = 0; i < 4; ++i) {
        unsigned uu = vr[i];
        o[2 * i]     = fmaf(pu, __uint_as_float(uu << 16),         o[2 * i]);
        o[2 * i + 1] = fmaf(pu, __uint_as_float(uu & 0xffff0000u), o[2 * i + 1]);
      }
    }
    m = mn;
  }
  float invl = 1.f / l;
  bf16 ob[8];
#pragma unroll
  for (int k = 0; k < 8; ++k) ob[k] = bf16(o[k] * invl);
  *(uint4v*)(ctx + qrow * 512 + lane * 8) = *(uint4v*)ob;
}

// ---------------------------------------------------------------------------
// layernorm of (queries + attn_out) -> bf16 qn
// ---------------------------------------------------------------------------
__global__ __launch_bounds__(256) void k_ln(
    const float* __restrict__ emb, const float* __restrict__ lq,
    const float* __restrict__ attn,
    const float* __restrict__ g, const float* __restrict__ bb,
    bf16* __restrict__ qn)
{
  int r = blockIdx.x * 4 + (threadIdx.x >> 6);
  int lane = threadIdx.x & 63;
  int bn = r >> 2, j = r & 3;
  const float* src = (j == 0) ? emb + (size_t)bn * D_ : lq + (size_t)(j - 1) * D_;
  float h[8];
  float s = 0.f, s2 = 0.f;
#pragma unroll
  for (int i = 0; i < 8; ++i) {
    int d = i * 64 + lane;
    float v = src[d] + attn[(size_t)r * D_ + d];
    h[i] = v; s += v; s2 += v * v;
  }
#pragma unroll
  for (int off = 32; off; off >>= 1) { s += __shfl_xor(s, off); s2 += __shfl_xor(s2, off); }
  float mean = s * (1.f / 512.f);
  float var = s2 * (1.f / 512.f) - mean * mean;
  float inv = rsqrtf(var + 1e-5f);
#pragma unroll
  for (int i = 0; i < 8; ++i) {
    int d = i * 64 + lane;
    qn[(size_t)r * D_ + d] = bf16((h[i] - mean) * inv * g[d] + bb[d]);
  }
}

// ---------------------------------------------------------------------------
// pooled[b,n,d] = segment mean of x
// ---------------------------------------------------------------------------
__global__ __launch_bounds__(256) void k_pool(
    const float* __restrict__ x, const int* __restrict__ segst,
    const int* __restrict__ dur, float* __restrict__ pooled)
{
  int bn = blockIdx.x;
  int b = bn >> 7;
  int s0 = segst[bn], cnt = dur[bn];
  int d0 = threadIdx.x;
  float a0 = 0.f, a1 = 0.f;
  for (int i = 0; i < cnt; ++i) {
    const float* xr = x + (size_t)(b * T_ + s0 + i) * D_;
    a0 += xr[d0];
    a1 += xr[d0 + 256];
  }
  float inv = 1.f / ((float)cnt + 1e-8f);
  pooled[(size_t)bn * D_ + d0] = a0 * inv;
  pooled[(size_t)bn * D_ + d0 + 256] = a1 * inv;
}

// ---------------------------------------------------------------------------
// mu/logvar/z + KL partial
// ---------------------------------------------------------------------------
__global__ __launch_bounds__(128) void k_muz(
    const float* __restrict__ hidden,
    const float* __restrict__ mu_w, const float* __restrict__ mu_b,
    const float* __restrict__ lv_w, const float* __restrict__ lv_b,
    const float* __restrict__ eps, float* __restrict__ z, float* __restrict__ klpart)
{
  __shared__ float hs[512];
  __shared__ float ms[64], ls[64];
  int bn = blockIdx.x;
  int tid = threadIdx.x;
  for (int i = tid; i < 512; i += 128) hs[i] = hidden[(size_t)bn * 512 + i];
  __syncthreads();
  int ld = tid & 63;
  const float* wrow = (tid < 64) ? (mu_w + (size_t)ld * 512) : (lv_w + (size_t)ld * 512);
  float acc = 0.f;
  for (int k = 0; k < 512; ++k) acc = fmaf(hs[k], wrow[k], acc);
  acc += (tid < 64) ? mu_b[ld] : lv_b[ld];
  if (tid < 64) ms[ld] = acc; else ls[ld] = acc;
  __syncthreads();
  if (tid < 64) {
    float mu = ms[ld], lv = ls[ld];
    z[(size_t)bn * 64 + ld] = mu + eps[(size_t)bn * 64 + ld] * expf(0.5f * lv);
    float klt = 1.f + lv - mu * mu - expf(lv);
#pragma unroll
    for (int off = 32; off; off >>= 1) klt += __shfl_xor(klt, off);
    if (ld == 0) klpart[bn] = klt;
  }
}

// ---------------------------------------------------------------------------
// im2col A for conv1: azc bf16 [8192][224], k = tap*65 + c, zero-padded
// ---------------------------------------------------------------------------
__global__ void k_azc(const float* __restrict__ z, const int* __restrict__ idx,
                      const int* __restrict__ segst, const int* __restrict__ dur,
                      bf16* __restrict__ azc)
{
  int gid = blockIdx.x * blockDim.x + threadIdx.x;
  if (gid >= 8192 * 224) return;
  int k = gid % 224;
  int m = gid / 224;
  int b = m >> 10, t = m & 1023;
  float v = 0.f;
  if (k < 195) {
    int tap = k / 65, c = k - tap * 65;
    int tt = t + tap - 1;
    if (tt >= 0 && tt < T_) {
      int iv = idx[b * T_ + tt];
      if (c < 64) v = z[(size_t)(b * N_ + iv) * 64 + c];
      else {
        int s0 = segst[b * N_ + iv];
        float d = (float)dur[b * N_ + iv];
        v = ((float)(tt - s0) + 0.5f) / d;
      }
    }
  }
  azc[gid] = bf16(v);
}

// zero pad rows of y1p (bf16)
__global__ void k_zero_pad(bf16* __restrict__ y1p) {
  int gid = blockIdx.x * blockDim.x + threadIdx.x;
  if (gid >= B_ * 2 * 512) return;
  int d = gid & 511;
  int rest = gid >> 9;
  int which = rest & 1;
  int b = rest >> 1;
  int rr = which ? (T_ + 1) : 0;
  y1p[(size_t)(b * (T_ + 2) + rr) * 512 + d] = bf16(0.f);
}

// ---------------------------------------------------------------------------
// final scalar outputs
// ---------------------------------------------------------------------------
__global__ __launch_bounds__(256) void k_final(
    const float* __restrict__ klpart, const float* __restrict__ lacc,
    const float* __restrict__ klw, float* __restrict__ out)
{
  __shared__ float sa[4];
  float a = 0.f;
  for (int i = threadIdx.x; i < 1024; i += 256) a += klpart[i];
#pragma unroll
  for (int off = 32; off; off >>= 1) a += __shfl_xor(a, off);
  int w = threadIdx.x >> 6, lane = threadIdx.x & 63;
  if (lane == 0) sa[w] = a;
  __syncthreads();
  if (threadIdx.x == 0) {
    float kl = sa[0] + sa[1] + sa[2] + sa[3];
    out[(size_t)B_ * T_ * D_]     = -0.5f * kl * klw[0];
    out[(size_t)B_ * T_ * D_ + 1] = (lacc[0] + lacc[1]) / (float)(B_ * T_ * D_);
  }
}

// ---------------------------------------------------------------------------
extern "C" void kernel_launch(void* const* d_in, const int* in_sizes, int n_in,
                              void* d_out, int out_size, void* d_ws, size_t ws_size,
                              hipStream_t stream)
{
  const float* emb  = (const float*)d_in[0];
  const float* algn = (const float*)d_in[1];
  const float* x    = (const float*)d_in[2];
  const float* klw  = (const float*)d_in[5];
  const float* eps  = (const float*)d_in[6];
  const float* lq   = (const float*)d_in[7];
  const float* inw  = (const float*)d_in[8];
  const float* inb  = (const float*)d_in[9];
  const float* outw = (const float*)d_in[10];
  const float* outb = (const float*)d_in[11];
  const float* lng  = (const float*)d_in[12];
  const float* lnb  = (const float*)d_in[13];
  const float* botw = (const float*)d_in[14];
  const float* botb = (const float*)d_in[15];
  const float* muw  = (const float*)d_in[16];
  const float* mub  = (const float*)d_in[17];
  const float* lvw  = (const float*)d_in[18];
  const float* lvb  = (const float*)d_in[19];
  const float* c1w  = (const float*)d_in[20];
  const float* c1b  = (const float*)d_in[21];
  const float* c2w  = (const float*)d_in[22];
  const float* c2b  = (const float*)d_in[23];
  float* out = (float*)d_out;

  float* ws = (float*)d_ws;
  size_t o = 0;
  auto allocF = [&](size_t n) { float* p = ws + o; o += n; return p; };
  auto allocB = [&](size_t n) { bf16* p = (bf16*)(ws + o); o += (n + 1) / 2; return p; };

  bf16* kvB    = allocB(8192ull * 1024);
  bf16* xb     = allocB(8192ull * 512);     // dead after kv GEMM; azc aliases it
  bf16* qryB   = allocB(4096ull * 512);
  bf16* qbufB  = allocB(4096ull * 512);
  bf16* ctxB   = allocB(4096ull * 512);
  bf16* qnB    = allocB(4096ull * 512);
  bf16* inwb   = allocB(1536ull * 512);
  bf16* outwb  = allocB(512ull * 512);
  bf16* botwb  = allocB(512ull * 2048);
  bf16* w1tb   = allocB(512ull * 224);
  bf16* w2tb   = allocB(512ull * 1536);
  bf16* y1p    = allocB(8ull * (T_ + 2) * 512);
  float* attnF  = allocF(4096ull * 512);    // dead after k_ln; botP aliases it
  float* pooled = allocF(1024ull * 512);
  float* hidden = allocF(1024ull * 512);
  float* zbuf   = allocF(1024ull * 64);
  float* klpart = allocF(1024);
  float* lacc   = allocF(2);
  int* idx   = (int*)(ws + o); o += 8192;
  int* segst = (int*)(ws + o); o += 1024;
  int* durI  = (int*)(ws + o); o += 1024;
  bf16* azc  = xb;                          // 8192*224 bf16 < 8192*512 bf16
  float* botP = attnF;                      // 4*1024*512 fp32 == 4096*512 fp32

  // segmentation + conversions + repacks
  k_seg_init<<<dim3((B_ * N_ + 255) / 256), 256, 0, stream>>>(durI, segst, lacc);
  k_seg_build<<<dim3(B_ * T_ / 4), 256, 0, stream>>>(algn, idx, durI, segst);
  k_f2b4<<<dim3(8192 * 512 / 4 / 256), 256, 0, stream>>>(x, xb, 8192 * 512 / 4);
  k_f2b4<<<dim3(1536 * 512 / 4 / 256), 256, 0, stream>>>(inw, inwb, 1536 * 512 / 4);
  k_f2b4<<<dim3(512 * 512 / 4 / 256), 256, 0, stream>>>(outw, outwb, 512 * 512 / 4);
  k_f2b4<<<dim3(512 * 2048 / 4 / 256), 256, 0, stream>>>(botw, botwb, 512 * 2048 / 4);
  k_w1t<<<dim3(512 * 224 / 256), 256, 0, stream>>>(c1w, w1tb);
  k_w2t<<<dim3(512 * 1536 / 256), 256, 0, stream>>>(c2w, w2tb);
  k_build_queries<<<dim3(B_ * N_ * Q_ * D_ / 256), 256, 0, stream>>>(emb, lq, qryB);

  // kv projection: [8192,512] x [1024,512]^T -> bf16 [8192,1024]
  k_mgemm<0, 0, 0, bf16><<<dim3(8, 64), 512, 0, stream>>>(
      xb, 512, inwb + 512 * 512, 512, inb + 512, kvB, 1024, 8192, 1024, 512);
  // q projection
  k_mgemm<0, 0, 0, bf16><<<dim3(4, 32), 512, 0, stream>>>(
      qryB, 512, inwb, 512, inb, qbufB, 512, 4096, 512, 512);

  k_attn<<<dim3(B_ * N_), 256, 0, stream>>>(qbufB, kvB, segst, durI, ctxB);

  // out projection -> fp32 attnF
  k_mgemm<0, 0, 0, float><<<dim3(4, 32), 512, 0, stream>>>(
      ctxB, 512, outwb, 512, outb, attnF, 512, 4096, 512, 512);

  k_ln<<<dim3(1024), 256, 0, stream>>>(emb, lq, attnF, lng, lnb, qnB);
  k_pool<<<dim3(B_ * N_), 256, 0, stream>>>(x, segst, durI, pooled);

  // bottleneck: split-K=4 partials + epilogue
  k_mgemm<3, 0, 0, float><<<dim3(4, 8, 4), 512, 0, stream>>>(
      qnB, 2048, botwb, 2048, nullptr, botP, 512, 1024, 512, 512);
  k_bot_epi<<<dim3(1024 * 512 / 256), 256, 0, stream>>>(botP, botb, pooled, hidden);

  k_muz<<<dim3(B_ * N_), 128, 0, stream>>>(hidden, muw, mub, lvw, lvb, eps, zbuf, klpart);
  k_azc<<<dim3(8192 * 224 / 256), 256, 0, stream>>>(zbuf, idx, segst, durI, azc);
  k_zero_pad<<<dim3((B_ * 2 * 512 + 255) / 256), 256, 0, stream>>>(y1p);

  // conv1: silu -> bf16 y1p (padded rows, CMODE=1)
  k_mgemm<1, 0, 1, bf16><<<dim3(4, 64), 512, 0, stream>>>(
      azc, 224, w1tb, 224, c1b, y1p, 512, 8192, 512, 224);
  // conv2: padded A (APAD=1), K=1536 -> fp32 out, fused L1/L2 loss vs x
  k_mgemm<4, 1, 0, float><<<dim3(4, 64), 512, 0, stream>>>(
      y1p, 512, w2tb, 1536, c2b, out, 512, 8192, 512, 1536, x, lacc);

  k_final<<<dim3(1), 256, 0, stream>>>(klpart, lacc, klw, out);
}

// Round 6
// 195.305 us; speedup vs baseline: 5.8831x; 1.0180x over previous
//
#include <hip/hip_runtime.h>
#include <hip/hip_bf16.h>
#include <math.h>

#define B_  8
#define N_  128
#define T_  1024
#define D_  512
#define LD_ 64
#define H_  8
#define Q_  4

typedef __hip_bfloat16 bf16;
typedef __attribute__((ext_vector_type(8))) short short8v;
typedef __attribute__((ext_vector_type(4))) float f32x4;
typedef __attribute__((ext_vector_type(4))) float float4v;
typedef __attribute__((ext_vector_type(4))) unsigned int uint4v;

__device__ __forceinline__ void gload16(const void* g, void* l) {
  __builtin_amdgcn_global_load_lds(
      (const __attribute__((address_space(1))) void*)g,
      (__attribute__((address_space(3))) void*)l, 16, 0, 0);
}

// ---------------------------------------------------------------------------
// segmentation: wave-per-row ballot scan; also zeros loss accumulators
// ---------------------------------------------------------------------------
__global__ void k_seg_init(int* __restrict__ dur, int* __restrict__ segst,
                           float* __restrict__ lacc) {
  int i = blockIdx.x * blockDim.x + threadIdx.x;
  if (i < B_ * N_) { dur[i] = 0; segst[i] = 0x7fffffff; }
  if (i < 2) lacc[i] = 0.f;
}

__global__ __launch_bounds__(256) void k_seg_build(
    const float* __restrict__ align, int* __restrict__ idx,
    int* __restrict__ dur, int* __restrict__ segst) {
  int row = blockIdx.x * 4 + (threadIdx.x >> 6);    // b*T + t
  int lane = threadIdx.x & 63;
  const float* r = align + (size_t)row * N_;
  unsigned long long m0 = __ballot(r[lane] > 0.5f);
  unsigned long long m1 = __ballot(r[lane + 64] > 0.5f);
  if (lane == 0) {
    int n = m0 ? (__ffsll(m0) - 1) : (m1 ? (__ffsll(m1) - 1 + 64) : 0);
    idx[row] = n;
    int b = row >> 10, t = row & 1023;
    atomicAdd(&dur[b * N_ + n], 1);
    atomicMin(&segst[b * N_ + n], t);
  }
}

// ---------------------------------------------------------------------------
// fp32 -> bf16, 4 elems/thread
// ---------------------------------------------------------------------------
__global__ void k_f2b4(const float* __restrict__ in, bf16* __restrict__ out, int n4) {
  int gid = blockIdx.x * blockDim.x + threadIdx.x;
  if (gid >= n4) return;
  float4v v = *(const float4v*)(in + (size_t)gid * 4);
  bf16 o[4] = {bf16(v.x), bf16(v.y), bf16(v.z), bf16(v.w)};
  *(ulong1*)(out + (size_t)gid * 4) = *(ulong1*)o;
}

__global__ void k_build_queries(const float* __restrict__ emb, const float* __restrict__ lq,
                                bf16* __restrict__ out) {
  int gid = blockIdx.x * blockDim.x + threadIdx.x;
  if (gid >= B_ * N_ * Q_ * D_) return;
  int d = gid & (D_ - 1);
  int row = gid >> 9;
  int j = row & 3;
  int bn = row >> 2;
  float v = (j == 0) ? emb[(size_t)bn * D_ + d] : lq[(j - 1) * D_ + d];
  out[gid] = bf16(v);
}

// conv weight repacks to bf16 [co][K] matching A-panel k = tap*C + ci
// conv1 K padded to 256 (zeros beyond 195)
__global__ void k_w1t(const float* __restrict__ w, bf16* __restrict__ wt) {
  int gid = blockIdx.x * blockDim.x + threadIdx.x;
  if (gid >= 512 * 256) return;
  int kk = gid & 255; int c = gid >> 8;
  float v = 0.f;
  if (kk < 195) { int tap = kk / 65, i = kk - tap * 65; v = w[c * 195 + i * 3 + tap]; }
  wt[gid] = bf16(v);
}
__global__ void k_w2t(const float* __restrict__ w, bf16* __restrict__ wt) {
  int gid = blockIdx.x * blockDim.x + threadIdx.x;
  if (gid >= 512 * 1536) return;
  int kk = gid % 1536; int co = gid / 1536;
  int tap = kk >> 9, ci = kk & 511;
  wt[gid] = bf16(w[co * 1536 + ci * 3 + tap]);
}

// ---------------------------------------------------------------------------
// bf16 MFMA GEMM, 128x128 tile, BK=64, 8 waves (2x4, 64x32 each), depth-4
// pipelined global_load_lds, counted vmcnt, LDS slot swizzle (pre-swizzled
// source + swizzled read; linear gload_lds dest).
//   EPI: 0 none, 1 silu, 3 raw partial (split-K), 4 none + fused L1/L2 loss
//   APAD: A physical row = m + 2*(m>>10); CMODE: C row = m + 2*(m>>10) + 1
// M%128==0, Nc%128==0, K%64==0.
// ---------------------------------------------------------------------------
template<int EPI, int APAD, int CMODE, typename CT>
__global__ __launch_bounds__(512) void k_mgemm(
    const bf16* __restrict__ A, int lda,
    const bf16* __restrict__ W, int ldw,
    const float* __restrict__ bias,
    CT* __restrict__ C, int ldc,
    int M, int Nc, int K,
    const float* __restrict__ xref = nullptr,
    float* __restrict__ lacc = nullptr)
{
  __shared__ __align__(16) short As[4][8192];
  __shared__ __align__(16) short Bs[4][8192];
  const int tid = threadIdx.x;
  const int m0 = blockIdx.y * 128;
  const int n0 = blockIdx.x * 128;
  const int kbase = blockIdx.z * K;
  const int w = tid >> 6, lane = tid & 63;
  const int wm = (w >> 2) * 64, wn = (w & 3) * 32;
  const int lr = lane & 15;
  const int cg = lane >> 4;                 // k-chunk group 0..3

  // staging: thread t covers rows (t>>3) and (t>>3)+64, slot t&7 (16B chunks
  // of the 128B row). Source chunk pre-swizzled: LDS slot s holds global
  // chunk s ^ (row&7); row&7 identical for both rows (+64).
  const int r0 = tid >> 3;
  const int srcoff = (((tid & 7) ^ (r0 & 7)) << 3);
  int gmA0 = m0 + r0, gmA1 = m0 + r0 + 64;
  int ar0 = APAD ? gmA0 + ((gmA0 >> 10) << 1) : gmA0;
  int ar1 = APAD ? gmA1 + ((gmA1 >> 10) << 1) : gmA1;
  const size_t aOff0 = (size_t)ar0 * lda + kbase + srcoff;
  const size_t aOff1 = (size_t)ar1 * lda + kbase + srcoff;
  const size_t wOff0 = (size_t)(n0 + r0) * ldw + kbase + srcoff;
  const size_t wOff1 = (size_t)(n0 + r0 + 64) * ldw + kbase + srcoff;

  const int nt = K >> 6;

#define STAGE_(tt, buf) do { \
    size_t kk_ = (size_t)(tt) * 64; \
    gload16(A + aOff0 + kk_, &As[buf][tid * 8]); \
    gload16(A + aOff1 + kk_, &As[buf][4096 + tid * 8]); \
    gload16(W + wOff0 + kk_, &Bs[buf][tid * 8]); \
    gload16(W + wOff1 + kk_, &Bs[buf][4096 + tid * 8]); \
  } while (0)

  STAGE_(0, 0);
  if (nt > 1) STAGE_(1, 1);
  if (nt > 2) STAGE_(2, 2);

  f32x4 acc[4][2] = {};
  int cur = 0;
  for (int t = 0; t < nt; ++t) {
    if (t + 3 < nt) {
      STAGE_(t + 3, (cur + 3) & 3);
      asm volatile("s_waitcnt vmcnt(12)" ::: "memory");
    } else if (t + 2 < nt) {
      asm volatile("s_waitcnt vmcnt(8)" ::: "memory");
    } else if (t + 1 < nt) {
      asm volatile("s_waitcnt vmcnt(4)" ::: "memory");
    } else {
      asm volatile("s_waitcnt vmcnt(0)" ::: "memory");
    }
    __builtin_amdgcn_sched_barrier(0);
    __builtin_amdgcn_s_barrier();
    __builtin_amdgcn_sched_barrier(0);
#pragma unroll
    for (int h = 0; h < 2; ++h) {
      short8v af[4], bfv[2];
#pragma unroll
      for (int i = 0; i < 4; ++i) {
        int rr = wm + i * 16 + lr;
        af[i] = *(const short8v*)&As[cur][rr * 64 + (((h * 4 + cg) ^ (rr & 7)) << 3)];
      }
#pragma unroll
      for (int j = 0; j < 2; ++j) {
        int rr = wn + j * 16 + lr;
        bfv[j] = *(const short8v*)&Bs[cur][rr * 64 + (((h * 4 + cg) ^ (rr & 7)) << 3)];
      }
      __builtin_amdgcn_s_setprio(1);
#pragma unroll
      for (int i = 0; i < 4; ++i)
#pragma unroll
        for (int j = 0; j < 2; ++j)
          acc[i][j] = __builtin_amdgcn_mfma_f32_16x16x32_bf16(af[i], bfv[j], acc[i][j], 0, 0, 0);
      __builtin_amdgcn_s_setprio(0);
    }
    __builtin_amdgcn_sched_barrier(0);
    __builtin_amdgcn_s_barrier();
    __builtin_amdgcn_sched_barrier(0);
    cur = (cur + 1) & 3;
  }
#undef STAGE_

  if (EPI == 3) C += (size_t)blockIdx.z * M * ldc;
  const int orow = (lane >> 4) * 4;
  const int ocol = lane & 15;
  float la = 0.f, lb = 0.f;
#pragma unroll
  for (int i = 0; i < 4; ++i) {
#pragma unroll
    for (int q = 0; q < 4; ++q) {
      int gm = m0 + wm + i * 16 + orow + q;
      int cr = CMODE ? gm + ((gm >> 10) << 1) + 1 : gm;
#pragma unroll
      for (int j = 0; j < 2; ++j) {
        int gn = n0 + wn + j * 16 + ocol;
        float v = acc[i][j][q];
        if (EPI != 3) v += bias[gn];
        if (EPI == 1) v = v / (1.f + __expf(-v));
        if (EPI == 4) {
          float diff = xref[(size_t)gm * Nc + gn] - v;
          la += fabsf(diff);
          lb += diff * diff;
        }
        C[(size_t)cr * ldc + gn] = (CT)v;
      }
    }
  }
  if (EPI == 4) {
    __shared__ float sh1[8], sh2[8];
#pragma unroll
    for (int off = 32; off; off >>= 1) { la += __shfl_xor(la, off); lb += __shfl_xor(lb, off); }
    if (lane == 0) { sh1[w] = la; sh2[w] = lb; }
    __syncthreads();
    if (tid == 0) {
      float s1 = 0.f, s2 = 0.f;
#pragma unroll
      for (int i = 0; i < 8; ++i) { s1 += sh1[i]; s2 += sh2[i]; }
      atomicAdd(&lacc[0], s1);
      atomicAdd(&lacc[1], s2);
    }
  }
}

// split-K epilogue for bottleneck: sum 4 partials + bias, silu, + pooled
__global__ __launch_bounds__(256) void k_bot_epi(
    const float* __restrict__ part, const float* __restrict__ bias,
    const float* __restrict__ pooled, float* __restrict__ hidden) {
  int gid = blockIdx.x * blockDim.x + threadIdx.x;
  if (gid >= 1024 * 512) return;
  int n = gid & 511;
  const size_t S = 1024ull * 512;
  float v = part[gid] + part[gid + S] + part[gid + 2 * S] + part[gid + 3 * S] + bias[n];
  v = v / (1.f + __expf(-v));
  hidden[gid] = v + pooled[gid];
}

// ---------------------------------------------------------------------------
// segment attention, one pass, all 8 heads at once.
// lane owns d = lane*8 .. lane*8+8 (head = lane>>3); wave w = query j.
// ---------------------------------------------------------------------------
__global__ __launch_bounds__(256) void k_attn(
    const bf16* __restrict__ qbuf, const bf16* __restrict__ kv,
    const int* __restrict__ segst, const int* __restrict__ dur,
    bf16* __restrict__ ctx)
{
  int bn = blockIdx.x;
  int b = bn >> 7;
  int w = threadIdx.x >> 6;
  int lane = threadIdx.x & 63;
  int s0 = segst[bn], cnt = dur[bn];
  if (cnt == 0) { s0 = 0; cnt = T_; }
  size_t qrow = (size_t)bn * 4 + w;
  const bf16* kvb = kv + ((size_t)b * T_ + s0) * 1024;

  float qf[8];
  {
    uint4v qv = *(const uint4v*)(qbuf + qrow * 512 + lane * 8);
#pragma unroll
    for (int i = 0; i < 4; ++i) {
      unsigned u = qv[i];
      qf[2 * i]     = __uint_as_float(u << 16);
      qf[2 * i + 1] = __uint_as_float(u & 0xffff0000u);
    }
  }

  float m = -1e30f, l = 0.f;
  float o[8] = {};
  for (int s = 0; s < cnt; s += 4) {
    float sc4[4];
#pragma unroll
    for (int u = 0; u < 4; ++u) {
      int ss = s + u;
      int sscl = (ss < cnt) ? ss : (cnt - 1);
      uint4v kr = *(const uint4v*)(kvb + (size_t)sscl * 1024 + lane * 8);
      float d0 = 0.f;
#pragma unroll
      for (int i = 0; i < 4; ++i) {
        unsigned uu = kr[i];
        d0 = fmaf(qf[2 * i],     __uint_as_float(uu << 16),         d0);
        d0 = fmaf(qf[2 * i + 1], __uint_as_float(uu & 0xffff0000u), d0);
      }
      d0 += __shfl_xor(d0, 1);
      d0 += __shfl_xor(d0, 2);
      d0 += __shfl_xor(d0, 4);
      sc4[u] = (ss < cnt) ? d0 * 0.125f : -1e30f;
    }
    float cmax = fmaxf(fmaxf(sc4[0], sc4[1]), fmaxf(sc4[2], sc4[3]));
    float mn = fmaxf(m, cmax);
    float c = __expf(m - mn);
    float p[4];
#pragma unroll
    for (int u = 0; u < 4; ++u) p[u] = __expf(sc4[u] - mn);
    l = l * c + p[0] + p[1] + p[2] + p[3];
#pragma unroll
    for (int k = 0; k < 8; ++k) o[k] *= c;
#pragma unroll
    for (int u = 0; u < 4; ++u) {
      int ss = s + u;
      int sscl = (ss < cnt) ? ss : (cnt - 1);
      uint4v vr = *(const uint4v*)(kvb + (size_t)sscl * 1024 + 512 + lane * 8);
      float pu = p[u];
#pragma unroll
      for (int i = 0; i < 4; ++i) {
        unsigned uu = vr[i];
        o[2 * i]     = fmaf(pu, __uint_as_float(uu << 16),         o[2 * i]);
        o[2 * i + 1] = fmaf(pu, __uint_as_float(uu & 0xffff0000u), o[2 * i + 1]);
      }
    }
    m = mn;
  }
  float invl = 1.f / l;
  bf16 ob[8];
#pragma unroll
  for (int k = 0; k < 8; ++k) ob[k] = bf16(o[k] * invl);
  *(uint4v*)(ctx + qrow * 512 + lane * 8) = *(uint4v*)ob;
}

// ---------------------------------------------------------------------------
// layernorm of (queries + attn_out) -> bf16 qn
// ---------------------------------------------------------------------------
__global__ __launch_bounds__(256) void k_ln(
    const float* __restrict__ emb, const float* __restrict__ lq,
    const float* __restrict__ attn,
    const float* __restrict__ g, const float* __restrict__ bb,
    bf16* __restrict__ qn)
{
  int r = blockIdx.x * 4 + (threadIdx.x >> 6);
  int lane = threadIdx.x & 63;
  int bn = r >> 2, j = r & 3;
  const float* src = (j == 0) ? emb + (size_t)bn * D_ : lq + (size_t)(j - 1) * D_;
  float h[8];
  float s = 0.f, s2 = 0.f;
#pragma unroll
  for (int i = 0; i < 8; ++i) {
    int d = i * 64 + lane;
    float v = src[d] + attn[(size_t)r * D_ + d];
    h[i] = v; s += v; s2 += v * v;
  }
#pragma unroll
  for (int off = 32; off; off >>= 1) { s += __shfl_xor(s, off); s2 += __shfl_xor(s2, off); }
  float mean = s * (1.f / 512.f);
  float var = s2 * (1.f / 512.f) - mean * mean;
  float inv = rsqrtf(var + 1e-5f);
#pragma unroll
  for (int i = 0; i < 8; ++i) {
    int d = i * 64 + lane;
    qn[(size_t)r * D_ + d] = bf16((h[i] - mean) * inv * g[d] + bb[d]);
  }
}

// ---------------------------------------------------------------------------
// pooled[b,n,d] = segment mean of x
// ---------------------------------------------------------------------------
__global__ __launch_bounds__(256) void k_pool(
    const float* __restrict__ x, const int* __restrict__ segst,
    const int* __restrict__ dur, float* __restrict__ pooled)
{
  int bn = blockIdx.x;
  int b = bn >> 7;
  int s0 = segst[bn], cnt = dur[bn];
  int d0 = threadIdx.x;
  float a0 = 0.f, a1 = 0.f;
  for (int i = 0; i < cnt; ++i) {
    const float* xr = x + (size_t)(b * T_ + s0 + i) * D_;
    a0 += xr[d0];
    a1 += xr[d0 + 256];
  }
  float inv = 1.f / ((float)cnt + 1e-8f);
  pooled[(size_t)bn * D_ + d0] = a0 * inv;
  pooled[(size_t)bn * D_ + d0 + 256] = a1 * inv;
}

// ---------------------------------------------------------------------------
// mu/logvar/z + KL partial
// ---------------------------------------------------------------------------
__global__ __launch_bounds__(128) void k_muz(
    const float* __restrict__ hidden,
    const float* __restrict__ mu_w, const float* __restrict__ mu_b,
    const float* __restrict__ lv_w, const float* __restrict__ lv_b,
    const float* __restrict__ eps, float* __restrict__ z, float* __restrict__ klpart)
{
  __shared__ float hs[512];
  __shared__ float ms[64], ls[64];
  int bn = blockIdx.x;
  int tid = threadIdx.x;
  for (int i = tid; i < 512; i += 128) hs[i] = hidden[(size_t)bn * 512 + i];
  __syncthreads();
  int ld = tid & 63;
  const float* wrow = (tid < 64) ? (mu_w + (size_t)ld * 512) : (lv_w + (size_t)ld * 512);
  float acc = 0.f;
  for (int k = 0; k < 512; ++k) acc = fmaf(hs[k], wrow[k], acc);
  acc += (tid < 64) ? mu_b[ld] : lv_b[ld];
  if (tid < 64) ms[ld] = acc; else ls[ld] = acc;
  __syncthreads();
  if (tid < 64) {
    float mu = ms[ld], lv = ls[ld];
    z[(size_t)bn * 64 + ld] = mu + eps[(size_t)bn * 64 + ld] * expf(0.5f * lv);
    float klt = 1.f + lv - mu * mu - expf(lv);
#pragma unroll
    for (int off = 32; off; off >>= 1) klt += __shfl_xor(klt, off);
    if (ld == 0) klpart[bn] = klt;
  }
}

// ---------------------------------------------------------------------------
// im2col A for conv1: azc bf16 [8192][256], k = tap*65 + c, zero-padded K
// ---------------------------------------------------------------------------
__global__ void k_azc(const float* __restrict__ z, const int* __restrict__ idx,
                      const int* __restrict__ segst, const int* __restrict__ dur,
                      bf16* __restrict__ azc)
{
  int gid = blockIdx.x * blockDim.x + threadIdx.x;
  if (gid >= 8192 * 256) return;
  int k = gid & 255;
  int m = gid >> 8;
  int b = m >> 10, t = m & 1023;
  float v = 0.f;
  if (k < 195) {
    int tap = k / 65, c = k - tap * 65;
    int tt = t + tap - 1;
    if (tt >= 0 && tt < T_) {
      int iv = idx[b * T_ + tt];
      if (c < 64) v = z[(size_t)(b * N_ + iv) * 64 + c];
      else {
        int s0 = segst[b * N_ + iv];
        float d = (float)dur[b * N_ + iv];
        v = ((float)(tt - s0) + 0.5f) / d;
      }
    }
  }
  azc[gid] = bf16(v);
}

// zero pad rows of y1p (bf16)
__global__ void k_zero_pad(bf16* __restrict__ y1p) {
  int gid = blockIdx.x * blockDim.x + threadIdx.x;
  if (gid >= B_ * 2 * 512) return;
  int d = gid & 511;
  int rest = gid >> 9;
  int which = rest & 1;
  int b = rest >> 1;
  int rr = which ? (T_ + 1) : 0;
  y1p[(size_t)(b * (T_ + 2) + rr) * 512 + d] = bf16(0.f);
}

// ---------------------------------------------------------------------------
// final scalar outputs
// ---------------------------------------------------------------------------
__global__ __launch_bounds__(256) void k_final(
    const float* __restrict__ klpart, const float* __restrict__ lacc,
    const float* __restrict__ klw, float* __restrict__ out)
{
  __shared__ float sa[4];
  float a = 0.f;
  for (int i = threadIdx.x; i < 1024; i += 256) a += klpart[i];
#pragma unroll
  for (int off = 32; off; off >>= 1) a += __shfl_xor(a, off);
  int w = threadIdx.x >> 6, lane = threadIdx.x & 63;
  if (lane == 0) sa[w] = a;
  __syncthreads();
  if (threadIdx.x == 0) {
    float kl = sa[0] + sa[1] + sa[2] + sa[3];
    out[(size_t)B_ * T_ * D_]     = -0.5f * kl * klw[0];
    out[(size_t)B_ * T_ * D_ + 1] = (lacc[0] + lacc[1]) / (float)(B_ * T_ * D_);
  }
}

// ---------------------------------------------------------------------------
extern "C" void kernel_launch(void* const* d_in, const int* in_sizes, int n_in,
                              void* d_out, int out_size, void* d_ws, size_t ws_size,
                              hipStream_t stream)
{
  const float* emb  = (const float*)d_in[0];
  const float* algn = (const float*)d_in[1];
  const float* x    = (const float*)d_in[2];
  const float* klw  = (const float*)d_in[5];
  const float* eps  = (const float*)d_in[6];
  const float* lq   = (const float*)d_in[7];
  const float* inw  = (const float*)d_in[8];
  const float* inb  = (const float*)d_in[9];
  const float* outw = (const float*)d_in[10];
  const float* outb = (const float*)d_in[11];
  const float* lng  = (const float*)d_in[12];
  const float* lnb  = (const float*)d_in[13];
  const float* botw = (const float*)d_in[14];
  const float* botb = (const float*)d_in[15];
  const float* muw  = (const float*)d_in[16];
  const float* mub  = (const float*)d_in[17];
  const float* lvw  = (const float*)d_in[18];
  const float* lvb  = (const float*)d_in[19];
  const float* c1w  = (const float*)d_in[20];
  const float* c1b  = (const float*)d_in[21];
  const float* c2w  = (const float*)d_in[22];
  const float* c2b  = (const float*)d_in[23];
  float* out = (float*)d_out;

  float* ws = (float*)d_ws;
  size_t o = 0;
  auto allocF = [&](size_t n) { float* p = ws + o; o += n; return p; };
  auto allocB = [&](size_t n) { bf16* p = (bf16*)(ws + o); o += (n + 1) / 2; return p; };

  bf16* kvB    = allocB(8192ull * 1024);
  bf16* xb     = allocB(8192ull * 512);     // dead after kv GEMM; azc aliases it
  bf16* qryB   = allocB(4096ull * 512);
  bf16* qbufB  = allocB(4096ull * 512);
  bf16* ctxB   = allocB(4096ull * 512);
  bf16* qnB    = allocB(4096ull * 512);
  bf16* inwb   = allocB(1536ull * 512);
  bf16* outwb  = allocB(512ull * 512);
  bf16* botwb  = allocB(512ull * 2048);
  bf16* w1tb   = allocB(512ull * 256);
  bf16* w2tb   = allocB(512ull * 1536);
  bf16* y1p    = allocB(8ull * (T_ + 2) * 512);
  float* attnF  = allocF(4096ull * 512);    // dead after k_ln; botP aliases it
  float* pooled = allocF(1024ull * 512);
  float* hidden = allocF(1024ull * 512);
  float* zbuf   = allocF(1024ull * 64);
  float* klpart = allocF(1024);
  float* lacc   = allocF(2);
  int* idx   = (int*)(ws + o); o += 8192;
  int* segst = (int*)(ws + o); o += 1024;
  int* durI  = (int*)(ws + o); o += 1024;
  bf16* azc  = xb;                          // 8192*256 bf16 < 8192*512 bf16
  float* botP = attnF;                      // 4*1024*512 fp32 == 4096*512 fp32

  // segmentation + conversions + repacks
  k_seg_init<<<dim3((B_ * N_ + 255) / 256), 256, 0, stream>>>(durI, segst, lacc);
  k_seg_build<<<dim3(B_ * T_ / 4), 256, 0, stream>>>(algn, idx, durI, segst);
  k_f2b4<<<dim3(8192 * 512 / 4 / 256), 256, 0, stream>>>(x, xb, 8192 * 512 / 4);
  k_f2b4<<<dim3(1536 * 512 / 4 / 256), 256, 0, stream>>>(inw, inwb, 1536 * 512 / 4);
  k_f2b4<<<dim3(512 * 512 / 4 / 256), 256, 0, stream>>>(outw, outwb, 512 * 512 / 4);
  k_f2b4<<<dim3(512 * 2048 / 4 / 256), 256, 0, stream>>>(botw, botwb, 512 * 2048 / 4);
  k_w1t<<<dim3(512 * 256 / 256), 256, 0, stream>>>(c1w, w1tb);
  k_w2t<<<dim3(512 * 1536 / 256), 256, 0, stream>>>(c2w, w2tb);
  k_build_queries<<<dim3(B_ * N_ * Q_ * D_ / 256), 256, 0, stream>>>(emb, lq, qryB);

  // kv projection: [8192,512] x [1024,512]^T -> bf16 [8192,1024]
  k_mgemm<0, 0, 0, bf16><<<dim3(8, 64), 512, 0, stream>>>(
      xb, 512, inwb + 512 * 512, 512, inb + 512, kvB, 1024, 8192, 1024, 512);
  // q projection
  k_mgemm<0, 0, 0, bf16><<<dim3(4, 32), 512, 0, stream>>>(
      qryB, 512, inwb, 512, inb, qbufB, 512, 4096, 512, 512);

  k_attn<<<dim3(B_ * N_), 256, 0, stream>>>(qbufB, kvB, segst, durI, ctxB);

  // out projection -> fp32 attnF
  k_mgemm<0, 0, 0, float><<<dim3(4, 32), 512, 0, stream>>>(
      ctxB, 512, outwb, 512, outb, attnF, 512, 4096, 512, 512);

  k_ln<<<dim3(1024), 256, 0, stream>>>(emb, lq, attnF, lng, lnb, qnB);
  k_pool<<<dim3(B_ * N_), 256, 0, stream>>>(x, segst, durI, pooled);

  // bottleneck: split-K=4 partials + epilogue
  k_mgemm<3, 0, 0, float><<<dim3(4, 8, 4), 512, 0, stream>>>(
      qnB, 2048, botwb, 2048, nullptr, botP, 512, 1024, 512, 512);
  k_bot_epi<<<dim3(1024 * 512 / 256), 256, 0, stream>>>(botP, botb, pooled, hidden);

  k_muz<<<dim3(B_ * N_), 128, 0, stream>>>(hidden, muw, mub, lvw, lvb, eps, zbuf, klpart);
  k_azc<<<dim3(8192 * 256 / 256), 256, 0, stream>>>(zbuf, idx, segst, durI, azc);
  k_zero_pad<<<dim3((B_ * 2 * 512 + 255) / 256), 256, 0, stream>>>(y1p);

  // conv1: K padded to 256, silu -> bf16 y1p (padded rows, CMODE=1)
  k_mgemm<1, 0, 1, bf16><<<dim3(4, 64), 512, 0, stream>>>(
      azc, 256, w1tb, 256, c1b, y1p, 512, 8192, 512, 256);
  // conv2: padded A (APAD=1), K=1536 -> fp32 out, fused L1/L2 loss vs x
  k_mgemm<4, 1, 0, float><<<dim3(4, 64), 512, 0, stream>>>(
      y1p, 512, w2tb, 1536, c2b, out, 512, 8192, 512, 1536, x, lacc);

  k_final<<<dim3(1), 256, 0, stream>>>(klpart, lacc, klw, out);
}

// Round 7
// 194.814 us; speedup vs baseline: 5.8979x; 1.0025x over previous
//
#include <hip/hip_runtime.h>
#include <hip/hip_bf16.h>
#include <math.h>

#define B_  8
#define N_  128
#define T_  1024
#define D_  512
#define LD_ 64
#define H_  8
#define Q_  4

typedef __hip_bfloat16 bf16;
typedef __attribute__((ext_vector_type(8))) short short8v;
typedef __attribute__((ext_vector_type(4))) float f32x4;
typedef __attribute__((ext_vector_type(4))) float float4v;
typedef __attribute__((ext_vector_type(4))) unsigned int uint4v;

__device__ __forceinline__ void gload16(const void* g, void* l) {
  __builtin_amdgcn_global_load_lds(
      (const __attribute__((address_space(1))) void*)g,
      (__attribute__((address_space(3))) void*)l, 16, 0, 0);
}

// ---------------------------------------------------------------------------
// segmentation: wave-per-row ballot scan; also zeros loss accumulators
// ---------------------------------------------------------------------------
__global__ void k_seg_init(int* __restrict__ dur, int* __restrict__ segst,
                           float* __restrict__ lacc) {
  int i = blockIdx.x * blockDim.x + threadIdx.x;
  if (i < B_ * N_) { dur[i] = 0; segst[i] = 0x7fffffff; }
  if (i < 2) lacc[i] = 0.f;
}

__global__ __launch_bounds__(256) void k_seg_build(
    const float* __restrict__ align, int* __restrict__ idx,
    int* __restrict__ dur, int* __restrict__ segst) {
  int row = blockIdx.x * 4 + (threadIdx.x >> 6);    // b*T + t
  int lane = threadIdx.x & 63;
  const float* r = align + (size_t)row * N_;
  unsigned long long m0 = __ballot(r[lane] > 0.5f);
  unsigned long long m1 = __ballot(r[lane + 64] > 0.5f);
  if (lane == 0) {
    int n = m0 ? (__ffsll(m0) - 1) : (m1 ? (__ffsll(m1) - 1 + 64) : 0);
    idx[row] = n;
    int b = row >> 10, t = row & 1023;
    atomicAdd(&dur[b * N_ + n], 1);
    atomicMin(&segst[b * N_ + n], t);
  }
}

// ---------------------------------------------------------------------------
// fp32 -> bf16, 4 elems/thread
// ---------------------------------------------------------------------------
__global__ void k_f2b4(const float* __restrict__ in, bf16* __restrict__ out, int n4) {
  int gid = blockIdx.x * blockDim.x + threadIdx.x;
  if (gid >= n4) return;
  float4v v = *(const float4v*)(in + (size_t)gid * 4);
  bf16 o[4] = {bf16(v.x), bf16(v.y), bf16(v.z), bf16(v.w)};
  *(ulong1*)(out + (size_t)gid * 4) = *(ulong1*)o;
}

__global__ void k_build_queries(const float* __restrict__ emb, const float* __restrict__ lq,
                                bf16* __restrict__ out) {
  int gid = blockIdx.x * blockDim.x + threadIdx.x;
  if (gid >= B_ * N_ * Q_ * D_) return;
  int d = gid & (D_ - 1);
  int row = gid >> 9;
  int j = row & 3;
  int bn = row >> 2;
  float v = (j == 0) ? emb[(size_t)bn * D_ + d] : lq[(j - 1) * D_ + d];
  out[gid] = bf16(v);
}

// conv weight repacks to bf16 [co][K] matching A-panel k = tap*C + ci
// conv1 K padded to 256 (zeros beyond 195)
__global__ void k_w1t(const float* __restrict__ w, bf16* __restrict__ wt) {
  int gid = blockIdx.x * blockDim.x + threadIdx.x;
  if (gid >= 512 * 256) return;
  int kk = gid & 255; int c = gid >> 8;
  float v = 0.f;
  if (kk < 195) { int tap = kk / 65, i = kk - tap * 65; v = w[c * 195 + i * 3 + tap]; }
  wt[gid] = bf16(v);
}
__global__ void k_w2t(const float* __restrict__ w, bf16* __restrict__ wt) {
  int gid = blockIdx.x * blockDim.x + threadIdx.x;
  if (gid >= 512 * 1536) return;
  int kk = gid % 1536; int co = gid / 1536;
  int tap = kk >> 9, ci = kk & 511;
  wt[gid] = bf16(w[co * 1536 + ci * 3 + tap]);
}

// ---------------------------------------------------------------------------
// bf16 MFMA GEMM, 64x128 tile, BK=64, 4 waves (each 64x32), depth-3 pipelined
// global_load_lds (counted vmcnt), slot-XOR LDS swizzle, 72KB LDS ->
// 2 blocks/CU co-residency (the latency-hiding mechanism).
//   EPI: 0 none, 1 silu, 3 raw partial (split-K), 4 none + fused L1/L2 loss
//   APAD: A physical row = m + 2*(m>>10); CMODE: C row = m + 2*(m>>10) + 1
// M%64==0, Nc%128==0, K%64==0.
// ---------------------------------------------------------------------------
template<int EPI, int APAD, int CMODE, typename CT>
__global__ __launch_bounds__(256, 2) void k_mgemm(
    const bf16* __restrict__ A, int lda,
    const bf16* __restrict__ W, int ldw,
    const float* __restrict__ bias,
    CT* __restrict__ C, int ldc,
    int M, int Nc, int K,
    const float* __restrict__ xref = nullptr,
    float* __restrict__ lacc = nullptr)
{
  __shared__ __align__(16) short As[3][4096];   // 64 rows x 64 k
  __shared__ __align__(16) short Bs[3][8192];   // 128 rows x 64 k
  const int tid = threadIdx.x;
  const int m0 = blockIdx.y * 64;
  const int n0 = blockIdx.x * 128;
  const int kbase = blockIdx.z * K;
  const int w = tid >> 6, lane = tid & 63;
  const int wn = w * 32;
  const int lr = lane & 15;
  const int cg = lane >> 4;                      // k-chunk group 0..3

  // staging (per-wave): lane stages rows rA(+32) of A, rA+j*32 of B, at LDS
  // slot lane&7; source chunk pre-swizzled (slot ^ (row&7), row&7 == rg&7).
  const int rg = lane >> 3;                      // 0..7
  const int soff = (((lane & 7) ^ rg) << 3);     // element offset of 16B chunk
  const int rA = w * 8 + rg;                     // 0..31
  int gA0 = m0 + rA, gA1 = m0 + rA + 32;
  int ar0 = APAD ? gA0 + ((gA0 >> 10) << 1) : gA0;
  int ar1 = APAD ? gA1 + ((gA1 >> 10) << 1) : gA1;
  const size_t aOff0 = (size_t)ar0 * lda + kbase + soff;
  const size_t aOff1 = (size_t)ar1 * lda + kbase + soff;
  size_t wOffs[4];
#pragma unroll
  for (int j = 0; j < 4; ++j)
    wOffs[j] = (size_t)(n0 + rA + j * 32) * ldw + kbase + soff;

  const int nt = K >> 6;

#define STAGE_(tt, buf) do { \
    size_t kk_ = (size_t)(tt) * 64; \
    gload16(A + aOff0 + kk_, &As[buf][tid * 8]); \
    gload16(A + aOff1 + kk_, &As[buf][2048 + tid * 8]); \
    gload16(W + wOffs[0] + kk_, &Bs[buf][tid * 8]); \
    gload16(W + wOffs[1] + kk_, &Bs[buf][2048 + tid * 8]); \
    gload16(W + wOffs[2] + kk_, &Bs[buf][4096 + tid * 8]); \
    gload16(W + wOffs[3] + kk_, &Bs[buf][6144 + tid * 8]); \
  } while (0)

  STAGE_(0, 0);
  if (nt > 1) STAGE_(1, 1);

  f32x4 acc[4][2] = {};
  int cur = 0;
  for (int t = 0; t < nt; ++t) {
    if (t + 2 < nt) {
      int b2 = cur + 2; if (b2 >= 3) b2 -= 3;
      STAGE_(t + 2, b2);
      asm volatile("s_waitcnt vmcnt(12)" ::: "memory");
    } else if (t + 1 < nt) {
      asm volatile("s_waitcnt vmcnt(6)" ::: "memory");
    } else {
      asm volatile("s_waitcnt vmcnt(0)" ::: "memory");
    }
    __builtin_amdgcn_sched_barrier(0);
    __builtin_amdgcn_s_barrier();
    __builtin_amdgcn_sched_barrier(0);
#pragma unroll
    for (int h = 0; h < 2; ++h) {
      short8v af[4], bfv[2];
#pragma unroll
      for (int i = 0; i < 4; ++i) {
        int rr = i * 16 + lr;
        af[i] = *(const short8v*)&As[cur][rr * 64 + (((h * 4 + cg) ^ (rr & 7)) << 3)];
      }
#pragma unroll
      for (int j = 0; j < 2; ++j) {
        int rr = wn + j * 16 + lr;
        bfv[j] = *(const short8v*)&Bs[cur][rr * 64 + (((h * 4 + cg) ^ (rr & 7)) << 3)];
      }
      __builtin_amdgcn_s_setprio(1);
#pragma unroll
      for (int i = 0; i < 4; ++i)
#pragma unroll
        for (int j = 0; j < 2; ++j)
          acc[i][j] = __builtin_amdgcn_mfma_f32_16x16x32_bf16(af[i], bfv[j], acc[i][j], 0, 0, 0);
      __builtin_amdgcn_s_setprio(0);
    }
    __builtin_amdgcn_sched_barrier(0);
    __builtin_amdgcn_s_barrier();
    __builtin_amdgcn_sched_barrier(0);
    cur = (cur == 2) ? 0 : cur + 1;
  }
#undef STAGE_

  if (EPI == 3) C += (size_t)blockIdx.z * M * ldc;
  const int orow = (lane >> 4) * 4;
  const int ocol = lane & 15;
  float la = 0.f, lb = 0.f;
#pragma unroll
  for (int i = 0; i < 4; ++i) {
#pragma unroll
    for (int q = 0; q < 4; ++q) {
      int gm = m0 + i * 16 + orow + q;
      int cr = CMODE ? gm + ((gm >> 10) << 1) + 1 : gm;
#pragma unroll
      for (int j = 0; j < 2; ++j) {
        int gn = n0 + wn + j * 16 + ocol;
        float v = acc[i][j][q];
        if (EPI != 3) v += bias[gn];
        if (EPI == 1) v = v / (1.f + __expf(-v));
        if (EPI == 4) {
          float diff = xref[(size_t)gm * Nc + gn] - v;
          la += fabsf(diff);
          lb += diff * diff;
        }
        C[(size_t)cr * ldc + gn] = (CT)v;
      }
    }
  }
  if (EPI == 4) {
    __shared__ float sh1[4], sh2[4];
#pragma unroll
    for (int off = 32; off; off >>= 1) { la += __shfl_xor(la, off); lb += __shfl_xor(lb, off); }
    if (lane == 0) { sh1[w] = la; sh2[w] = lb; }
    __syncthreads();
    if (tid == 0) {
      atomicAdd(&lacc[0], sh1[0] + sh1[1] + sh1[2] + sh1[3]);
      atomicAdd(&lacc[1], sh2[0] + sh2[1] + sh2[2] + sh2[3]);
    }
  }
}

// split-K epilogue for bottleneck: sum 4 partials + bias, silu, + pooled
__global__ __launch_bounds__(256) void k_bot_epi(
    const float* __restrict__ part, const float* __restrict__ bias,
    const float* __restrict__ pooled, float* __restrict__ hidden) {
  int gid = blockIdx.x * blockDim.x + threadIdx.x;
  if (gid >= 1024 * 512) return;
  int n = gid & 511;
  const size_t S = 1024ull * 512;
  float v = part[gid] + part[gid + S] + part[gid + 2 * S] + part[gid + 3 * S] + bias[n];
  v = v / (1.f + __expf(-v));
  hidden[gid] = v + pooled[gid];
}

// ---------------------------------------------------------------------------
// segment attention, one pass, all 8 heads at once.
// lane owns d = lane*8 .. lane*8+8 (head = lane>>3); wave w = query j.
// ---------------------------------------------------------------------------
__global__ __launch_bounds__(256) void k_attn(
    const bf16* __restrict__ qbuf, const bf16* __restrict__ kv,
    const int* __restrict__ segst, const int* __restrict__ dur,
    bf16* __restrict__ ctx)
{
  int bn = blockIdx.x;
  int b = bn >> 7;
  int w = threadIdx.x >> 6;
  int lane = threadIdx.x & 63;
  int s0 = segst[bn], cnt = dur[bn];
  if (cnt == 0) { s0 = 0; cnt = T_; }
  size_t qrow = (size_t)bn * 4 + w;
  const bf16* kvb = kv + ((size_t)b * T_ + s0) * 1024;

  float qf[8];
  {
    uint4v qv = *(const uint4v*)(qbuf + qrow * 512 + lane * 8);
#pragma unroll
    for (int i = 0; i < 4; ++i) {
      unsigned u = qv[i];
      qf[2 * i]     = __uint_as_float(u << 16);
      qf[2 * i + 1] = __uint_as_float(u & 0xffff0000u);
    }
  }

  float m = -1e30f, l = 0.f;
  float o[8] = {};
  for (int s = 0; s < cnt; s += 4) {
    float sc4[4];
#pragma unroll
    for (int u = 0; u < 4; ++u) {
      int ss = s + u;
      int sscl = (ss < cnt) ? ss : (cnt - 1);
      uint4v kr = *(const uint4v*)(kvb + (size_t)sscl * 1024 + lane * 8);
      float d0 = 0.f;
#pragma unroll
      for (int i = 0; i < 4; ++i) {
        unsigned uu = kr[i];
        d0 = fmaf(qf[2 * i],     __uint_as_float(uu << 16),         d0);
        d0 = fmaf(qf[2 * i + 1], __uint_as_float(uu & 0xffff0000u), d0);
      }
      d0 += __shfl_xor(d0, 1);
      d0 += __shfl_xor(d0, 2);
      d0 += __shfl_xor(d0, 4);
      sc4[u] = (ss < cnt) ? d0 * 0.125f : -1e30f;
    }
    float cmax = fmaxf(fmaxf(sc4[0], sc4[1]), fmaxf(sc4[2], sc4[3]));
    float mn = fmaxf(m, cmax);
    float c = __expf(m - mn);
    float p[4];
#pragma unroll
    for (int u = 0; u < 4; ++u) p[u] = __expf(sc4[u] - mn);
    l = l * c + p[0] + p[1] + p[2] + p[3];
#pragma unroll
    for (int k = 0; k < 8; ++k) o[k] *= c;
#pragma unroll
    for (int u = 0; u < 4; ++u) {
      int ss = s + u;
      int sscl = (ss < cnt) ? ss : (cnt - 1);
      uint4v vr = *(const uint4v*)(kvb + (size_t)sscl * 1024 + 512 + lane * 8);
      float pu = p[u];
#pragma unroll
      for (int i = 0; i < 4; ++i) {
        unsigned uu = vr[i];
        o[2 * i]     = fmaf(pu, __uint_as_float(uu << 16),         o[2 * i]);
        o[2 * i + 1] = fmaf(pu, __uint_as_float(uu & 0xffff0000u), o[2 * i + 1]);
      }
    }
    m = mn;
  }
  float invl = 1.f / l;
  bf16 ob[8];
#pragma unroll
  for (int k = 0; k < 8; ++k) ob[k] = bf16(o[k] * invl);
  *(uint4v*)(ctx + qrow * 512 + lane * 8) = *(uint4v*)ob;
}

// ---------------------------------------------------------------------------
// layernorm of (queries + attn_out) -> bf16 qn
// ---------------------------------------------------------------------------
__global__ __launch_bounds__(256) void k_ln(
    const float* __restrict__ emb, const float* __restrict__ lq,
    const float* __restrict__ attn,
    const float* __restrict__ g, const float* __restrict__ bb,
    bf16* __restrict__ qn)
{
  int r = blockIdx.x * 4 + (threadIdx.x >> 6);
  int lane = threadIdx.x & 63;
  int bn = r >> 2, j = r & 3;
  const float* src = (j == 0) ? emb + (size_t)bn * D_ : lq + (size_t)(j - 1) * D_;
  float h[8];
  float s = 0.f, s2 = 0.f;
#pragma unroll
  for (int i = 0; i < 8; ++i) {
    int d = i * 64 + lane;
    float v = src[d] + attn[(size_t)r * D_ + d];
    h[i] = v; s += v; s2 += v * v;
  }
#pragma unroll
  for (int off = 32; off; off >>= 1) { s += __shfl_xor(s, off); s2 += __shfl_xor(s2, off); }
  float mean = s * (1.f / 512.f);
  float var = s2 * (1.f / 512.f) - mean * mean;
  float inv = rsqrtf(var + 1e-5f);
#pragma unroll
  for (int i = 0; i < 8; ++i) {
    int d = i * 64 + lane;
    qn[(size_t)r * D_ + d] = bf16((h[i] - mean) * inv * g[d] + bb[d]);
  }
}

// ---------------------------------------------------------------------------
// pooled[b,n,d] = segment mean of x
// ---------------------------------------------------------------------------
__global__ __launch_bounds__(256) void k_pool(
    const float* __restrict__ x, const int* __restrict__ segst,
    const int* __restrict__ dur, float* __restrict__ pooled)
{
  int bn = blockIdx.x;
  int b = bn >> 7;
  int s0 = segst[bn], cnt = dur[bn];
  int d0 = threadIdx.x;
  float a0 = 0.f, a1 = 0.f;
  for (int i = 0; i < cnt; ++i) {
    const float* xr = x + (size_t)(b * T_ + s0 + i) * D_;
    a0 += xr[d0];
    a1 += xr[d0 + 256];
  }
  float inv = 1.f / ((float)cnt + 1e-8f);
  pooled[(size_t)bn * D_ + d0] = a0 * inv;
  pooled[(size_t)bn * D_ + d0 + 256] = a1 * inv;
}

// ---------------------------------------------------------------------------
// mu/logvar/z + KL partial
// ---------------------------------------------------------------------------
__global__ __launch_bounds__(128) void k_muz(
    const float* __restrict__ hidden,
    const float* __restrict__ mu_w, const float* __restrict__ mu_b,
    const float* __restrict__ lv_w, const float* __restrict__ lv_b,
    const float* __restrict__ eps, float* __restrict__ z, float* __restrict__ klpart)
{
  __shared__ float hs[512];
  __shared__ float ms[64], ls[64];
  int bn = blockIdx.x;
  int tid = threadIdx.x;
  for (int i = tid; i < 512; i += 128) hs[i] = hidden[(size_t)bn * 512 + i];
  __syncthreads();
  int ld = tid & 63;
  const float* wrow = (tid < 64) ? (mu_w + (size_t)ld * 512) : (lv_w + (size_t)ld * 512);
  float acc = 0.f;
  for (int k = 0; k < 512; ++k) acc = fmaf(hs[k], wrow[k], acc);
  acc += (tid < 64) ? mu_b[ld] : lv_b[ld];
  if (tid < 64) ms[ld] = acc; else ls[ld] = acc;
  __syncthreads();
  if (tid < 64) {
    float mu = ms[ld], lv = ls[ld];
    z[(size_t)bn * 64 + ld] = mu + eps[(size_t)bn * 64 + ld] * expf(0.5f * lv);
    float klt = 1.f + lv - mu * mu - expf(lv);
#pragma unroll
    for (int off = 32; off; off >>= 1) klt += __shfl_xor(klt, off);
    if (ld == 0) klpart[bn] = klt;
  }
}

// ---------------------------------------------------------------------------
// im2col A for conv1: azc bf16 [8192][256], k = tap*65 + c, zero-padded K
// ---------------------------------------------------------------------------
__global__ void k_azc(const float* __restrict__ z, const int* __restrict__ idx,
                      const int* __restrict__ segst, const int* __restrict__ dur,
                      bf16* __restrict__ azc)
{
  int gid = blockIdx.x * blockDim.x + threadIdx.x;
  if (gid >= 8192 * 256) return;
  int k = gid & 255;
  int m = gid >> 8;
  int b = m >> 10, t = m & 1023;
  float v = 0.f;
  if (k < 195) {
    int tap = k / 65, c = k - tap * 65;
    int tt = t + tap - 1;
    if (tt >= 0 && tt < T_) {
      int iv = idx[b * T_ + tt];
      if (c < 64) v = z[(size_t)(b * N_ + iv) * 64 + c];
      else {
        int s0 = segst[b * N_ + iv];
        float d = (float)dur[b * N_ + iv];
        v = ((float)(tt - s0) + 0.5f) / d;
      }
    }
  }
  azc[gid] = bf16(v);
}

// zero pad rows of y1p (bf16)
__global__ void k_zero_pad(bf16* __restrict__ y1p) {
  int gid = blockIdx.x * blockDim.x + threadIdx.x;
  if (gid >= B_ * 2 * 512) return;
  int d = gid & 511;
  int rest = gid >> 9;
  int which = rest & 1;
  int b = rest >> 1;
  int rr = which ? (T_ + 1) : 0;
  y1p[(size_t)(b * (T_ + 2) + rr) * 512 + d] = bf16(0.f);
}

// ---------------------------------------------------------------------------
// final scalar outputs
// ---------------------------------------------------------------------------
__global__ __launch_bounds__(256) void k_final(
    const float* __restrict__ klpart, const float* __restrict__ lacc,
    const float* __restrict__ klw, float* __restrict__ out)
{
  __shared__ float sa[4];
  float a = 0.f;
  for (int i = threadIdx.x; i < 1024; i += 256) a += klpart[i];
#pragma unroll
  for (int off = 32; off; off >>= 1) a += __shfl_xor(a, off);
  int w = threadIdx.x >> 6, lane = threadIdx.x & 63;
  if (lane == 0) sa[w] = a;
  __syncthreads();
  if (threadIdx.x == 0) {
    float kl = sa[0] + sa[1] + sa[2] + sa[3];
    out[(size_t)B_ * T_ * D_]     = -0.5f * kl * klw[0];
    out[(size_t)B_ * T_ * D_ + 1] = (lacc[0] + lacc[1]) / (float)(B_ * T_ * D_);
  }
}

// ---------------------------------------------------------------------------
extern "C" void kernel_launch(void* const* d_in, const int* in_sizes, int n_in,
                              void* d_out, int out_size, void* d_ws, size_t ws_size,
                              hipStream_t stream)
{
  const float* emb  = (const float*)d_in[0];
  const float* algn = (const float*)d_in[1];
  const float* x    = (const float*)d_in[2];
  const float* klw  = (const float*)d_in[5];
  const float* eps  = (const float*)d_in[6];
  const float* lq   = (const float*)d_in[7];
  const float* inw  = (const float*)d_in[8];
  const float* inb  = (const float*)d_in[9];
  const float* outw = (const float*)d_in[10];
  const float* outb = (const float*)d_in[11];
  const float* lng  = (const float*)d_in[12];
  const float* lnb  = (const float*)d_in[13];
  const float* botw = (const float*)d_in[14];
  const float* botb = (const float*)d_in[15];
  const float* muw  = (const float*)d_in[16];
  const float* mub  = (const float*)d_in[17];
  const float* lvw  = (const float*)d_in[18];
  const float* lvb  = (const float*)d_in[19];
  const float* c1w  = (const float*)d_in[20];
  const float* c1b  = (const float*)d_in[21];
  const float* c2w  = (const float*)d_in[22];
  const float* c2b  = (const float*)d_in[23];
  float* out = (float*)d_out;

  float* ws = (float*)d_ws;
  size_t o = 0;
  auto allocF = [&](size_t n) { float* p = ws + o; o += n; return p; };
  auto allocB = [&](size_t n) { bf16* p = (bf16*)(ws + o); o += (n + 1) / 2; return p; };

  bf16* kvB    = allocB(8192ull * 1024);
  bf16* xb     = allocB(8192ull * 512);     // dead after kv GEMM; azc aliases it
  bf16* qryB   = allocB(4096ull * 512);
  bf16* qbufB  = allocB(4096ull * 512);
  bf16* ctxB   = allocB(4096ull * 512);
  bf16* qnB    = allocB(4096ull * 512);
  bf16* inwb   = allocB(1536ull * 512);
  bf16* outwb  = allocB(512ull * 512);
  bf16* botwb  = allocB(512ull * 2048);
  bf16* w1tb   = allocB(512ull * 256);
  bf16* w2tb   = allocB(512ull * 1536);
  bf16* y1p    = allocB(8ull * (T_ + 2) * 512);
  float* attnF  = allocF(4096ull * 512);    // dead after k_ln; botP aliases it
  float* pooled = allocF(1024ull * 512);
  float* hidden = allocF(1024ull * 512);
  float* zbuf   = allocF(1024ull * 64);
  float* klpart = allocF(1024);
  float* lacc   = allocF(2);
  int* idx   = (int*)(ws + o); o += 8192;
  int* segst = (int*)(ws + o); o += 1024;
  int* durI  = (int*)(ws + o); o += 1024;
  bf16* azc  = xb;                          // 8192*256 bf16 < 8192*512 bf16
  float* botP = attnF;                      // 4*1024*512 fp32 == 4096*512 fp32

  // segmentation + conversions + repacks
  k_seg_init<<<dim3((B_ * N_ + 255) / 256), 256, 0, stream>>>(durI, segst, lacc);
  k_seg_build<<<dim3(B_ * T_ / 4), 256, 0, stream>>>(algn, idx, durI, segst);
  k_f2b4<<<dim3(8192 * 512 / 4 / 256), 256, 0, stream>>>(x, xb, 8192 * 512 / 4);
  k_f2b4<<<dim3(1536 * 512 / 4 / 256), 256, 0, stream>>>(inw, inwb, 1536 * 512 / 4);
  k_f2b4<<<dim3(512 * 512 / 4 / 256), 256, 0, stream>>>(outw, outwb, 512 * 512 / 4);
  k_f2b4<<<dim3(512 * 2048 / 4 / 256), 256, 0, stream>>>(botw, botwb, 512 * 2048 / 4);
  k_w1t<<<dim3(512 * 256 / 256), 256, 0, stream>>>(c1w, w1tb);
  k_w2t<<<dim3(512 * 1536 / 256), 256, 0, stream>>>(c2w, w2tb);
  k_build_queries<<<dim3(B_ * N_ * Q_ * D_ / 256), 256, 0, stream>>>(emb, lq, qryB);

  // kv projection: [8192,512] x [1024,512]^T -> bf16 [8192,1024]
  k_mgemm<0, 0, 0, bf16><<<dim3(8, 128), 256, 0, stream>>>(
      xb, 512, inwb + 512 * 512, 512, inb + 512, kvB, 1024, 8192, 1024, 512);
  // q projection
  k_mgemm<0, 0, 0, bf16><<<dim3(4, 64), 256, 0, stream>>>(
      qryB, 512, inwb, 512, inb, qbufB, 512, 4096, 512, 512);

  k_attn<<<dim3(B_ * N_), 256, 0, stream>>>(qbufB, kvB, segst, durI, ctxB);

  // out projection -> fp32 attnF
  k_mgemm<0, 0, 0, float><<<dim3(4, 64), 256, 0, stream>>>(
      ctxB, 512, outwb, 512, outb, attnF, 512, 4096, 512, 512);

  k_ln<<<dim3(1024), 256, 0, stream>>>(emb, lq, attnF, lng, lnb, qnB);
  k_pool<<<dim3(B_ * N_), 256, 0, stream>>>(x, segst, durI, pooled);

  // bottleneck: split-K=4 partials + epilogue
  k_mgemm<3, 0, 0, float><<<dim3(4, 16, 4), 256, 0, stream>>>(
      qnB, 2048, botwb, 2048, nullptr, botP, 512, 1024, 512, 512);
  k_bot_epi<<<dim3(1024 * 512 / 256), 256, 0, stream>>>(botP, botb, pooled, hidden);

  k_muz<<<dim3(B_ * N_), 128, 0, stream>>>(hidden, muw, mub, lvw, lvb, eps, zbuf, klpart);
  k_azc<<<dim3(8192 * 256 / 256), 256, 0, stream>>>(zbuf, idx, segst, durI, azc);
  k_zero_pad<<<dim3((B_ * 2 * 512 + 255) / 256), 256, 0, stream>>>(y1p);

  // conv1: K padded to 256, silu -> bf16 y1p (padded rows, CMODE=1)
  k_mgemm<1, 0, 1, bf16><<<dim3(4, 128), 256, 0, stream>>>(
      azc, 256, w1tb, 256, c1b, y1p, 512, 8192, 512, 256);
  // conv2: padded A (APAD=1), K=1536 -> fp32 out, fused L1/L2 loss vs x
  k_mgemm<4, 1, 0, float><<<dim3(4, 128), 256, 0, stream>>>(
      y1p, 512, w2tb, 1536, c2b, out, 512, 8192, 512, 1536, x, lacc);

  k_final<<<dim3(1), 256, 0, stream>>>(klpart, lacc, klw, out);
}

// Round 9
// 172.329 us; speedup vs baseline: 6.6675x; 1.1305x over previous
//
#include <hip/hip_runtime.h>
#include <hip/hip_bf16.h>
#include <math.h>

#define B_  8
#define N_  128
#define T_  1024
#define D_  512
#define LD_ 64
#define H_  8
#define Q_  4

typedef __hip_bfloat16 bf16;
typedef __attribute__((ext_vector_type(8))) short short8v;
typedef __attribute__((ext_vector_type(4))) float f32x4;
typedef __attribute__((ext_vector_type(4))) float float4v;
typedef __attribute__((ext_vector_type(4))) unsigned int uint4v;

__device__ __forceinline__ void gload16(const void* g, void* l) {
  __builtin_amdgcn_global_load_lds(
      (const __attribute__((address_space(1))) void*)g,
      (__attribute__((address_space(3))) void*)l, 16, 0, 0);
}

__device__ __forceinline__ void f2b4s(const float* in, bf16* out) {
  float4v v = *(const float4v*)in;
  bf16 o[4] = {bf16(v.x), bf16(v.y), bf16(v.z), bf16(v.w)};
  *(ulong1*)out = *(ulong1*)o;
}

// ---------------------------------------------------------------------------
// mega-prep: all dtype conversions / repacks / query build / seg+loss init
// in ONE launch (range-switched). Cumulative ranges:
//   [0, 1048576)           x -> xb, 4-wide            (8192*512/4)
//   [.., 1245184)          inw -> inwb, 4-wide        (1536*512/4)
//   [.., 1310720)          outw -> outwb, 4-wide      (512*512/4)
//   [.., 1572864)          botw -> botwb, 4-wide      (512*2048/4)
//   [.., 1703936)          conv1 repack, scalar       (512*256)
//   [.., 2490368)          conv2 repack, scalar       (512*1536)
//   [.., 3014656)          queries build, 4-wide      (4096*512/4 = 524288)
//   [.., 3015680)          dur/segst init             (1024)
//   [.., 3015682)          lacc zero                  (2)
// grid = ceil(3015682/256) = 11781
// ---------------------------------------------------------------------------
__global__ __launch_bounds__(256) void k_prep(
    const float* __restrict__ x, const float* __restrict__ inw,
    const float* __restrict__ outw, const float* __restrict__ botw,
    const float* __restrict__ c1w, const float* __restrict__ c2w,
    const float* __restrict__ emb, const float* __restrict__ lq,
    bf16* __restrict__ xb, bf16* __restrict__ inwb, bf16* __restrict__ outwb,
    bf16* __restrict__ botwb, bf16* __restrict__ w1tb, bf16* __restrict__ w2tb,
    bf16* __restrict__ qryB,
    int* __restrict__ dur, int* __restrict__ segst, float* __restrict__ lacc)
{
  int g = blockIdx.x * 256 + threadIdx.x;
  if (g < 1048576) {
    f2b4s(x + (size_t)g * 4, xb + (size_t)g * 4);
  } else if (g < 1245184) {
    int i = g - 1048576;
    f2b4s(inw + (size_t)i * 4, inwb + (size_t)i * 4);
  } else if (g < 1310720) {
    int i = g - 1245184;
    f2b4s(outw + (size_t)i * 4, outwb + (size_t)i * 4);
  } else if (g < 1572864) {
    int i = g - 1310720;
    f2b4s(botw + (size_t)i * 4, botwb + (size_t)i * 4);
  } else if (g < 1703936) {
    int i = g - 1572864;              // 512*256
    int kk = i & 255, c = i >> 8;
    float v = 0.f;
    if (kk < 195) { int tap = kk / 65, ii = kk - tap * 65; v = c1w[c * 195 + ii * 3 + tap]; }
    w1tb[i] = bf16(v);
  } else if (g < 2490368) {
    int i = g - 1703936;              // 512*1536
    int kk = i % 1536, co = i / 1536;
    int tap = kk >> 9, ci = kk & 511;
    w2tb[i] = bf16(c2w[co * 1536 + ci * 3 + tap]);
  } else if (g < 3014656) {
    int i4 = g - 2490368;             // 524288 items of 4 elems
    int e = i4 * 4;                   // element index < 2097152
    int d = e & 511;
    int row = e >> 9;                 // < 4096
    int j = row & 3;
    int bn = row >> 2;                // < 1024
    const float* src = (j == 0) ? emb + (size_t)bn * 512 + d
                                : lq + (size_t)(j - 1) * 512 + d;
    f2b4s(src, qryB + (size_t)e);
  } else if (g < 3015680) {
    int i = g - 3014656;
    dur[i] = 0; segst[i] = 0x7fffffff;
  } else if (g < 3015682) {
    lacc[g - 3015680] = 0.f;
  }
}

// ---------------------------------------------------------------------------
// segmentation: wave-per-row ballot scan (dur/segst pre-initialized by prep)
// ---------------------------------------------------------------------------
__global__ __launch_bounds__(256) void k_seg_build(
    const float* __restrict__ align, int* __restrict__ idx,
    int* __restrict__ dur, int* __restrict__ segst) {
  int row = blockIdx.x * 4 + (threadIdx.x >> 6);    // b*T + t
  int lane = threadIdx.x & 63;
  const float* r = align + (size_t)row * N_;
  unsigned long long m0 = __ballot(r[lane] > 0.5f);
  unsigned long long m1 = __ballot(r[lane + 64] > 0.5f);
  if (lane == 0) {
    int n = m0 ? (__ffsll(m0) - 1) : (m1 ? (__ffsll(m1) - 1 + 64) : 0);
    idx[row] = n;
    int b = row >> 10, t = row & 1023;
    atomicAdd(&dur[b * N_ + n], 1);
    atomicMin(&segst[b * N_ + n], t);
  }
}

// ---------------------------------------------------------------------------
// bf16 MFMA GEMM, 64x128 tile, BK=64, 4 waves (each 64x32), depth-3 pipelined
// global_load_lds (counted vmcnt), slot-XOR LDS swizzle, 72KB LDS ->
// 2 blocks/CU co-residency.
//   EPI: 0 none, 1 silu, 3 raw partial (split-K), 4 none + fused L1/L2 loss
//   APAD: A physical row = m + 2*(m>>10); CMODE: C row = m + 2*(m>>10) + 1
// ---------------------------------------------------------------------------
template<int EPI, int APAD, int CMODE, typename CT>
__global__ __launch_bounds__(256, 2) void k_mgemm(
    const bf16* __restrict__ A, int lda,
    const bf16* __restrict__ W, int ldw,
    const float* __restrict__ bias,
    CT* __restrict__ C, int ldc,
    int M, int Nc, int K,
    const float* __restrict__ xref = nullptr,
    float* __restrict__ lacc = nullptr)
{
  __shared__ __align__(16) short As[3][4096];   // 64 rows x 64 k
  __shared__ __align__(16) short Bs[3][8192];   // 128 rows x 64 k
  const int tid = threadIdx.x;
  const int m0 = blockIdx.y * 64;
  const int n0 = blockIdx.x * 128;
  const int kbase = blockIdx.z * K;
  const int w = tid >> 6, lane = tid & 63;
  const int wn = w * 32;
  const int lr = lane & 15;
  const int cg = lane >> 4;                      // k-chunk group 0..3

  const int rg = lane >> 3;                      // 0..7
  const int soff = (((lane & 7) ^ rg) << 3);     // pre-swizzled source chunk
  const int rA = w * 8 + rg;                     // 0..31
  int gA0 = m0 + rA, gA1 = m0 + rA + 32;
  int ar0 = APAD ? gA0 + ((gA0 >> 10) << 1) : gA0;
  int ar1 = APAD ? gA1 + ((gA1 >> 10) << 1) : gA1;
  const size_t aOff0 = (size_t)ar0 * lda + kbase + soff;
  const size_t aOff1 = (size_t)ar1 * lda + kbase + soff;
  size_t wOffs[4];
#pragma unroll
  for (int j = 0; j < 4; ++j)
    wOffs[j] = (size_t)(n0 + rA + j * 32) * ldw + kbase + soff;

  const int nt = K >> 6;

#define STAGE_(tt, buf) do { \
    size_t kk_ = (size_t)(tt) * 64; \
    gload16(A + aOff0 + kk_, &As[buf][tid * 8]); \
    gload16(A + aOff1 + kk_, &As[buf][2048 + tid * 8]); \
    gload16(W + wOffs[0] + kk_, &Bs[buf][tid * 8]); \
    gload16(W + wOffs[1] + kk_, &Bs[buf][2048 + tid * 8]); \
    gload16(W + wOffs[2] + kk_, &Bs[buf][4096 + tid * 8]); \
    gload16(W + wOffs[3] + kk_, &Bs[buf][6144 + tid * 8]); \
  } while (0)

  STAGE_(0, 0);
  if (nt > 1) STAGE_(1, 1);

  f32x4 acc[4][2] = {};
  int cur = 0;
  for (int t = 0; t < nt; ++t) {
    if (t + 2 < nt) {
      int b2 = cur + 2; if (b2 >= 3) b2 -= 3;
      STAGE_(t + 2, b2);
      asm volatile("s_waitcnt vmcnt(12)" ::: "memory");
    } else if (t + 1 < nt) {
      asm volatile("s_waitcnt vmcnt(6)" ::: "memory");
    } else {
      asm volatile("s_waitcnt vmcnt(0)" ::: "memory");
    }
    __builtin_amdgcn_sched_barrier(0);
    __builtin_amdgcn_s_barrier();
    __builtin_amdgcn_sched_barrier(0);
#pragma unroll
    for (int h = 0; h < 2; ++h) {
      short8v af[4], bfv[2];
#pragma unroll
      for (int i = 0; i < 4; ++i) {
        int rr = i * 16 + lr;
        af[i] = *(const short8v*)&As[cur][rr * 64 + (((h * 4 + cg) ^ (rr & 7)) << 3)];
      }
#pragma unroll
      for (int j = 0; j < 2; ++j) {
        int rr = wn + j * 16 + lr;
        bfv[j] = *(const short8v*)&Bs[cur][rr * 64 + (((h * 4 + cg) ^ (rr & 7)) << 3)];
      }
      __builtin_amdgcn_s_setprio(1);
#pragma unroll
      for (int i = 0; i < 4; ++i)
#pragma unroll
        for (int j = 0; j < 2; ++j)
          acc[i][j] = __builtin_amdgcn_mfma_f32_16x16x32_bf16(af[i], bfv[j], acc[i][j], 0, 0, 0);
      __builtin_amdgcn_s_setprio(0);
    }
    __builtin_amdgcn_sched_barrier(0);
    __builtin_amdgcn_s_barrier();
    __builtin_amdgcn_sched_barrier(0);
    cur = (cur == 2) ? 0 : cur + 1;
  }
#undef STAGE_

  if (EPI == 3) C += (size_t)blockIdx.z * M * ldc;
  const int orow = (lane >> 4) * 4;
  const int ocol = lane & 15;
  float la = 0.f, lb = 0.f;
#pragma unroll
  for (int i = 0; i < 4; ++i) {
#pragma unroll
    for (int q = 0; q < 4; ++q) {
      int gm = m0 + i * 16 + orow + q;
      int cr = CMODE ? gm + ((gm >> 10) << 1) + 1 : gm;
#pragma unroll
      for (int j = 0; j < 2; ++j) {
        int gn = n0 + wn + j * 16 + ocol;
        float v = acc[i][j][q];
        if (EPI != 3) v += bias[gn];
        if (EPI == 1) v = v / (1.f + __expf(-v));
        if (EPI == 4) {
          float diff = xref[(size_t)gm * Nc + gn] - v;
          la += fabsf(diff);
          lb += diff * diff;
        }
        C[(size_t)cr * ldc + gn] = (CT)v;
      }
    }
  }
  if (EPI == 4) {
    __shared__ float sh1[4], sh2[4];
#pragma unroll
    for (int off = 32; off; off >>= 1) { la += __shfl_xor(la, off); lb += __shfl_xor(lb, off); }
    if (lane == 0) { sh1[w] = la; sh2[w] = lb; }
    __syncthreads();
    if (tid == 0) {
      atomicAdd(&lacc[0], sh1[0] + sh1[1] + sh1[2] + sh1[3]);
      atomicAdd(&lacc[1], sh2[0] + sh2[1] + sh2[2] + sh2[3]);
    }
  }
}

// ---------------------------------------------------------------------------
// segment attention, one pass, all 8 heads at once.
// ---------------------------------------------------------------------------
__global__ __launch_bounds__(256) void k_attn(
    const bf16* __restrict__ qbuf, const bf16* __restrict__ kv,
    const int* __restrict__ segst, const int* __restrict__ dur,
    bf16* __restrict__ ctx)
{
  int bn = blockIdx.x;
  int b = bn >> 7;
  int w = threadIdx.x >> 6;
  int lane = threadIdx.x & 63;
  int s0 = segst[bn], cnt = dur[bn];
  if (cnt == 0) { s0 = 0; cnt = T_; }
  size_t qrow = (size_t)bn * 4 + w;
  const bf16* kvb = kv + ((size_t)b * T_ + s0) * 1024;

  float qf[8];
  {
    uint4v qv = *(const uint4v*)(qbuf + qrow * 512 + lane * 8);
#pragma unroll
    for (int i = 0; i < 4; ++i) {
      unsigned u = qv[i];
      qf[2 * i]     = __uint_as_float(u << 16);
      qf[2 * i + 1] = __uint_as_float(u & 0xffff0000u);
    }
  }

  float m = -1e30f, l = 0.f;
  float o[8] = {};
  for (int s = 0; s < cnt; s += 4) {
    float sc4[4];
#pragma unroll
    for (int u = 0; u < 4; ++u) {
      int ss = s + u;
      int sscl = (ss < cnt) ? ss : (cnt - 1);
      uint4v kr = *(const uint4v*)(kvb + (size_t)sscl * 1024 + lane * 8);
      float d0 = 0.f;
#pragma unroll
      for (int i = 0; i < 4; ++i) {
        unsigned uu = kr[i];
        d0 = fmaf(qf[2 * i],     __uint_as_float(uu << 16),         d0);
        d0 = fmaf(qf[2 * i + 1], __uint_as_float(uu & 0xffff0000u), d0);
      }
      d0 += __shfl_xor(d0, 1);
      d0 += __shfl_xor(d0, 2);
      d0 += __shfl_xor(d0, 4);
      sc4[u] = (ss < cnt) ? d0 * 0.125f : -1e30f;
    }
    float cmax = fmaxf(fmaxf(sc4[0], sc4[1]), fmaxf(sc4[2], sc4[3]));
    float mn = fmaxf(m, cmax);
    float c = __expf(m - mn);
    float p[4];
#pragma unroll
    for (int u = 0; u < 4; ++u) p[u] = __expf(sc4[u] - mn);
    l = l * c + p[0] + p[1] + p[2] + p[3];
#pragma unroll
    for (int k = 0; k < 8; ++k) o[k] *= c;
#pragma unroll
    for (int u = 0; u < 4; ++u) {
      int ss = s + u;
      int sscl = (ss < cnt) ? ss : (cnt - 1);
      uint4v vr = *(const uint4v*)(kvb + (size_t)sscl * 1024 + 512 + lane * 8);
      float pu = p[u];
#pragma unroll
      for (int i = 0; i < 4; ++i) {
        unsigned uu = vr[i];
        o[2 * i]     = fmaf(pu, __uint_as_float(uu << 16),         o[2 * i]);
        o[2 * i + 1] = fmaf(pu, __uint_as_float(uu & 0xffff0000u), o[2 * i + 1]);
      }
    }
    m = mn;
  }
  float invl = 1.f / l;
  bf16 ob[8];
#pragma unroll
  for (int k = 0; k < 8; ++k) ob[k] = bf16(o[k] * invl);
  *(uint4v*)(ctx + qrow * 512 + lane * 8) = *(uint4v*)ob;
}

// ---------------------------------------------------------------------------
// fused: blocks [0,1024) layernorm of (queries + attn_out) -> bf16 qn
//        blocks [1024,2048) pooled[b,n,:] = segment mean of x
// ---------------------------------------------------------------------------
__global__ __launch_bounds__(256) void k_lnpool(
    const float* __restrict__ emb, const float* __restrict__ lq,
    const float* __restrict__ attn,
    const float* __restrict__ g, const float* __restrict__ bb,
    bf16* __restrict__ qn,
    const float* __restrict__ x, const int* __restrict__ segst,
    const int* __restrict__ dur, float* __restrict__ pooled)
{
  if (blockIdx.x < 1024) {
    int r = blockIdx.x * 4 + (threadIdx.x >> 6);
    int lane = threadIdx.x & 63;
    int bn = r >> 2, j = r & 3;
    const float* src = (j == 0) ? emb + (size_t)bn * D_ : lq + (size_t)(j - 1) * D_;
    float h[8];
    float s = 0.f, s2 = 0.f;
#pragma unroll
    for (int i = 0; i < 8; ++i) {
      int d = i * 64 + lane;
      float v = src[d] + attn[(size_t)r * D_ + d];
      h[i] = v; s += v; s2 += v * v;
    }
#pragma unroll
    for (int off = 32; off; off >>= 1) { s += __shfl_xor(s, off); s2 += __shfl_xor(s2, off); }
    float mean = s * (1.f / 512.f);
    float var = s2 * (1.f / 512.f) - mean * mean;
    float inv = rsqrtf(var + 1e-5f);
#pragma unroll
    for (int i = 0; i < 8; ++i) {
      int d = i * 64 + lane;
      qn[(size_t)r * D_ + d] = bf16((h[i] - mean) * inv * g[d] + bb[d]);
    }
  } else {
    int bn = blockIdx.x - 1024;
    int b = bn >> 7;
    int s0 = segst[bn], cnt = dur[bn];
    int d0 = threadIdx.x;
    float a0 = 0.f, a1 = 0.f;
    for (int i = 0; i < cnt; ++i) {
      const float* xr = x + (size_t)(b * T_ + s0 + i) * D_;
      a0 += xr[d0];
      a1 += xr[d0 + 256];
    }
    float inv = 1.f / ((float)cnt + 1e-8f);
    pooled[(size_t)bn * D_ + d0] = a0 * inv;
    pooled[(size_t)bn * D_ + d0 + 256] = a1 * inv;
  }
}

// ---------------------------------------------------------------------------
// fused bottleneck epilogue + mu/logvar/z + KL partial.
// hidden = silu(sum_kz part + bias) + pooled lives only in LDS.
// ---------------------------------------------------------------------------
__global__ __launch_bounds__(128) void k_muz(
    const float* __restrict__ part, const float* __restrict__ bbias,
    const float* __restrict__ pooled,
    const float* __restrict__ mu_w, const float* __restrict__ mu_b,
    const float* __restrict__ lv_w, const float* __restrict__ lv_b,
    const float* __restrict__ eps, float* __restrict__ z, float* __restrict__ klpart)
{
  __shared__ float hs[512];
  __shared__ float ms[64], ls[64];
  int bn = blockIdx.x;
  int tid = threadIdx.x;
  const size_t S = 1024ull * 512;
  for (int i = tid; i < 512; i += 128) {
    size_t off = (size_t)bn * 512 + i;
    float v = part[off] + part[off + S] + part[off + 2 * S] + part[off + 3 * S] + bbias[i];
    v = v / (1.f + __expf(-v));
    hs[i] = v + pooled[off];
  }
  __syncthreads();
  int ld = tid & 63;
  const float* wrow = (tid < 64) ? (mu_w + (size_t)ld * 512) : (lv_w + (size_t)ld * 512);
  float acc = 0.f;
  for (int k = 0; k < 512; ++k) acc = fmaf(hs[k], wrow[k], acc);
  acc += (tid < 64) ? mu_b[ld] : lv_b[ld];
  if (tid < 64) ms[ld] = acc; else ls[ld] = acc;
  __syncthreads();
  if (tid < 64) {
    float mu = ms[ld], lv = ls[ld];
    z[(size_t)bn * 64 + ld] = mu + eps[(size_t)bn * 64 + ld] * expf(0.5f * lv);
    float klt = 1.f + lv - mu * mu - expf(lv);
#pragma unroll
    for (int off = 32; off; off >>= 1) klt += __shfl_xor(klt, off);
    if (ld == 0) klpart[bn] = klt;
  }
}

// ---------------------------------------------------------------------------
// im2col A for conv1 (azc bf16 [8192][256]) + y1p pad-row zeroing fused
// ---------------------------------------------------------------------------
__global__ void k_azc(const float* __restrict__ z, const int* __restrict__ idx,
                      const int* __restrict__ segst, const int* __restrict__ dur,
                      bf16* __restrict__ azc, bf16* __restrict__ y1p)
{
  int gid = blockIdx.x * blockDim.x + threadIdx.x;
  if (blockIdx.x < 32) {
    // 8192 pad elements: 2 rows x 512 per batch
    int d = gid & 511;
    int rest = gid >> 9;
    int which = rest & 1;
    int b = rest >> 1;
    int rr = which ? (T_ + 1) : 0;
    y1p[(size_t)(b * (T_ + 2) + rr) * 512 + d] = bf16(0.f);
  }
  if (gid >= 8192 * 256) return;
  int k = gid & 255;
  int m = gid >> 8;
  int b = m >> 10, t = m & 1023;
  float v = 0.f;
  if (k < 195) {
    int tap = k / 65, c = k - tap * 65;
    int tt = t + tap - 1;
    if (tt >= 0 && tt < T_) {
      int iv = idx[b * T_ + tt];
      if (c < 64) v = z[(size_t)(b * N_ + iv) * 64 + c];
      else {
        int s0 = segst[b * N_ + iv];
        float d2 = (float)dur[b * N_ + iv];
        v = ((float)(tt - s0) + 0.5f) / d2;
      }
    }
  }
  azc[gid] = bf16(v);
}

// ---------------------------------------------------------------------------
// final scalar outputs
// ---------------------------------------------------------------------------
__global__ __launch_bounds__(256) void k_final(
    const float* __restrict__ klpart, const float* __restrict__ lacc,
    const float* __restrict__ klw, float* __restrict__ out)
{
  __shared__ float sa[4];
  float a = 0.f;
  for (int i = threadIdx.x; i < 1024; i += 256) a += klpart[i];
#pragma unroll
  for (int off = 32; off; off >>= 1) a += __shfl_xor(a, off);
  int w = threadIdx.x >> 6, lane = threadIdx.x & 63;
  if (lane == 0) sa[w] = a;
  __syncthreads();
  if (threadIdx.x == 0) {
    float kl = sa[0] + sa[1] + sa[2] + sa[3];
    out[(size_t)B_ * T_ * D_]     = -0.5f * kl * klw[0];
    out[(size_t)B_ * T_ * D_ + 1] = (lacc[0] + lacc[1]) / (float)(B_ * T_ * D_);
  }
}

// ---------------------------------------------------------------------------
extern "C" void kernel_launch(void* const* d_in, const int* in_sizes, int n_in,
                              void* d_out, int out_size, void* d_ws, size_t ws_size,
                              hipStream_t stream)
{
  const float* emb  = (const float*)d_in[0];
  const float* algn = (const float*)d_in[1];
  const float* x    = (const float*)d_in[2];
  const float* klw  = (const float*)d_in[5];
  const float* eps  = (const float*)d_in[6];
  const float* lq   = (const float*)d_in[7];
  const float* inw  = (const float*)d_in[8];
  const float* inb  = (const float*)d_in[9];
  const float* outw = (const float*)d_in[10];
  const float* outb = (const float*)d_in[11];
  const float* lng  = (const float*)d_in[12];
  const float* lnb  = (const float*)d_in[13];
  const float* botw = (const float*)d_in[14];
  const float* botb = (const float*)d_in[15];
  const float* muw  = (const float*)d_in[16];
  const float* mub  = (const float*)d_in[17];
  const float* lvw  = (const float*)d_in[18];
  const float* lvb  = (const float*)d_in[19];
  const float* c1w  = (const float*)d_in[20];
  const float* c1b  = (const float*)d_in[21];
  const float* c2w  = (const float*)d_in[22];
  const float* c2b  = (const float*)d_in[23];
  float* out = (float*)d_out;

  float* ws = (float*)d_ws;
  size_t o = 0;
  auto allocF = [&](size_t n) { float* p = ws + o; o += n; return p; };
  auto allocB = [&](size_t n) { bf16* p = (bf16*)(ws + o); o += (n + 1) / 2; return p; };

  bf16* kvB    = allocB(8192ull * 1024);
  bf16* xb     = allocB(8192ull * 512);     // dead after kv GEMM; azc aliases it
  bf16* qryB   = allocB(4096ull * 512);
  bf16* qbufB  = allocB(4096ull * 512);
  bf16* ctxB   = allocB(4096ull * 512);
  bf16* qnB    = allocB(4096ull * 512);
  bf16* inwb   = allocB(1536ull * 512);
  bf16* outwb  = allocB(512ull * 512);
  bf16* botwb  = allocB(512ull * 2048);
  bf16* w1tb   = allocB(512ull * 256);
  bf16* w2tb   = allocB(512ull * 1536);
  bf16* y1p    = allocB(8ull * (T_ + 2) * 512);
  float* attnF  = allocF(4096ull * 512);    // dead after ln; botP aliases it
  float* pooled = allocF(1024ull * 512);
  float* zbuf   = allocF(1024ull * 64);
  float* klpart = allocF(1024);
  float* lacc   = allocF(2);
  int* idx   = (int*)(ws + o); o += 8192;
  int* segst = (int*)(ws + o); o += 1024;
  int* durI  = (int*)(ws + o); o += 1024;
  bf16* azc  = xb;                          // 8192*256 bf16 < 8192*512 bf16
  float* botP = attnF;                      // 4*1024*512 fp32 == 4096*512 fp32

  // 1. mega-prep (conversions, repacks, queries, seg/loss init)
  k_prep<<<dim3(11781), 256, 0, stream>>>(
      x, inw, outw, botw, c1w, c2w, emb, lq,
      xb, inwb, outwb, botwb, w1tb, w2tb, qryB, durI, segst, lacc);
  // 2. segmentation
  k_seg_build<<<dim3(B_ * T_ / 4), 256, 0, stream>>>(algn, idx, durI, segst);

  // 3. kv projection: [8192,512] x [1024,512]^T -> bf16 [8192,1024]
  k_mgemm<0, 0, 0, bf16><<<dim3(8, 128), 256, 0, stream>>>(
      xb, 512, inwb + 512 * 512, 512, inb + 512, kvB, 1024, 8192, 1024, 512);
  // 4. q projection
  k_mgemm<0, 0, 0, bf16><<<dim3(4, 64), 256, 0, stream>>>(
      qryB, 512, inwb, 512, inb, qbufB, 512, 4096, 512, 512);

  // 5. attention
  k_attn<<<dim3(B_ * N_), 256, 0, stream>>>(qbufB, kvB, segst, durI, ctxB);

  // 6. out projection -> fp32 attnF
  k_mgemm<0, 0, 0, float><<<dim3(4, 64), 256, 0, stream>>>(
      ctxB, 512, outwb, 512, outb, attnF, 512, 4096, 512, 512);

  // 7. layernorm + pooling (fused)
  k_lnpool<<<dim3(2048), 256, 0, stream>>>(
      emb, lq, attnF, lng, lnb, qnB, x, segst, durI, pooled);

  // 8. bottleneck: split-K=4 partials
  k_mgemm<3, 0, 0, float><<<dim3(4, 16, 4), 256, 0, stream>>>(
      qnB, 2048, botwb, 2048, nullptr, botP, 512, 1024, 512, 512);
  // 9. fused bot-epilogue + VAE + KL
  k_muz<<<dim3(B_ * N_), 128, 0, stream>>>(
      botP, botb, pooled, muw, mub, lvw, lvb, eps, zbuf, klpart);

  // 10. conv1 im2col + y1p pad zeroing (fused)
  k_azc<<<dim3(8192 * 256 / 256), 256, 0, stream>>>(zbuf, idx, segst, durI, azc, y1p);

  // 11. conv1: K=256, silu -> bf16 y1p (padded rows, CMODE=1)
  k_mgemm<1, 0, 1, bf16><<<dim3(4, 128), 256, 0, stream>>>(
      azc, 256, w1tb, 256, c1b, y1p, 512, 8192, 512, 256);
  // 12. conv2: padded A (APAD=1), K=1536 -> fp32 out, fused L1/L2 loss vs x
  k_mgemm<4, 1, 0, float><<<dim3(4, 128), 256, 0, stream>>>(
      y1p, 512, w2tb, 1536, c2b, out, 512, 8192, 512, 1536, x, lacc);

  // 13. final scalars
  k_final<<<dim3(1), 256, 0, stream>>>(klpart, lacc, klw, out);
}